// Round 3
// baseline (5483.833 us; speedup 1.0000x reference)
//
#include <hip/hip_runtime.h>
#include <hip/hip_bf16.h>
#include <math.h>

typedef __hip_bfloat16 bf16;

#define NQ      16384
#define CDIM    256
#define NHEADS  8
#define NPOINTS 4
#define NCAM    6
#define HF      58
#define WF      100
#define HWF     (HF*WF)        /* 5800 */
#define NFEAT   (NCAM*HWF)     /* 34800 */
#define HD      32
#define NLAYERS 6

__device__ __forceinline__ float toF(float x) { return x; }
__device__ __forceinline__ float toF(bf16 x) { return __bfloat162float(x); }
__device__ __forceinline__ void storeD(float* p, float v) { *p = v; }
__device__ __forceinline__ void storeD(bf16* p, float v) { *p = __float2bfloat16(v); }

// ---------------------------------------------------------------------------
// Tiled fp32 GEMM: D[M,N] = A[M,K] * B[K,N] + bias[N]  (optional ReLU)
// A: float or bf16 (template). B/bias: float (model weights). D: float or bf16.
// FEATS=true: A is image_feats (NCAM,256,HF,WF) read as logical (NFEAT,256).
// ---------------------------------------------------------------------------
template <typename AT, typename DT, bool RELU, bool FEATS>
__global__ __launch_bounds__(256) void gemm_bias(
    const AT* __restrict__ A, const float* __restrict__ B,
    const float* __restrict__ bias, DT* __restrict__ D,
    int M, int N, int K)
{
    const int BM = 64, BN = 64, BK = 16;
    __shared__ float As[BK][BM + 1];
    __shared__ float Bs[BK][BN + 1];

    int tid = threadIdx.x;
    int bm = blockIdx.y * BM, bn = blockIdx.x * BN;
    int tx = tid & 15, ty = tid >> 4;

    float acc[4][4] = {};

    for (int k0 = 0; k0 < K; k0 += BK) {
        if (FEATS) {
            int kk = tid >> 4;           // 0..15 (k)
            int m4 = (tid & 15) * 4;     // 0..60 (m)
#pragma unroll
            for (int j = 0; j < 4; j++) {
                int m = bm + m4 + j;
                float v = 0.f;
                if (m < M) {
                    int c = (unsigned)m / HWF;
                    int r = m - c * HWF;
                    v = toF(A[((size_t)c * CDIM + (k0 + kk)) * HWF + r]);
                }
                As[kk][m4 + j] = v;
            }
        } else {
            int a_r = tid >> 2;          // 0..63 (m)
            int a_c = (tid & 3) * 4;     // 0,4,8,12 (k)
            int gm = bm + a_r;
            bool ok = gm < M;
            const AT* ap = A + (size_t)gm * K + k0 + a_c;
#pragma unroll
            for (int i = 0; i < 4; i++)
                As[a_c + i][a_r] = ok ? toF(ap[i]) : 0.f;
        }
        {
            int b_r = tid >> 4;          // 0..15 (k)
            int b_c = (tid & 15) * 4;    // 0..60 (n)
            int gn = bn + b_c;
            const float* bp = B + (size_t)(k0 + b_r) * N + gn;
#pragma unroll
            for (int j = 0; j < 4; j++)
                Bs[b_r][b_c + j] = (gn + j < N) ? bp[j] : 0.f;
        }
        __syncthreads();
#pragma unroll
        for (int k = 0; k < BK; k++) {
            float ar[4], br[4];
#pragma unroll
            for (int i = 0; i < 4; i++) ar[i] = As[k][ty * 4 + i];
#pragma unroll
            for (int j = 0; j < 4; j++) br[j] = Bs[k][tx * 4 + j];
#pragma unroll
            for (int i = 0; i < 4; i++)
#pragma unroll
                for (int j = 0; j < 4; j++)
                    acc[i][j] += ar[i] * br[j];
        }
        __syncthreads();
    }

#pragma unroll
    for (int i = 0; i < 4; i++) {
        int gm = bm + ty * 4 + i;
        if (gm >= M) continue;
#pragma unroll
        for (int j = 0; j < 4; j++) {
            int gn = bn + tx * 4 + j;
            if (gn >= N) continue;
            float v = acc[i][j] + bias[gn];
            if (RELU) v = fmaxf(v, 0.f);
            storeD(&D[(size_t)gm * N + gn], v);
        }
    }
}

// ---------------------------------------------------------------------------
__global__ __launch_bounds__(256) void copy_f32(const float* __restrict__ in,
                                                float* __restrict__ out, int n)
{
    int i = blockIdx.x * 256 + threadIdx.x;
    if (i < n) out[i] = in[i];
}

// ---------------------------------------------------------------------------
// 4x4 matrix inverse (Gauss-Jordan, partial pivoting), one thread per camera
// ---------------------------------------------------------------------------
__global__ void invert4_kernel(const float* __restrict__ extr, float* __restrict__ ego)
{
    int c = threadIdx.x;
    if (c >= NCAM) return;
    float a[4][8];
    for (int i = 0; i < 4; i++)
        for (int j = 0; j < 4; j++) {
            a[i][j] = extr[c * 16 + i * 4 + j];
            a[i][4 + j] = (i == j) ? 1.f : 0.f;
        }
    for (int col = 0; col < 4; col++) {
        int piv = col;
        float best = fabsf(a[col][col]);
        for (int r = col + 1; r < 4; r++) {
            float v = fabsf(a[r][col]);
            if (v > best) { best = v; piv = r; }
        }
        if (piv != col)
            for (int j = 0; j < 8; j++) {
                float t = a[col][j]; a[col][j] = a[piv][j]; a[piv][j] = t;
            }
        float inv = 1.f / a[col][col];
        for (int j = 0; j < 8; j++) a[col][j] *= inv;
        for (int r = 0; r < 4; r++) {
            if (r == col) continue;
            float f = a[r][col];
            for (int j = 0; j < 8; j++) a[r][j] -= f * a[col][j];
        }
    }
    for (int i = 0; i < 4; i++)
        for (int j = 0; j < 4; j++)
            ego[c * 16 + i * 4 + j] = a[i][4 + j];
}

// ---------------------------------------------------------------------------
__global__ __launch_bounds__(256) void refcam_kernel(
    const float* __restrict__ ego, const float* __restrict__ intr,
    float* __restrict__ refcam, float* __restrict__ validb)
{
    int t = blockIdx.x * 256 + threadIdx.x;
    if (t >= NCAM * NQ * NPOINTS) return;
    int p = t & 3;
    int n = (t >> 2) & (NQ - 1);
    int c = t >> 16;

    float gx = ((n & 127) + 0.5f) / 128.0f;
    float gy = ((n >> 7) + 0.5f) / 128.0f;
    float xm = -51.2f + gx * 102.4f;
    float ym = -51.2f + gy * 102.4f;
    float zm = -5.0f + (p + 0.5f) * 2.0f;

    const float* E = ego + c * 16;
    float pc[3];
#pragma unroll
    for (int i = 0; i < 3; i++)
        pc[i] = E[i * 4 + 0] * xm + E[i * 4 + 1] * ym + E[i * 4 + 2] * zm + E[i * 4 + 3];

    const float* I = intr + c * 9;
    float im[3];
#pragma unroll
    for (int i = 0; i < 3; i++)
        im[i] = I[i * 3 + 0] * pc[0] + I[i * 3 + 1] * pc[1] + I[i * 3 + 2] * pc[2];

    float z = im[2];
    float zc = fmaxf(z, 1e-5f);
    float un = im[0] / (zc * (float)WF);
    float vn = im[1] / (zc * (float)HF);
    float val = (z > 1e-5f && un >= 0.f && un <= 1.f && vn >= 0.f && vn <= 1.f) ? 1.f : 0.f;

    size_t idx = ((size_t)c * NQ + n) * NPOINTS + p;
    refcam[idx * 2] = un;
    refcam[idx * 2 + 1] = vn;
    validb[idx] = val;
}

__global__ __launch_bounds__(256) void cnt_kernel(const float* __restrict__ validb,
                                                  float* __restrict__ cnt)
{
    int n = blockIdx.x * 256 + threadIdx.x;
    if (n >= NQ) return;
    float s = 0.f;
    for (int c = 0; c < NCAM; c++)
#pragma unroll
        for (int p = 0; p < NPOINTS; p++)
            s += validb[((size_t)c * NQ + n) * NPOINTS + p];
    cnt[n] = fmaxf(s, 1.f);
}

// ---------------------------------------------------------------------------
// Bilinear tap on (H,W,C=256) grid at channel col, zero padding
// ---------------------------------------------------------------------------
__device__ __forceinline__ float bilin(const bf16* __restrict__ v, float lx, float ly,
                                       int H, int W, int col)
{
    float ix = lx * (float)W - 0.5f;
    float iy = ly * (float)H - 0.5f;
    float xf = floorf(ix), yf = floorf(iy);
    float fx = ix - xf, fy = iy - yf;
    int x0 = (int)xf, y0 = (int)yf;
    float acc = 0.f;
#pragma unroll
    for (int dy = 0; dy < 2; dy++) {
        int yi = y0 + dy;
        if (yi < 0 || yi >= H) continue;
        float wy = dy ? fy : 1.f - fy;
#pragma unroll
        for (int dx = 0; dx < 2; dx++) {
            int xi = x0 + dx;
            if (xi < 0 || xi >= W) continue;
            float wx = dx ? fx : 1.f - fx;
            acc += wy * wx * toF(v[((size_t)yi * W + xi) * CDIM + col]);
        }
    }
    return acc;
}

// ---------------------------------------------------------------------------
// TSA deformable sampling: block per query, thread per (head,channel)
// ---------------------------------------------------------------------------
__global__ __launch_bounds__(256) void tsa_sample_kernel(
    const bf16* __restrict__ vprev, const bf16* __restrict__ vcur,
    const float* __restrict__ off, const float* __restrict__ logits,
    float* __restrict__ outA)
{
    int n = blockIdx.x;
    int t = threadIdx.x;
    int d = t & (HD - 1);
    int h = t >> 5;

    const float* lg = logits + (size_t)n * (NHEADS * NPOINTS) + h * NPOINTS;
    float l0 = lg[0], l1 = lg[1], l2 = lg[2], l3 = lg[3];
    float mx = fmaxf(fmaxf(l0, l1), fmaxf(l2, l3));
    float e0 = expf(l0 - mx), e1 = expf(l1 - mx), e2 = expf(l2 - mx), e3 = expf(l3 - mx);
    float inv = 1.f / (e0 + e1 + e2 + e3);
    float w[4] = { e0 * inv, e1 * inv, e2 * inv, e3 * inv };

    float rx = ((n & 127) + 0.5f) / 128.f;
    float ry = ((n >> 7) + 0.5f) / 128.f;
    const float* of = off + (size_t)n * (NHEADS * NPOINTS * 2) + h * (NPOINTS * 2);
    int col = h * HD + d;

    float acc = 0.f;
#pragma unroll
    for (int p = 0; p < NPOINTS; p++) {
        float lx = rx + of[p * 2] * (1.f / 128.f);
        float ly = ry + of[p * 2 + 1] * (1.f / 128.f);
        acc += w[p] * (bilin(vprev, lx, ly, 128, 128, col) +
                       bilin(vcur, lx, ly, 128, 128, col));
    }
    outA[(size_t)n * CDIM + col] = 0.5f * acc;
}

// ---------------------------------------------------------------------------
// SCA deformable sampling: block per query, thread per (head,channel)
// ---------------------------------------------------------------------------
__global__ __launch_bounds__(256) void sca_sample_kernel(
    const bf16* __restrict__ vimg,
    const float* __restrict__ off, const float* __restrict__ logits,
    const float* __restrict__ refcam, const float* __restrict__ validb,
    const float* __restrict__ cnt, float* __restrict__ outA)
{
    int n = blockIdx.x;
    int t = threadIdx.x;
    int d = t & (HD - 1);
    int h = t >> 5;

    const float* lg = logits + (size_t)n * (NHEADS * NPOINTS) + h * NPOINTS;
    float l0 = lg[0], l1 = lg[1], l2 = lg[2], l3 = lg[3];
    float mx = fmaxf(fmaxf(l0, l1), fmaxf(l2, l3));
    float e0 = expf(l0 - mx), e1 = expf(l1 - mx), e2 = expf(l2 - mx), e3 = expf(l3 - mx);
    float inv = 1.f / (e0 + e1 + e2 + e3);
    float w[4] = { e0 * inv, e1 * inv, e2 * inv, e3 * inv };

    const float* of = off + (size_t)n * (NHEADS * NPOINTS * 2) + h * (NPOINTS * 2);
    float ox[4], oy[4];
#pragma unroll
    for (int p = 0; p < NPOINTS; p++) {
        ox[p] = of[p * 2] * (1.f / (float)WF);
        oy[p] = of[p * 2 + 1] * (1.f / (float)HF);
    }
    int col = h * HD + d;

    float acc = 0.f;
    for (int c = 0; c < NCAM; c++) {
        const bf16* vb = vimg + (size_t)c * HWF * CDIM;
        size_t base = ((size_t)c * NQ + n) * NPOINTS;
#pragma unroll
        for (int p = 0; p < NPOINTS; p++) {
            float vl = validb[base + p];
            if (vl == 0.f) continue;          // uniform across block (same n)
            float lx = refcam[(base + p) * 2] + ox[p];
            float ly = refcam[(base + p) * 2 + 1] + oy[p];
            acc += w[p] * vl * bilin(vb, lx, ly, HF, WF, col);
        }
    }
    outA[(size_t)n * CDIM + col] = acc / cnt[n];
}

// ---------------------------------------------------------------------------
// q = LayerNorm(q + t) * g + b   (one wave per row of 256)
// ---------------------------------------------------------------------------
__global__ __launch_bounds__(256) void add_ln_kernel(
    float* __restrict__ q, const float* __restrict__ t,
    const float* __restrict__ g, const float* __restrict__ b)
{
    int wave = threadIdx.x >> 6;
    int lane = threadIdx.x & 63;
    int row = blockIdx.x * 4 + wave;
    float* qr = q + (size_t)row * CDIM;
    const float* tr = t + (size_t)row * CDIM;

    float x[4];
    float s = 0.f, sq = 0.f;
#pragma unroll
    for (int i = 0; i < 4; i++) {
        int cidx = i * 64 + lane;
        x[i] = qr[cidx] + tr[cidx];
        s += x[i];
        sq += x[i] * x[i];
    }
#pragma unroll
    for (int m = 32; m > 0; m >>= 1) {
        s += __shfl_xor(s, m);
        sq += __shfl_xor(sq, m);
    }
    float mean = s * (1.f / CDIM);
    float var = fmaxf(sq * (1.f / CDIM) - mean * mean, 0.f);
    float r = rsqrtf(var + 1e-5f);
#pragma unroll
    for (int i = 0; i < 4; i++) {
        int cidx = i * 64 + lane;
        qr[cidx] = (x[i] - mean) * r * g[cidx] + b[cidx];
    }
}

// ---------------------------------------------------------------------------
// out[ch*16384 + n] = q[n*256 + ch]
// ---------------------------------------------------------------------------
__global__ void out_transpose_kernel(const float* __restrict__ q, float* __restrict__ out)
{
    __shared__ float tile[32][33];
    int n0 = blockIdx.x * 32;
    int c0 = blockIdx.y * 32;
    int tx = threadIdx.x, ty = threadIdx.y;
    for (int i = 0; i < 32; i += 8)
        tile[ty + i][tx] = q[(size_t)(n0 + ty + i) * CDIM + c0 + tx];
    __syncthreads();
    for (int i = 0; i < 32; i += 8)
        out[(size_t)(c0 + ty + i) * NQ + n0 + tx] = tile[tx][ty + i];
}

// ---------------------------------------------------------------------------
// Host launcher
// ---------------------------------------------------------------------------
extern "C" void kernel_launch(void* const* d_in, const int* in_sizes, int n_in,
                              void* d_out, int out_size, void* d_ws, size_t ws_size,
                              hipStream_t stream)
{
    const float* image_feats = (const float*)d_in[0];
    const float* intr        = (const float*)d_in[1];
    const float* extr        = (const float*)d_in[2];
    const float* prev_bev    = (const float*)d_in[3];
    const float* bev_embed   = (const float*)d_in[4];
    const float* tsa_vw = (const float*)d_in[5];
    const float* tsa_vb = (const float*)d_in[6];
    const float* tsa_ow = (const float*)d_in[7];
    const float* tsa_ob = (const float*)d_in[8];
    const float* tsa_aw = (const float*)d_in[9];
    const float* tsa_ab = (const float*)d_in[10];
    const float* tsa_pw = (const float*)d_in[11];
    const float* tsa_pb = (const float*)d_in[12];
    const float* sca_vw = (const float*)d_in[13];
    const float* sca_vb = (const float*)d_in[14];
    const float* sca_ow = (const float*)d_in[15];
    const float* sca_ob = (const float*)d_in[16];
    const float* sca_aw = (const float*)d_in[17];
    const float* sca_ab = (const float*)d_in[18];
    const float* sca_pw = (const float*)d_in[19];
    const float* sca_pb = (const float*)d_in[20];
    const float* ffn_w1 = (const float*)d_in[21];
    const float* ffn_b1 = (const float*)d_in[22];
    const float* ffn_w2 = (const float*)d_in[23];
    const float* ffn_b2 = (const float*)d_in[24];
    const float* ln1_g  = (const float*)d_in[25];
    const float* ln1_b  = (const float*)d_in[26];
    const float* ln2_g  = (const float*)d_in[27];
    const float* ln2_b  = (const float*)d_in[28];
    const float* ln3_g  = (const float*)d_in[29];
    const float* ln3_b  = (const float*)d_in[30];

    // --- workspace layout (~80 MB total) ---
    char* wp = (char*)d_ws;
    auto alloc = [&](size_t bytes) -> void* {
        void* r = (void*)wp;
        wp += (bytes + 255) & ~(size_t)255;
        return r;
    };
    float* q      = (float*)alloc((size_t)NQ * CDIM * 4);        // 16.78 MB
    float* attnA  = (float*)alloc((size_t)NQ * CDIM * 4);        // 16.78 MB
    float* tmp    = (float*)alloc((size_t)NQ * CDIM * 4);        // 16.78 MB
    float* offb   = (float*)alloc((size_t)NQ * 64 * 4);          //  4.19 MB
    float* logits = (float*)alloc((size_t)NQ * 32 * 4);          //  2.10 MB
    float* refcam = (float*)alloc((size_t)NCAM * NQ * NPOINTS * 2 * 4); // 3.15 MB
    float* validb = (float*)alloc((size_t)NCAM * NQ * NPOINTS * 4);     // 1.57 MB
    float* cnt    = (float*)alloc((size_t)NQ * 4);               //  0.07 MB
    float* ego    = (float*)alloc(128 * 4);
    bf16*  big    = (bf16*) alloc((size_t)NFEAT * CDIM * 2);     // 17.82 MB (union)

    bf16* vprev  = big;                         // TSA: 2 x 8.39 MB
    bf16* vcur   = big + (size_t)NQ * CDIM;
    bf16* vimg   = big;                         // SCA: 17.82 MB
    bf16* hidden = big;                         // FFN: 16.78 MB

    auto gemmF = [&](const float* A, const float* B, const float* bias, float* D,
                     int M, int N, int K) {
        dim3 g((N + 63) / 64, (M + 63) / 64);
        gemm_bias<float, float, false, false><<<g, 256, 0, stream>>>(A, B, bias, D, M, N, K);
    };

    // --- prep ---
    copy_f32<<<(NQ * CDIM + 255) / 256, 256, 0, stream>>>(bev_embed, q, NQ * CDIM);
    invert4_kernel<<<1, 64, 0, stream>>>(extr, ego);
    refcam_kernel<<<(NCAM * NQ * NPOINTS + 255) / 256, 256, 0, stream>>>(ego, intr, refcam, validb);
    cnt_kernel<<<(NQ + 255) / 256, 256, 0, stream>>>(validb, cnt);

    for (int l = 0; l < NLAYERS; l++) {
        // ---- TSA ----
        {
            dim3 g(CDIM / 64, NQ / 64);
            gemm_bias<float, bf16, false, false><<<g, 256, 0, stream>>>(
                prev_bev, tsa_vw + (size_t)l * CDIM * CDIM, tsa_vb + l * CDIM,
                vprev, NQ, CDIM, CDIM);
            gemm_bias<float, bf16, false, false><<<g, 256, 0, stream>>>(
                q, tsa_vw + (size_t)l * CDIM * CDIM, tsa_vb + l * CDIM,
                vcur, NQ, CDIM, CDIM);
        }
        gemmF(q, tsa_ow + (size_t)l * CDIM * 64, tsa_ob + l * 64, offb, NQ, 64, CDIM);
        gemmF(q, tsa_aw + (size_t)l * CDIM * 32, tsa_ab + l * 32, logits, NQ, 32, CDIM);
        tsa_sample_kernel<<<NQ, 256, 0, stream>>>(vprev, vcur, offb, logits, attnA);
        gemmF(attnA, tsa_pw + (size_t)l * CDIM * CDIM, tsa_pb + l * CDIM, tmp, NQ, CDIM, CDIM);
        add_ln_kernel<<<NQ / 4, 256, 0, stream>>>(q, tmp, ln1_g + l * CDIM, ln1_b + l * CDIM);

        // ---- SCA ----
        {
            dim3 g(CDIM / 64, (NFEAT + 63) / 64);
            gemm_bias<float, bf16, false, true><<<g, 256, 0, stream>>>(
                image_feats, sca_vw + (size_t)l * CDIM * CDIM, sca_vb + l * CDIM,
                vimg, NFEAT, CDIM, CDIM);
        }
        gemmF(q, sca_ow + (size_t)l * CDIM * 64, sca_ob + l * 64, offb, NQ, 64, CDIM);
        gemmF(q, sca_aw + (size_t)l * CDIM * 32, sca_ab + l * 32, logits, NQ, 32, CDIM);
        sca_sample_kernel<<<NQ, 256, 0, stream>>>(vimg, offb, logits, refcam, validb, cnt, attnA);
        gemmF(attnA, sca_pw + (size_t)l * CDIM * CDIM, sca_pb + l * CDIM, tmp, NQ, CDIM, CDIM);
        add_ln_kernel<<<NQ / 4, 256, 0, stream>>>(q, tmp, ln2_g + l * CDIM, ln2_b + l * CDIM);

        // ---- FFN ----
        {
            dim3 g(512 / 64, NQ / 64);
            gemm_bias<float, bf16, true, false><<<g, 256, 0, stream>>>(
                q, ffn_w1 + (size_t)l * CDIM * 512, ffn_b1 + l * 512,
                hidden, NQ, 512, CDIM);
        }
        {
            dim3 g(CDIM / 64, NQ / 64);
            gemm_bias<bf16, float, false, false><<<g, 256, 0, stream>>>(
                hidden, ffn_w2 + (size_t)l * 512 * CDIM, ffn_b2 + l * CDIM,
                tmp, NQ, CDIM, 512);
        }
        add_ln_kernel<<<NQ / 4, 256, 0, stream>>>(q, tmp, ln3_g + l * CDIM, ln3_b + l * CDIM);
    }

    {
        dim3 g(NQ / 32, CDIM / 32);
        out_transpose_kernel<<<g, dim3(32, 8), 0, stream>>>(q, (float*)d_out);
    }
}

// Round 4
// 2917.995 us; speedup vs baseline: 1.8793x; 1.8793x over previous
//
#include <hip/hip_runtime.h>
#include <hip/hip_bf16.h>
#include <math.h>

typedef __hip_bfloat16 bf16;

#define NQ      16384
#define CDIM    256
#define NHEADS  8
#define NPOINTS 4
#define NCAM    6
#define HF      58
#define WF      100
#define HWF     (HF*WF)        /* 5800 */
#define NFEAT   (NCAM*HWF)     /* 34800 */
#define HD      32
#define NLAYERS 6

typedef __attribute__((ext_vector_type(8))) short short8;
typedef __attribute__((ext_vector_type(4))) float floatx4;

__device__ __forceinline__ float toF(float x) { return x; }
__device__ __forceinline__ float toF(bf16 x) { return __bfloat162float(x); }
__device__ __forceinline__ void storeD(float* p, float v) { *p = v; }
__device__ __forceinline__ void storeD(bf16* p, float v) { *p = __float2bfloat16(v); }

// ---------------------------------------------------------------------------
// MFMA bf16 GEMM: D[M,N] = A[M,K] * BT[N,K]^T + bias[N]  (optional ReLU)
// 128x128 tile, BK=32, 4 waves in 2x2, each wave 64x64 (4x4 frags of 16x16).
// LDS rows padded to 40 bf16 (80 B) -> 16B-aligned b128 ops, ~2-way banks.
// N, K must be multiples of 128/32 resp. (true for all call sites).
// ---------------------------------------------------------------------------
template <typename DT, bool RELU>
__global__ __launch_bounds__(256) void gemm_mfma(
    const bf16* __restrict__ A, const bf16* __restrict__ BT,
    const float* __restrict__ bias, DT* __restrict__ D,
    int M, int N, int K)
{
    __shared__ bf16 As[128 * 40];
    __shared__ bf16 Bs[128 * 40];

    int tid = threadIdx.x;
    int lane = tid & 63, w = tid >> 6;
    int wm = w & 1, wn = w >> 1;           // wave 2x2 grid
    int l15 = lane & 15, quad = lane >> 4;
    int bm = blockIdx.y * 128, bn = blockIdx.x * 128;

    floatx4 acc[4][4];
#pragma unroll
    for (int i = 0; i < 4; i++)
#pragma unroll
        for (int j = 0; j < 4; j++)
            acc[i][j] = (floatx4){0.f, 0.f, 0.f, 0.f};

    int srow = tid >> 2;          // 0..63
    int skc  = (tid & 3) * 8;     // 0,8,16,24

    for (int k0 = 0; k0 < K; k0 += 32) {
#pragma unroll
        for (int r = 0; r < 2; r++) {
            int row = srow + r * 64;
            int gm = bm + row;
            int4 va = {0, 0, 0, 0};
            if (gm < M) va = *(const int4*)(A + (size_t)gm * K + k0 + skc);
            *(int4*)(&As[row * 40 + skc]) = va;
            int gn = bn + row;   // N multiple of 128 -> always valid
            int4 vb = *(const int4*)(BT + (size_t)gn * K + k0 + skc);
            *(int4*)(&Bs[row * 40 + skc]) = vb;
        }
        __syncthreads();

        short8 a[4], b[4];
#pragma unroll
        for (int i = 0; i < 4; i++)
            a[i] = *(const short8*)(&As[(wm * 64 + i * 16 + l15) * 40 + quad * 8]);
#pragma unroll
        for (int j = 0; j < 4; j++)
            b[j] = *(const short8*)(&Bs[(wn * 64 + j * 16 + l15) * 40 + quad * 8]);
#pragma unroll
        for (int i = 0; i < 4; i++)
#pragma unroll
            for (int j = 0; j < 4; j++)
                acc[i][j] = __builtin_amdgcn_mfma_f32_16x16x32_bf16(
                    a[i], b[j], acc[i][j], 0, 0, 0);
        __syncthreads();
    }

    // C/D layout: col = lane&15, row = quad*4 + reg  [m89/m91 verified]
#pragma unroll
    for (int i = 0; i < 4; i++) {
#pragma unroll
        for (int j = 0; j < 4; j++) {
            int col = bn + wn * 64 + j * 16 + l15;
            float bv = bias[col];
#pragma unroll
            for (int r = 0; r < 4; r++) {
                int row = bm + wm * 64 + i * 16 + quad * 4 + r;
                if (row < M) {
                    float v = acc[i][j][r] + bv;
                    if (RELU) v = fmaxf(v, 0.f);
                    storeD(&D[(size_t)row * N + col], v);
                }
            }
        }
    }
}

// ---------------------------------------------------------------------------
// SIMT fp32 GEMM (kept for the small-N offset/attn-logit GEMMs; exact fp32)
// ---------------------------------------------------------------------------
__global__ __launch_bounds__(256) void gemm_bias_f32(
    const float* __restrict__ A, const float* __restrict__ B,
    const float* __restrict__ bias, float* __restrict__ D,
    int M, int N, int K)
{
    const int BM = 64, BN = 64, BK = 16;
    __shared__ float As[BK][BM + 1];
    __shared__ float Bs[BK][BN + 1];

    int tid = threadIdx.x;
    int bm = blockIdx.y * BM, bn = blockIdx.x * BN;
    int tx = tid & 15, ty = tid >> 4;

    float acc[4][4] = {};

    for (int k0 = 0; k0 < K; k0 += BK) {
        {
            int a_r = tid >> 2;
            int a_c = (tid & 3) * 4;
            int gm = bm + a_r;
            bool ok = gm < M;
            const float* ap = A + (size_t)gm * K + k0 + a_c;
#pragma unroll
            for (int i = 0; i < 4; i++)
                As[a_c + i][a_r] = ok ? ap[i] : 0.f;
        }
        {
            int b_r = tid >> 4;
            int b_c = (tid & 15) * 4;
            int gn = bn + b_c;
            const float* bp = B + (size_t)(k0 + b_r) * N + gn;
#pragma unroll
            for (int j = 0; j < 4; j++)
                Bs[b_r][b_c + j] = (gn + j < N) ? bp[j] : 0.f;
        }
        __syncthreads();
#pragma unroll
        for (int k = 0; k < BK; k++) {
            float ar[4], br[4];
#pragma unroll
            for (int i = 0; i < 4; i++) ar[i] = As[k][ty * 4 + i];
#pragma unroll
            for (int j = 0; j < 4; j++) br[j] = Bs[k][tx * 4 + j];
#pragma unroll
            for (int i = 0; i < 4; i++)
#pragma unroll
                for (int j = 0; j < 4; j++)
                    acc[i][j] += ar[i] * br[j];
        }
        __syncthreads();
    }

#pragma unroll
    for (int i = 0; i < 4; i++) {
        int gm = bm + ty * 4 + i;
        if (gm >= M) continue;
#pragma unroll
        for (int j = 0; j < 4; j++) {
            int gn = bn + tx * 4 + j;
            if (gn >= N) continue;
            D[(size_t)gm * N + gn] = acc[i][j] + bias[gn];
        }
    }
}

// ---------------------------------------------------------------------------
// Weight convert+transpose: W (K x N, fp32) -> WT (N x K, bf16)
// ---------------------------------------------------------------------------
__global__ void wt_cvt_kernel(const float* __restrict__ W, bf16* __restrict__ WT,
                              int K, int N)
{
    __shared__ float tile[32][33];
    int k0 = blockIdx.x * 32, n0 = blockIdx.y * 32;
    int tx = threadIdx.x, ty = threadIdx.y;
    for (int i = 0; i < 32; i += 8)
        tile[ty + i][tx] = W[(size_t)(k0 + ty + i) * N + n0 + tx];
    __syncthreads();
    for (int i = 0; i < 32; i += 8)
        WT[(size_t)(n0 + ty + i) * K + k0 + tx] = __float2bfloat16(tile[tx][ty + i]);
}

// image_feats (6,256,HF,WF) fp32 -> featsT (NFEAT,256) bf16
__global__ void feats_cvt_kernel(const float* __restrict__ in, bf16* __restrict__ outT)
{
    __shared__ float tile[32][33];
    int c = blockIdx.z;
    int r0 = blockIdx.x * 32, ch0 = blockIdx.y * 32;
    int tx = threadIdx.x, ty = threadIdx.y;
    for (int i = 0; i < 32; i += 8) {
        int r = r0 + tx, ch = ch0 + ty + i;
        tile[ty + i][tx] = (r < HWF) ? in[((size_t)c * CDIM + ch) * HWF + r] : 0.f;
    }
    __syncthreads();
    for (int i = 0; i < 32; i += 8) {
        int r = r0 + ty + i, ch = ch0 + tx;
        if (r < HWF)
            outT[((size_t)c * HWF + r) * CDIM + ch] = __float2bfloat16(tile[tx][ty + i]);
    }
}

__global__ __launch_bounds__(256) void cvt_bf16_kernel(const float* __restrict__ in,
                                                       bf16* __restrict__ out, int n)
{
    int i = blockIdx.x * 256 + threadIdx.x;
    if (i < n) out[i] = __float2bfloat16(in[i]);
}

// q fp32 + qb bf16 from bev_embed
__global__ __launch_bounds__(256) void init_q_kernel(const float* __restrict__ in,
                                                     float* __restrict__ q,
                                                     bf16* __restrict__ qb, int n)
{
    int i = blockIdx.x * 256 + threadIdx.x;
    if (i < n) { float v = in[i]; q[i] = v; qb[i] = __float2bfloat16(v); }
}

// ---------------------------------------------------------------------------
// 4x4 matrix inverse (Gauss-Jordan), one thread per camera
// ---------------------------------------------------------------------------
__global__ void invert4_kernel(const float* __restrict__ extr, float* __restrict__ ego)
{
    int c = threadIdx.x;
    if (c >= NCAM) return;
    float a[4][8];
    for (int i = 0; i < 4; i++)
        for (int j = 0; j < 4; j++) {
            a[i][j] = extr[c * 16 + i * 4 + j];
            a[i][4 + j] = (i == j) ? 1.f : 0.f;
        }
    for (int col = 0; col < 4; col++) {
        int piv = col;
        float best = fabsf(a[col][col]);
        for (int r = col + 1; r < 4; r++) {
            float v = fabsf(a[r][col]);
            if (v > best) { best = v; piv = r; }
        }
        if (piv != col)
            for (int j = 0; j < 8; j++) {
                float t = a[col][j]; a[col][j] = a[piv][j]; a[piv][j] = t;
            }
        float inv = 1.f / a[col][col];
        for (int j = 0; j < 8; j++) a[col][j] *= inv;
        for (int r = 0; r < 4; r++) {
            if (r == col) continue;
            float f = a[r][col];
            for (int j = 0; j < 8; j++) a[r][j] -= f * a[col][j];
        }
    }
    for (int i = 0; i < 4; i++)
        for (int j = 0; j < 4; j++)
            ego[c * 16 + i * 4 + j] = a[i][4 + j];
}

// ---------------------------------------------------------------------------
__global__ __launch_bounds__(256) void refcam_kernel(
    const float* __restrict__ ego, const float* __restrict__ intr,
    float* __restrict__ refcam, float* __restrict__ validb)
{
    int t = blockIdx.x * 256 + threadIdx.x;
    if (t >= NCAM * NQ * NPOINTS) return;
    int p = t & 3;
    int n = (t >> 2) & (NQ - 1);
    int c = t >> 16;

    float gx = ((n & 127) + 0.5f) / 128.0f;
    float gy = ((n >> 7) + 0.5f) / 128.0f;
    float xm = -51.2f + gx * 102.4f;
    float ym = -51.2f + gy * 102.4f;
    float zm = -5.0f + (p + 0.5f) * 2.0f;

    const float* E = ego + c * 16;
    float pc[3];
#pragma unroll
    for (int i = 0; i < 3; i++)
        pc[i] = E[i * 4 + 0] * xm + E[i * 4 + 1] * ym + E[i * 4 + 2] * zm + E[i * 4 + 3];

    const float* I = intr + c * 9;
    float im[3];
#pragma unroll
    for (int i = 0; i < 3; i++)
        im[i] = I[i * 3 + 0] * pc[0] + I[i * 3 + 1] * pc[1] + I[i * 3 + 2] * pc[2];

    float z = im[2];
    float zc = fmaxf(z, 1e-5f);
    float un = im[0] / (zc * (float)WF);
    float vn = im[1] / (zc * (float)HF);
    float val = (z > 1e-5f && un >= 0.f && un <= 1.f && vn >= 0.f && vn <= 1.f) ? 1.f : 0.f;

    size_t idx = ((size_t)c * NQ + n) * NPOINTS + p;
    refcam[idx * 2] = un;
    refcam[idx * 2 + 1] = vn;
    validb[idx] = val;
}

__global__ __launch_bounds__(256) void cnt_kernel(const float* __restrict__ validb,
                                                  float* __restrict__ cnt)
{
    int n = blockIdx.x * 256 + threadIdx.x;
    if (n >= NQ) return;
    float s = 0.f;
    for (int c = 0; c < NCAM; c++)
#pragma unroll
        for (int p = 0; p < NPOINTS; p++)
            s += validb[((size_t)c * NQ + n) * NPOINTS + p];
    cnt[n] = fmaxf(s, 1.f);
}

// ---------------------------------------------------------------------------
// Bilinear tap on (H,W,C=256) bf16 grid at channel col, zero padding
// ---------------------------------------------------------------------------
__device__ __forceinline__ float bilin(const bf16* __restrict__ v, float lx, float ly,
                                       int H, int W, int col)
{
    float ix = lx * (float)W - 0.5f;
    float iy = ly * (float)H - 0.5f;
    float xf = floorf(ix), yf = floorf(iy);
    float fx = ix - xf, fy = iy - yf;
    int x0 = (int)xf, y0 = (int)yf;
    float acc = 0.f;
#pragma unroll
    for (int dy = 0; dy < 2; dy++) {
        int yi = y0 + dy;
        if (yi < 0 || yi >= H) continue;
        float wy = dy ? fy : 1.f - fy;
#pragma unroll
        for (int dx = 0; dx < 2; dx++) {
            int xi = x0 + dx;
            if (xi < 0 || xi >= W) continue;
            float wx = dx ? fx : 1.f - fx;
            acc += wy * wx * toF(v[((size_t)yi * W + xi) * CDIM + col]);
        }
    }
    return acc;
}

// ---------------------------------------------------------------------------
// TSA deformable sampling: block per query, thread per (head,channel)
// ---------------------------------------------------------------------------
__global__ __launch_bounds__(256) void tsa_sample_kernel(
    const bf16* __restrict__ vprev, const bf16* __restrict__ vcur,
    const float* __restrict__ off, const float* __restrict__ logits,
    bf16* __restrict__ outA)
{
    int n = blockIdx.x;
    int t = threadIdx.x;
    int d = t & (HD - 1);
    int h = t >> 5;

    const float* lg = logits + (size_t)n * (NHEADS * NPOINTS) + h * NPOINTS;
    float l0 = lg[0], l1 = lg[1], l2 = lg[2], l3 = lg[3];
    float mx = fmaxf(fmaxf(l0, l1), fmaxf(l2, l3));
    float e0 = expf(l0 - mx), e1 = expf(l1 - mx), e2 = expf(l2 - mx), e3 = expf(l3 - mx);
    float inv = 1.f / (e0 + e1 + e2 + e3);
    float w[4] = { e0 * inv, e1 * inv, e2 * inv, e3 * inv };

    float rx = ((n & 127) + 0.5f) / 128.f;
    float ry = ((n >> 7) + 0.5f) / 128.f;
    const float* of = off + (size_t)n * (NHEADS * NPOINTS * 2) + h * (NPOINTS * 2);
    int col = h * HD + d;

    float acc = 0.f;
#pragma unroll
    for (int p = 0; p < NPOINTS; p++) {
        float lx = rx + of[p * 2] * (1.f / 128.f);
        float ly = ry + of[p * 2 + 1] * (1.f / 128.f);
        acc += w[p] * (bilin(vprev, lx, ly, 128, 128, col) +
                       bilin(vcur, lx, ly, 128, 128, col));
    }
    outA[(size_t)n * CDIM + col] = __float2bfloat16(0.5f * acc);
}

// ---------------------------------------------------------------------------
// SCA deformable sampling: block per query, thread per (head,channel)
// ---------------------------------------------------------------------------
__global__ __launch_bounds__(256) void sca_sample_kernel(
    const bf16* __restrict__ vimg,
    const float* __restrict__ off, const float* __restrict__ logits,
    const float* __restrict__ refcam, const float* __restrict__ validb,
    const float* __restrict__ cnt, bf16* __restrict__ outA)
{
    int n = blockIdx.x;
    int t = threadIdx.x;
    int d = t & (HD - 1);
    int h = t >> 5;

    const float* lg = logits + (size_t)n * (NHEADS * NPOINTS) + h * NPOINTS;
    float l0 = lg[0], l1 = lg[1], l2 = lg[2], l3 = lg[3];
    float mx = fmaxf(fmaxf(l0, l1), fmaxf(l2, l3));
    float e0 = expf(l0 - mx), e1 = expf(l1 - mx), e2 = expf(l2 - mx), e3 = expf(l3 - mx);
    float inv = 1.f / (e0 + e1 + e2 + e3);
    float w[4] = { e0 * inv, e1 * inv, e2 * inv, e3 * inv };

    const float* of = off + (size_t)n * (NHEADS * NPOINTS * 2) + h * (NPOINTS * 2);
    float ox[4], oy[4];
#pragma unroll
    for (int p = 0; p < NPOINTS; p++) {
        ox[p] = of[p * 2] * (1.f / (float)WF);
        oy[p] = of[p * 2 + 1] * (1.f / (float)HF);
    }
    int col = h * HD + d;

    float acc = 0.f;
    for (int c = 0; c < NCAM; c++) {
        const bf16* vb = vimg + (size_t)c * HWF * CDIM;
        size_t base = ((size_t)c * NQ + n) * NPOINTS;
#pragma unroll
        for (int p = 0; p < NPOINTS; p++) {
            float vl = validb[base + p];
            if (vl == 0.f) continue;          // uniform across block (same n)
            float lx = refcam[(base + p) * 2] + ox[p];
            float ly = refcam[(base + p) * 2 + 1] + oy[p];
            acc += w[p] * vl * bilin(vb, lx, ly, HF, WF, col);
        }
    }
    outA[(size_t)n * CDIM + col] = __float2bfloat16(acc / cnt[n]);
}

// ---------------------------------------------------------------------------
// q = LayerNorm(q + t) * g + b ; also refresh bf16 shadow qb
// ---------------------------------------------------------------------------
__global__ __launch_bounds__(256) void add_ln_kernel(
    float* __restrict__ q, bf16* __restrict__ qb, const bf16* __restrict__ t,
    const float* __restrict__ g, const float* __restrict__ b)
{
    int wave = threadIdx.x >> 6;
    int lane = threadIdx.x & 63;
    int row = blockIdx.x * 4 + wave;
    float* qr = q + (size_t)row * CDIM;
    bf16* qbr = qb + (size_t)row * CDIM;
    const bf16* tr = t + (size_t)row * CDIM;

    float x[4];
    float s = 0.f, sq = 0.f;
#pragma unroll
    for (int i = 0; i < 4; i++) {
        int cidx = i * 64 + lane;
        x[i] = qr[cidx] + toF(tr[cidx]);
        s += x[i];
        sq += x[i] * x[i];
    }
#pragma unroll
    for (int m = 32; m > 0; m >>= 1) {
        s += __shfl_xor(s, m);
        sq += __shfl_xor(sq, m);
    }
    float mean = s * (1.f / CDIM);
    float var = fmaxf(sq * (1.f / CDIM) - mean * mean, 0.f);
    float r = rsqrtf(var + 1e-5f);
#pragma unroll
    for (int i = 0; i < 4; i++) {
        int cidx = i * 64 + lane;
        float v = (x[i] - mean) * r * g[cidx] + b[cidx];
        qr[cidx] = v;
        qbr[cidx] = __float2bfloat16(v);
    }
}

// ---------------------------------------------------------------------------
// out[ch*16384 + n] = q[n*256 + ch]
// ---------------------------------------------------------------------------
__global__ void out_transpose_kernel(const float* __restrict__ q, float* __restrict__ out)
{
    __shared__ float tile[32][33];
    int n0 = blockIdx.x * 32;
    int c0 = blockIdx.y * 32;
    int tx = threadIdx.x, ty = threadIdx.y;
    for (int i = 0; i < 32; i += 8)
        tile[ty + i][tx] = q[(size_t)(n0 + ty + i) * CDIM + c0 + tx];
    __syncthreads();
    for (int i = 0; i < 32; i += 8)
        out[(size_t)(c0 + ty + i) * NQ + n0 + tx] = tile[tx][ty + i];
}

// ---------------------------------------------------------------------------
// Host launcher
// ---------------------------------------------------------------------------
extern "C" void kernel_launch(void* const* d_in, const int* in_sizes, int n_in,
                              void* d_out, int out_size, void* d_ws, size_t ws_size,
                              hipStream_t stream)
{
    const float* image_feats = (const float*)d_in[0];
    const float* intr        = (const float*)d_in[1];
    const float* extr        = (const float*)d_in[2];
    const float* prev_bev    = (const float*)d_in[3];
    const float* bev_embed   = (const float*)d_in[4];
    const float* tsa_vw = (const float*)d_in[5];
    const float* tsa_vb = (const float*)d_in[6];
    const float* tsa_ow = (const float*)d_in[7];
    const float* tsa_ob = (const float*)d_in[8];
    const float* tsa_aw = (const float*)d_in[9];
    const float* tsa_ab = (const float*)d_in[10];
    const float* tsa_pw = (const float*)d_in[11];
    const float* tsa_pb = (const float*)d_in[12];
    const float* sca_vw = (const float*)d_in[13];
    const float* sca_vb = (const float*)d_in[14];
    const float* sca_ow = (const float*)d_in[15];
    const float* sca_ob = (const float*)d_in[16];
    const float* sca_aw = (const float*)d_in[17];
    const float* sca_ab = (const float*)d_in[18];
    const float* sca_pw = (const float*)d_in[19];
    const float* sca_pb = (const float*)d_in[20];
    const float* ffn_w1 = (const float*)d_in[21];
    const float* ffn_b1 = (const float*)d_in[22];
    const float* ffn_w2 = (const float*)d_in[23];
    const float* ffn_b2 = (const float*)d_in[24];
    const float* ln1_g  = (const float*)d_in[25];
    const float* ln1_b  = (const float*)d_in[26];
    const float* ln2_g  = (const float*)d_in[27];
    const float* ln2_b  = (const float*)d_in[28];
    const float* ln3_g  = (const float*)d_in[29];
    const float* ln3_b  = (const float*)d_in[30];

    // --- workspace layout (~104 MB) ---
    char* wp = (char*)d_ws;
    auto alloc = [&](size_t bytes) -> void* {
        void* r = (void*)wp;
        wp += (bytes + 255) & ~(size_t)255;
        return r;
    };
    float* q      = (float*)alloc((size_t)NQ * CDIM * 4);        // 16.78 MB
    bf16*  qb     = (bf16*) alloc((size_t)NQ * CDIM * 2);        //  8.39 MB
    bf16*  tmp    = (bf16*) alloc((size_t)NQ * CDIM * 2);        //  8.39 MB
    bf16*  attnA  = (bf16*) alloc((size_t)NQ * CDIM * 2);        //  8.39 MB
    float* offb   = (float*)alloc((size_t)NQ * 64 * 4);          //  4.19 MB
    float* logits = (float*)alloc((size_t)NQ * 32 * 4);          //  2.10 MB
    float* refcam = (float*)alloc((size_t)NCAM * NQ * NPOINTS * 2 * 4); // 3.15 MB
    float* validb = (float*)alloc((size_t)NCAM * NQ * NPOINTS * 4);     // 1.57 MB
    float* cnt    = (float*)alloc((size_t)NQ * 4);
    float* ego    = (float*)alloc(128 * 4);
    bf16*  prevbf = (bf16*) alloc((size_t)NQ * CDIM * 2);        //  8.39 MB
    bf16*  featsT = (bf16*) alloc((size_t)NFEAT * CDIM * 2);     // 17.82 MB
    bf16*  wtsT   = (bf16*) alloc((size_t)NLAYERS * 524288 * 2); //  6.29 MB
    bf16*  big    = (bf16*) alloc((size_t)NFEAT * CDIM * 2);     // 17.82 MB (union)

    bf16* vprev  = big;                         // TSA: 2 x 8.39 MB
    bf16* vcur   = big + (size_t)NQ * CDIM;
    bf16* vimg   = big;                         // SCA: 17.82 MB
    bf16* hidden = big;                         // FFN: 16.78 MB

    // per-layer transposed-weight offsets inside wtsT
    const size_t WT_L   = 524288;
    const size_t O_VW   = 0;        // 256x256
    const size_t O_PW   = 65536;    // 256x256
    const size_t O_SVW  = 131072;   // 256x256
    const size_t O_SPW  = 196608;   // 256x256
    const size_t O_W1   = 262144;   // 512x256
    const size_t O_W2   = 393216;   // 256x512

    dim3 blk32(32, 8);

    // --- one-time prep (runs every call; graph-safe) ---
    init_q_kernel<<<(NQ * CDIM + 255) / 256, 256, 0, stream>>>(bev_embed, q, qb, NQ * CDIM);
    cvt_bf16_kernel<<<(NQ * CDIM + 255) / 256, 256, 0, stream>>>(prev_bev, prevbf, NQ * CDIM);
    invert4_kernel<<<1, 64, 0, stream>>>(extr, ego);
    refcam_kernel<<<(NCAM * NQ * NPOINTS + 255) / 256, 256, 0, stream>>>(ego, intr, refcam, validb);
    cnt_kernel<<<(NQ + 255) / 256, 256, 0, stream>>>(validb, cnt);
    {
        dim3 g((HWF + 31) / 32, CDIM / 32, NCAM);
        feats_cvt_kernel<<<g, blk32, 0, stream>>>(image_feats, featsT);
    }
    for (int l = 0; l < NLAYERS; l++) {
        bf16* base = wtsT + (size_t)l * WT_L;
        wt_cvt_kernel<<<dim3(8, 8),  blk32, 0, stream>>>(tsa_vw + (size_t)l * 65536,  base + O_VW,  256, 256);
        wt_cvt_kernel<<<dim3(8, 8),  blk32, 0, stream>>>(tsa_pw + (size_t)l * 65536,  base + O_PW,  256, 256);
        wt_cvt_kernel<<<dim3(8, 8),  blk32, 0, stream>>>(sca_vw + (size_t)l * 65536,  base + O_SVW, 256, 256);
        wt_cvt_kernel<<<dim3(8, 8),  blk32, 0, stream>>>(sca_pw + (size_t)l * 65536,  base + O_SPW, 256, 256);
        wt_cvt_kernel<<<dim3(8, 16), blk32, 0, stream>>>(ffn_w1 + (size_t)l * 131072, base + O_W1,  256, 512);
        wt_cvt_kernel<<<dim3(16, 8), blk32, 0, stream>>>(ffn_w2 + (size_t)l * 131072, base + O_W2,  512, 256);
    }

    auto gemmS = [&](const float* A, const float* B, const float* bias, float* D,
                     int M, int N, int K) {
        dim3 g((N + 63) / 64, (M + 63) / 64);
        gemm_bias_f32<<<g, 256, 0, stream>>>(A, B, bias, D, M, N, K);
    };

    for (int l = 0; l < NLAYERS; l++) {
        bf16* base = wtsT + (size_t)l * WT_L;

        // ---- TSA ----
        {
            dim3 g(2, NQ / 128);
            gemm_mfma<bf16, false><<<g, 256, 0, stream>>>(
                prevbf, base + O_VW, tsa_vb + l * CDIM, vprev, NQ, CDIM, CDIM);
            gemm_mfma<bf16, false><<<g, 256, 0, stream>>>(
                qb, base + O_VW, tsa_vb + l * CDIM, vcur, NQ, CDIM, CDIM);
        }
        gemmS(q, tsa_ow + (size_t)l * CDIM * 64, tsa_ob + l * 64, offb, NQ, 64, CDIM);
        gemmS(q, tsa_aw + (size_t)l * CDIM * 32, tsa_ab + l * 32, logits, NQ, 32, CDIM);
        tsa_sample_kernel<<<NQ, 256, 0, stream>>>(vprev, vcur, offb, logits, attnA);
        {
            dim3 g(2, NQ / 128);
            gemm_mfma<bf16, false><<<g, 256, 0, stream>>>(
                attnA, base + O_PW, tsa_pb + l * CDIM, tmp, NQ, CDIM, CDIM);
        }
        add_ln_kernel<<<NQ / 4, 256, 0, stream>>>(q, qb, tmp, ln1_g + l * CDIM, ln1_b + l * CDIM);

        // ---- SCA ----
        {
            dim3 g(2, (NFEAT + 127) / 128);
            gemm_mfma<bf16, false><<<g, 256, 0, stream>>>(
                featsT, base + O_SVW, sca_vb + l * CDIM, vimg, NFEAT, CDIM, CDIM);
        }
        gemmS(q, sca_ow + (size_t)l * CDIM * 64, sca_ob + l * 64, offb, NQ, 64, CDIM);
        gemmS(q, sca_aw + (size_t)l * CDIM * 32, sca_ab + l * 32, logits, NQ, 32, CDIM);
        sca_sample_kernel<<<NQ, 256, 0, stream>>>(vimg, offb, logits, refcam, validb, cnt, attnA);
        {
            dim3 g(2, NQ / 128);
            gemm_mfma<bf16, false><<<g, 256, 0, stream>>>(
                attnA, base + O_SPW, sca_pb + l * CDIM, tmp, NQ, CDIM, CDIM);
        }
        add_ln_kernel<<<NQ / 4, 256, 0, stream>>>(q, qb, tmp, ln2_g + l * CDIM, ln2_b + l * CDIM);

        // ---- FFN ----
        {
            dim3 g(4, NQ / 128);
            gemm_mfma<bf16, true><<<g, 256, 0, stream>>>(
                qb, base + O_W1, ffn_b1 + l * 512, hidden, NQ, 512, CDIM);
        }
        {
            dim3 g(2, NQ / 128);
            gemm_mfma<bf16, false><<<g, 256, 0, stream>>>(
                hidden, base + O_W2, ffn_b2 + l * CDIM, tmp, NQ, CDIM, 512);
        }
        add_ln_kernel<<<NQ / 4, 256, 0, stream>>>(q, qb, tmp, ln3_g + l * CDIM, ln3_b + l * CDIM);
    }

    {
        dim3 g(NQ / 32, CDIM / 32);
        out_transpose_kernel<<<g, blk32, 0, stream>>>(q, (float*)d_out);
    }
}

// Round 5
// 1700.686 us; speedup vs baseline: 3.2245x; 1.7158x over previous
//
#include <hip/hip_runtime.h>
#include <hip/hip_bf16.h>
#include <math.h>

typedef __hip_bfloat16 bf16;

#define NQ      16384
#define CDIM    256
#define NHEADS  8
#define NPOINTS 4
#define NCAM    6
#define HF      58
#define WF      100
#define HWF     (HF*WF)        /* 5800 */
#define NFEAT   (NCAM*HWF)     /* 34800 */
#define HD      32
#define NLAYERS 6

typedef __attribute__((ext_vector_type(8))) short short8;
typedef __attribute__((ext_vector_type(4))) float floatx4;

__device__ __forceinline__ float toF(float x) { return x; }
__device__ __forceinline__ float toF(bf16 x) { return __bfloat162float(x); }
__device__ __forceinline__ void storeD(float* p, float v) { *p = v; }
__device__ __forceinline__ void storeD(bf16* p, float v) { *p = __float2bfloat16(v); }

// bf16x2 (packed in a uint) -> two floats, exact
__device__ __forceinline__ float bfLo(unsigned u) { return __uint_as_float(u << 16); }
__device__ __forceinline__ float bfHi(unsigned u) { return __uint_as_float(u & 0xffff0000u); }

// ---------------------------------------------------------------------------
// MFMA bf16 GEMM: D[M,N] = A[M,K] * BT[N,K]^T + bias[N]  (optional ReLU)
// 128x128 tile, BK=32, 4 waves 2x2, each wave 64x64 (4x4 frags of 16x16x32).
// ---------------------------------------------------------------------------
template <typename DT, bool RELU>
__global__ __launch_bounds__(256) void gemm_mfma(
    const bf16* __restrict__ A, const bf16* __restrict__ BT,
    const float* __restrict__ bias, DT* __restrict__ D,
    int M, int N, int K)
{
    __shared__ bf16 As[128 * 40];
    __shared__ bf16 Bs[128 * 40];

    int tid = threadIdx.x;
    int lane = tid & 63, w = tid >> 6;
    int wm = w & 1, wn = w >> 1;
    int l15 = lane & 15, quad = lane >> 4;
    int bm = blockIdx.y * 128, bn = blockIdx.x * 128;

    floatx4 acc[4][4];
#pragma unroll
    for (int i = 0; i < 4; i++)
#pragma unroll
        for (int j = 0; j < 4; j++)
            acc[i][j] = (floatx4){0.f, 0.f, 0.f, 0.f};

    int srow = tid >> 2;
    int skc  = (tid & 3) * 8;

    for (int k0 = 0; k0 < K; k0 += 32) {
#pragma unroll
        for (int r = 0; r < 2; r++) {
            int row = srow + r * 64;
            int gm = bm + row;
            int4 va = {0, 0, 0, 0};
            if (gm < M) va = *(const int4*)(A + (size_t)gm * K + k0 + skc);
            *(int4*)(&As[row * 40 + skc]) = va;
            int gn = bn + row;   // N multiple of 128 -> always valid
            int4 vb = *(const int4*)(BT + (size_t)gn * K + k0 + skc);
            *(int4*)(&Bs[row * 40 + skc]) = vb;
        }
        __syncthreads();

        short8 a[4], b[4];
#pragma unroll
        for (int i = 0; i < 4; i++)
            a[i] = *(const short8*)(&As[(wm * 64 + i * 16 + l15) * 40 + quad * 8]);
#pragma unroll
        for (int j = 0; j < 4; j++)
            b[j] = *(const short8*)(&Bs[(wn * 64 + j * 16 + l15) * 40 + quad * 8]);
#pragma unroll
        for (int i = 0; i < 4; i++)
#pragma unroll
            for (int j = 0; j < 4; j++)
                acc[i][j] = __builtin_amdgcn_mfma_f32_16x16x32_bf16(
                    a[i], b[j], acc[i][j], 0, 0, 0);
        __syncthreads();
    }

#pragma unroll
    for (int i = 0; i < 4; i++) {
#pragma unroll
        for (int j = 0; j < 4; j++) {
            int col = bn + wn * 64 + j * 16 + l15;
            float bv = bias[col];
#pragma unroll
            for (int r = 0; r < 4; r++) {
                int row = bm + wm * 64 + i * 16 + quad * 4 + r;
                if (row < M) {
                    float v = acc[i][j][r] + bv;
                    if (RELU) v = fmaxf(v, 0.f);
                    storeD(&D[(size_t)row * N + col], v);
                }
            }
        }
    }
}

// ---------------------------------------------------------------------------
// Weight convert+transpose, batched over layers:
// W (L x K x N fp32) -> WT (L x N x K bf16)
// ---------------------------------------------------------------------------
__global__ void wt_cvt_kernel(const float* __restrict__ W, bf16* __restrict__ WT,
                              int K, int N)
{
    __shared__ float tile[32][33];
    int l = blockIdx.z;
    const float* Wl = W + (size_t)l * K * N;
    bf16* WTl = WT + (size_t)l * K * N;
    int k0 = blockIdx.x * 32, n0 = blockIdx.y * 32;
    int tx = threadIdx.x, ty = threadIdx.y;
    for (int i = 0; i < 32; i += 8)
        tile[ty + i][tx] = Wl[(size_t)(k0 + ty + i) * N + n0 + tx];
    __syncthreads();
    for (int i = 0; i < 32; i += 8)
        WTl[(size_t)(n0 + ty + i) * K + k0 + tx] = __float2bfloat16(tile[tx][ty + i]);
}

// Pack [ow | aw | 0] -> fused WT (L x 128 x 256 bf16) + fused bias (L x 128 f32)
__global__ void pack_offattn_kernel(const float* __restrict__ ow, const float* __restrict__ ob,
                                    const float* __restrict__ aw, const float* __restrict__ ab,
                                    bf16* __restrict__ WT, float* __restrict__ BIAS)
{
    int l = blockIdx.y;
    int n = blockIdx.x;      // 0..127
    int k = threadIdx.x;     // 0..255
    float v = 0.f;
    if (n < 64)      v = ow[((size_t)l * 256 + k) * 64 + n];
    else if (n < 96) v = aw[((size_t)l * 256 + k) * 32 + (n - 64)];
    WT[((size_t)l * 128 + n) * 256 + k] = __float2bfloat16(v);
    if (k == 0) {
        float bv = 0.f;
        if (n < 64)      bv = ob[l * 64 + n];
        else if (n < 96) bv = ab[l * 32 + (n - 64)];
        BIAS[l * 128 + n] = bv;
    }
}

// image_feats (6,256,HF,WF) fp32 -> featsT (NFEAT,256) bf16
__global__ void feats_cvt_kernel(const float* __restrict__ in, bf16* __restrict__ outT)
{
    __shared__ float tile[32][33];
    int c = blockIdx.z;
    int r0 = blockIdx.x * 32, ch0 = blockIdx.y * 32;
    int tx = threadIdx.x, ty = threadIdx.y;
    for (int i = 0; i < 32; i += 8) {
        int r = r0 + tx, ch = ch0 + ty + i;
        tile[ty + i][tx] = (r < HWF) ? in[((size_t)c * CDIM + ch) * HWF + r] : 0.f;
    }
    __syncthreads();
    for (int i = 0; i < 32; i += 8) {
        int r = r0 + ty + i, ch = ch0 + tx;
        if (r < HWF)
            outT[((size_t)c * HWF + r) * CDIM + ch] = __float2bfloat16(tile[tx][ty + i]);
    }
}

__global__ __launch_bounds__(256) void cvt_bf16_kernel(const float* __restrict__ in,
                                                       bf16* __restrict__ out, int n)
{
    int i = blockIdx.x * 256 + threadIdx.x;
    if (i < n) out[i] = __float2bfloat16(in[i]);
}

__global__ __launch_bounds__(256) void init_q_kernel(const float* __restrict__ in,
                                                     float* __restrict__ q,
                                                     bf16* __restrict__ qb, int n)
{
    int i = blockIdx.x * 256 + threadIdx.x;
    if (i < n) { float v = in[i]; q[i] = v; qb[i] = __float2bfloat16(v); }
}

// ---------------------------------------------------------------------------
// 4x4 inverse, one thread per camera
// ---------------------------------------------------------------------------
__global__ void invert4_kernel(const float* __restrict__ extr, float* __restrict__ ego)
{
    int c = threadIdx.x;
    if (c >= NCAM) return;
    float a[4][8];
    for (int i = 0; i < 4; i++)
        for (int j = 0; j < 4; j++) {
            a[i][j] = extr[c * 16 + i * 4 + j];
            a[i][4 + j] = (i == j) ? 1.f : 0.f;
        }
    for (int col = 0; col < 4; col++) {
        int piv = col;
        float best = fabsf(a[col][col]);
        for (int r = col + 1; r < 4; r++) {
            float v = fabsf(a[r][col]);
            if (v > best) { best = v; piv = r; }
        }
        if (piv != col)
            for (int j = 0; j < 8; j++) {
                float t = a[col][j]; a[col][j] = a[piv][j]; a[piv][j] = t;
            }
        float inv = 1.f / a[col][col];
        for (int j = 0; j < 8; j++) a[col][j] *= inv;
        for (int r = 0; r < 4; r++) {
            if (r == col) continue;
            float f = a[r][col];
            for (int j = 0; j < 8; j++) a[r][j] -= f * a[col][j];
        }
    }
    for (int i = 0; i < 4; i++)
        for (int j = 0; j < 4; j++)
            ego[c * 16 + i * 4 + j] = a[i][4 + j];
}

// ---------------------------------------------------------------------------
__global__ __launch_bounds__(256) void refcam_kernel(
    const float* __restrict__ ego, const float* __restrict__ intr,
    float* __restrict__ refcam, float* __restrict__ validb)
{
    int t = blockIdx.x * 256 + threadIdx.x;
    if (t >= NCAM * NQ * NPOINTS) return;
    int p = t & 3;
    int n = (t >> 2) & (NQ - 1);
    int c = t >> 16;

    float gx = ((n & 127) + 0.5f) / 128.0f;
    float gy = ((n >> 7) + 0.5f) / 128.0f;
    float xm = -51.2f + gx * 102.4f;
    float ym = -51.2f + gy * 102.4f;
    float zm = -5.0f + (p + 0.5f) * 2.0f;

    const float* E = ego + c * 16;
    float pc[3];
#pragma unroll
    for (int i = 0; i < 3; i++)
        pc[i] = E[i * 4 + 0] * xm + E[i * 4 + 1] * ym + E[i * 4 + 2] * zm + E[i * 4 + 3];

    const float* I = intr + c * 9;
    float im[3];
#pragma unroll
    for (int i = 0; i < 3; i++)
        im[i] = I[i * 3 + 0] * pc[0] + I[i * 3 + 1] * pc[1] + I[i * 3 + 2] * pc[2];

    float z = im[2];
    float zc = fmaxf(z, 1e-5f);
    float un = im[0] / (zc * (float)WF);
    float vn = im[1] / (zc * (float)HF);
    float val = (z > 1e-5f && un >= 0.f && un <= 1.f && vn >= 0.f && vn <= 1.f) ? 1.f : 0.f;

    size_t idx = ((size_t)c * NQ + n) * NPOINTS + p;
    refcam[idx * 2] = un;
    refcam[idx * 2 + 1] = vn;
    validb[idx] = val;
}

__global__ __launch_bounds__(256) void cnt_kernel(const float* __restrict__ validb,
                                                  float* __restrict__ cnt)
{
    int n = blockIdx.x * 256 + threadIdx.x;
    if (n >= NQ) return;
    float s = 0.f;
    for (int c = 0; c < NCAM; c++)
#pragma unroll
        for (int p = 0; p < NPOINTS; p++)
            s += validb[((size_t)c * NQ + n) * NPOINTS + p];
    cnt[n] = fmaxf(s, 1.f);
}

// ---------------------------------------------------------------------------
// TSA sampling. 8192 blocks (XCD-swizzled), 256 thr = 2 queries x 8 heads x
// 16 channel-pairs. vgrid = [prev; cur] (2 x NQ x 256 bf16, contiguous).
// offlog = fused [off(64) | logits(32) | pad] fp32, stride 128.
// ---------------------------------------------------------------------------
__global__ __launch_bounds__(256) void tsa_sample_kernel(
    const bf16* __restrict__ vgrid, const float* __restrict__ offlog,
    bf16* __restrict__ outA)
{
    int blk = blockIdx.x;
    int qpair = (blk & 7) * 1024 + (blk >> 3);   // XCD-contiguous slabs
    int t = threadIdx.x;
    int n = qpair * 2 + (t >> 7);
    int r = t & 127;
    int h = r >> 4;
    int dp = r & 15;
    int col = h * HD + dp * 2;

    const float* fl = offlog + (size_t)n * 128;
    const float* lg = fl + 64 + h * 4;
    float l0 = lg[0], l1 = lg[1], l2 = lg[2], l3 = lg[3];
    float mx = fmaxf(fmaxf(l0, l1), fmaxf(l2, l3));
    float e0 = expf(l0 - mx), e1 = expf(l1 - mx), e2 = expf(l2 - mx), e3 = expf(l3 - mx);
    float inv = 1.f / (e0 + e1 + e2 + e3);
    float w[4] = { e0 * inv, e1 * inv, e2 * inv, e3 * inv };

    const float* of = fl + h * 8;
    float rx = ((n & 127) + 0.5f) / 128.f;
    float ry = ((n >> 7) + 0.5f) / 128.f;

    const bf16* vp = vgrid;
    const bf16* vc = vgrid + (size_t)NQ * CDIM;

    float a0 = 0.f, a1 = 0.f;
#pragma unroll
    for (int p = 0; p < NPOINTS; p++) {
        float lx = rx + of[p * 2] * (1.f / 128.f);
        float ly = ry + of[p * 2 + 1] * (1.f / 128.f);
        float ix = lx * 128.f - 0.5f;
        float iy = ly * 128.f - 0.5f;
        float xf = floorf(ix), yf = floorf(iy);
        float fx = ix - xf, fy = iy - yf;
        int x0 = (int)xf, y0 = (int)yf;
#pragma unroll
        for (int dy = 0; dy < 2; dy++) {
            int yi = y0 + dy;
            if (yi < 0 || yi >= 128) continue;
            float wy = dy ? fy : 1.f - fy;
#pragma unroll
            for (int dx = 0; dx < 2; dx++) {
                int xi = x0 + dx;
                if (xi < 0 || xi >= 128) continue;
                float wgt = w[p] * wy * (dx ? fx : 1.f - fx);
                int pix = (yi * 128 + xi) * CDIM + col;
                unsigned up = *(const unsigned*)(vp + pix);
                unsigned uc = *(const unsigned*)(vc + pix);
                a0 += wgt * (bfLo(up) + bfLo(uc));
                a1 += wgt * (bfHi(up) + bfHi(uc));
            }
        }
    }
    union { bf16 b[2]; unsigned u; } pk;
    pk.b[0] = __float2bfloat16(0.5f * a0);
    pk.b[1] = __float2bfloat16(0.5f * a1);
    *(unsigned*)(outA + (size_t)n * CDIM + col) = pk.u;
}

// ---------------------------------------------------------------------------
// SCA sampling. Same block/thread mapping as TSA.
// ---------------------------------------------------------------------------
__global__ __launch_bounds__(256) void sca_sample_kernel(
    const bf16* __restrict__ vimg, const float* __restrict__ offlog,
    const float* __restrict__ refcam, const float* __restrict__ validb,
    const float* __restrict__ cnt, bf16* __restrict__ outA)
{
    int blk = blockIdx.x;
    int qpair = (blk & 7) * 1024 + (blk >> 3);
    int t = threadIdx.x;
    int n = qpair * 2 + (t >> 7);
    int r = t & 127;
    int h = r >> 4;
    int dp = r & 15;
    int col = h * HD + dp * 2;

    const float* fl = offlog + (size_t)n * 128;
    const float* lg = fl + 64 + h * 4;
    float l0 = lg[0], l1 = lg[1], l2 = lg[2], l3 = lg[3];
    float mx = fmaxf(fmaxf(l0, l1), fmaxf(l2, l3));
    float e0 = expf(l0 - mx), e1 = expf(l1 - mx), e2 = expf(l2 - mx), e3 = expf(l3 - mx);
    float inv = 1.f / (e0 + e1 + e2 + e3);
    float w[4] = { e0 * inv, e1 * inv, e2 * inv, e3 * inv };

    const float* of = fl + h * 8;
    float ox[4], oy[4];
#pragma unroll
    for (int p = 0; p < NPOINTS; p++) {
        ox[p] = of[p * 2] * (1.f / (float)WF);
        oy[p] = of[p * 2 + 1] * (1.f / (float)HF);
    }

    float a0 = 0.f, a1 = 0.f;
    for (int c = 0; c < NCAM; c++) {
        const bf16* vb = vimg + (size_t)c * HWF * CDIM;
        size_t base = ((size_t)c * NQ + n) * NPOINTS;
#pragma unroll
        for (int p = 0; p < NPOINTS; p++) {
            float vl = validb[base + p];
            if (vl == 0.f) continue;          // uniform across the wave
            float lx = refcam[(base + p) * 2] + ox[p];
            float ly = refcam[(base + p) * 2 + 1] + oy[p];
            float ix = lx * (float)WF - 0.5f;
            float iy = ly * (float)HF - 0.5f;
            float xf = floorf(ix), yf = floorf(iy);
            float fx = ix - xf, fy = iy - yf;
            int x0 = (int)xf, y0 = (int)yf;
            float wp_ = w[p] * vl;
#pragma unroll
            for (int dy = 0; dy < 2; dy++) {
                int yi = y0 + dy;
                if (yi < 0 || yi >= HF) continue;
                float wy = dy ? fy : 1.f - fy;
#pragma unroll
                for (int dx = 0; dx < 2; dx++) {
                    int xi = x0 + dx;
                    if (xi < 0 || xi >= WF) continue;
                    float wgt = wp_ * wy * (dx ? fx : 1.f - fx);
                    int pix = (yi * WF + xi) * CDIM + col;
                    unsigned u = *(const unsigned*)(vb + pix);
                    a0 += wgt * bfLo(u);
                    a1 += wgt * bfHi(u);
                }
            }
        }
    }
    float ic = 1.f / cnt[n];
    union { bf16 b[2]; unsigned u; } pk;
    pk.b[0] = __float2bfloat16(a0 * ic);
    pk.b[1] = __float2bfloat16(a1 * ic);
    *(unsigned*)(outA + (size_t)n * CDIM + col) = pk.u;
}

// ---------------------------------------------------------------------------
// q = LayerNorm(q + t) * g + b ; refresh bf16 shadow qb
// ---------------------------------------------------------------------------
__global__ __launch_bounds__(256) void add_ln_kernel(
    float* __restrict__ q, bf16* __restrict__ qb, const bf16* __restrict__ t,
    const float* __restrict__ g, const float* __restrict__ b)
{
    int wave = threadIdx.x >> 6;
    int lane = threadIdx.x & 63;
    int row = blockIdx.x * 4 + wave;
    float* qr = q + (size_t)row * CDIM;
    bf16* qbr = qb + (size_t)row * CDIM;
    const bf16* tr = t + (size_t)row * CDIM;

    float x[4];
    float s = 0.f, sq = 0.f;
#pragma unroll
    for (int i = 0; i < 4; i++) {
        int cidx = i * 64 + lane;
        x[i] = qr[cidx] + toF(tr[cidx]);
        s += x[i];
        sq += x[i] * x[i];
    }
#pragma unroll
    for (int m = 32; m > 0; m >>= 1) {
        s += __shfl_xor(s, m);
        sq += __shfl_xor(sq, m);
    }
    float mean = s * (1.f / CDIM);
    float var = fmaxf(sq * (1.f / CDIM) - mean * mean, 0.f);
    float rr = rsqrtf(var + 1e-5f);
#pragma unroll
    for (int i = 0; i < 4; i++) {
        int cidx = i * 64 + lane;
        float v = (x[i] - mean) * rr * g[cidx] + b[cidx];
        qr[cidx] = v;
        qbr[cidx] = __float2bfloat16(v);
    }
}

// ---------------------------------------------------------------------------
__global__ void out_transpose_kernel(const float* __restrict__ q, float* __restrict__ out)
{
    __shared__ float tile[32][33];
    int n0 = blockIdx.x * 32;
    int c0 = blockIdx.y * 32;
    int tx = threadIdx.x, ty = threadIdx.y;
    for (int i = 0; i < 32; i += 8)
        tile[ty + i][tx] = q[(size_t)(n0 + ty + i) * CDIM + c0 + tx];
    __syncthreads();
    for (int i = 0; i < 32; i += 8)
        out[(size_t)(c0 + ty + i) * NQ + n0 + tx] = tile[tx][ty + i];
}

// ---------------------------------------------------------------------------
// Host launcher
// ---------------------------------------------------------------------------
extern "C" void kernel_launch(void* const* d_in, const int* in_sizes, int n_in,
                              void* d_out, int out_size, void* d_ws, size_t ws_size,
                              hipStream_t stream)
{
    const float* image_feats = (const float*)d_in[0];
    const float* intr        = (const float*)d_in[1];
    const float* extr        = (const float*)d_in[2];
    const float* prev_bev    = (const float*)d_in[3];
    const float* bev_embed   = (const float*)d_in[4];
    const float* tsa_vw = (const float*)d_in[5];
    const float* tsa_vb = (const float*)d_in[6];
    const float* tsa_ow = (const float*)d_in[7];
    const float* tsa_ob = (const float*)d_in[8];
    const float* tsa_aw = (const float*)d_in[9];
    const float* tsa_ab = (const float*)d_in[10];
    const float* tsa_pw = (const float*)d_in[11];
    const float* tsa_pb = (const float*)d_in[12];
    const float* sca_vw = (const float*)d_in[13];
    const float* sca_vb = (const float*)d_in[14];
    const float* sca_ow = (const float*)d_in[15];
    const float* sca_ob = (const float*)d_in[16];
    const float* sca_aw = (const float*)d_in[17];
    const float* sca_ab = (const float*)d_in[18];
    const float* sca_pw = (const float*)d_in[19];
    const float* sca_pb = (const float*)d_in[20];
    const float* ffn_w1 = (const float*)d_in[21];
    const float* ffn_b1 = (const float*)d_in[22];
    const float* ffn_w2 = (const float*)d_in[23];
    const float* ffn_b2 = (const float*)d_in[24];
    const float* ln1_g  = (const float*)d_in[25];
    const float* ln1_b  = (const float*)d_in[26];
    const float* ln2_g  = (const float*)d_in[27];
    const float* ln2_b  = (const float*)d_in[28];
    const float* ln3_g  = (const float*)d_in[29];
    const float* ln3_b  = (const float*)d_in[30];

    // --- workspace layout (~106 MB) ---
    char* wp = (char*)d_ws;
    auto alloc = [&](size_t bytes) -> void* {
        void* r = (void*)wp;
        wp += (bytes + 255) & ~(size_t)255;
        return r;
    };
    float* q      = (float*)alloc((size_t)NQ * CDIM * 4);
    bf16*  prevbf = (bf16*) alloc((size_t)NQ * CDIM * 2);  // NOTE: qb must follow
    bf16*  qb     = (bf16*) alloc((size_t)NQ * CDIM * 2);  //       contiguously
    bf16*  tmp    = (bf16*) alloc((size_t)NQ * CDIM * 2);
    bf16*  attnA  = (bf16*) alloc((size_t)NQ * CDIM * 2);
    float* offlog = (float*)alloc((size_t)NQ * 128 * 4);
    float* refcam = (float*)alloc((size_t)NCAM * NQ * NPOINTS * 2 * 4);
    float* validb = (float*)alloc((size_t)NCAM * NQ * NPOINTS * 4);
    float* cnt    = (float*)alloc((size_t)NQ * 4);
    float* ego    = (float*)alloc(128 * 4);
    bf16*  featsT = (bf16*) alloc((size_t)NFEAT * CDIM * 2);
    bf16*  vwT  = (bf16*)alloc((size_t)NLAYERS * 65536 * 2);
    bf16*  pwT  = (bf16*)alloc((size_t)NLAYERS * 65536 * 2);
    bf16*  svwT = (bf16*)alloc((size_t)NLAYERS * 65536 * 2);
    bf16*  spwT = (bf16*)alloc((size_t)NLAYERS * 65536 * 2);
    bf16*  w1T  = (bf16*)alloc((size_t)NLAYERS * 131072 * 2);
    bf16*  w2T  = (bf16*)alloc((size_t)NLAYERS * 131072 * 2);
    bf16*  towT = (bf16*)alloc((size_t)NLAYERS * 32768 * 2);   // fused tsa [ow|aw]
    bf16*  sowT = (bf16*)alloc((size_t)NLAYERS * 32768 * 2);   // fused sca [ow|aw]
    float* tobF = (float*)alloc((size_t)NLAYERS * 128 * 4);
    float* sobF = (float*)alloc((size_t)NLAYERS * 128 * 4);
    bf16*  big  = (bf16*) alloc((size_t)NFEAT * CDIM * 2);     // union

    bf16* vgrid  = big;                         // TSA: [vprev; vcur]
    bf16* vimg   = big;                         // SCA
    bf16* hidden = big;                         // FFN

    dim3 blk32(32, 8);

    // --- prep ---
    init_q_kernel<<<(NQ * CDIM + 255) / 256, 256, 0, stream>>>(bev_embed, q, qb, NQ * CDIM);
    cvt_bf16_kernel<<<(NQ * CDIM + 255) / 256, 256, 0, stream>>>(prev_bev, prevbf, NQ * CDIM);
    invert4_kernel<<<1, 64, 0, stream>>>(extr, ego);
    refcam_kernel<<<(NCAM * NQ * NPOINTS + 255) / 256, 256, 0, stream>>>(ego, intr, refcam, validb);
    cnt_kernel<<<(NQ + 255) / 256, 256, 0, stream>>>(validb, cnt);
    {
        dim3 g((HWF + 31) / 32, CDIM / 32, NCAM);
        feats_cvt_kernel<<<g, blk32, 0, stream>>>(image_feats, featsT);
    }
    wt_cvt_kernel<<<dim3(8, 8,  NLAYERS), blk32, 0, stream>>>(tsa_vw, vwT,  256, 256);
    wt_cvt_kernel<<<dim3(8, 8,  NLAYERS), blk32, 0, stream>>>(tsa_pw, pwT,  256, 256);
    wt_cvt_kernel<<<dim3(8, 8,  NLAYERS), blk32, 0, stream>>>(sca_vw, svwT, 256, 256);
    wt_cvt_kernel<<<dim3(8, 8,  NLAYERS), blk32, 0, stream>>>(sca_pw, spwT, 256, 256);
    wt_cvt_kernel<<<dim3(8, 16, NLAYERS), blk32, 0, stream>>>(ffn_w1, w1T,  256, 512);
    wt_cvt_kernel<<<dim3(16, 8, NLAYERS), blk32, 0, stream>>>(ffn_w2, w2T,  512, 256);
    pack_offattn_kernel<<<dim3(128, NLAYERS), 256, 0, stream>>>(tsa_ow, tsa_ob, tsa_aw, tsa_ab, towT, tobF);
    pack_offattn_kernel<<<dim3(128, NLAYERS), 256, 0, stream>>>(sca_ow, sca_ob, sca_aw, sca_ab, sowT, sobF);

    for (int l = 0; l < NLAYERS; l++) {
        // ---- TSA ----
        gemm_mfma<bf16, false><<<dim3(2, 2 * NQ / 128), 256, 0, stream>>>(
            prevbf, vwT + (size_t)l * 65536, tsa_vb + l * CDIM,
            vgrid, 2 * NQ, CDIM, CDIM);           // [prevbf;qb] -> [vprev;vcur]
        gemm_mfma<float, false><<<dim3(1, NQ / 128), 256, 0, stream>>>(
            qb, towT + (size_t)l * 32768, tobF + l * 128, offlog, NQ, 128, CDIM);
        tsa_sample_kernel<<<NQ / 2, 256, 0, stream>>>(vgrid, offlog, attnA);
        gemm_mfma<bf16, false><<<dim3(2, NQ / 128), 256, 0, stream>>>(
            attnA, pwT + (size_t)l * 65536, tsa_pb + l * CDIM, tmp, NQ, CDIM, CDIM);
        add_ln_kernel<<<NQ / 4, 256, 0, stream>>>(q, qb, tmp, ln1_g + l * CDIM, ln1_b + l * CDIM);

        // ---- SCA ----
        gemm_mfma<bf16, false><<<dim3(2, (NFEAT + 127) / 128), 256, 0, stream>>>(
            featsT, svwT + (size_t)l * 65536, sca_vb + l * CDIM, vimg, NFEAT, CDIM, CDIM);
        gemm_mfma<float, false><<<dim3(1, NQ / 128), 256, 0, stream>>>(
            qb, sowT + (size_t)l * 32768, sobF + l * 128, offlog, NQ, 128, CDIM);
        sca_sample_kernel<<<NQ / 2, 256, 0, stream>>>(vimg, offlog, refcam, validb, cnt, attnA);
        gemm_mfma<bf16, false><<<dim3(2, NQ / 128), 256, 0, stream>>>(
            attnA, spwT + (size_t)l * 65536, sca_pb + l * CDIM, tmp, NQ, CDIM, CDIM);
        add_ln_kernel<<<NQ / 4, 256, 0, stream>>>(q, qb, tmp, ln2_g + l * CDIM, ln2_b + l * CDIM);

        // ---- FFN ----
        gemm_mfma<bf16, true><<<dim3(4, NQ / 128), 256, 0, stream>>>(
            qb, w1T + (size_t)l * 131072, ffn_b1 + l * 512, hidden, NQ, 512, CDIM);
        gemm_mfma<bf16, false><<<dim3(2, NQ / 128), 256, 0, stream>>>(
            hidden, w2T + (size_t)l * 131072, ffn_b2 + l * CDIM, tmp, NQ, CDIM, 512);
        add_ln_kernel<<<NQ / 4, 256, 0, stream>>>(q, qb, tmp, ln3_g + l * CDIM, ln3_b + l * CDIM);
    }

    {
        dim3 g(NQ / 32, CDIM / 32);
        out_transpose_kernel<<<g, blk32, 0, stream>>>(q, (float*)d_out);
    }
}

// Round 6
// 1408.282 us; speedup vs baseline: 3.8940x; 1.2076x over previous
//
#include <hip/hip_runtime.h>
#include <hip/hip_bf16.h>
#include <math.h>

typedef __hip_bfloat16 bf16;

#define NQ      16384
#define CDIM    256
#define NHEADS  8
#define NPOINTS 4
#define NCAM    6
#define HF      58
#define WF      100
#define HWF     (HF*WF)        /* 5800 */
#define NFEAT   (NCAM*HWF)     /* 34800 */
#define HD      32
#define NLAYERS 6

typedef __attribute__((ext_vector_type(8))) short short8;
typedef __attribute__((ext_vector_type(4))) float floatx4;

__device__ __forceinline__ float toF(float x) { return x; }
__device__ __forceinline__ float toF(bf16 x) { return __bfloat162float(x); }
__device__ __forceinline__ void storeD(float* p, float v) { *p = v; }
__device__ __forceinline__ void storeD(bf16* p, float v) { *p = __float2bfloat16(v); }

__device__ __forceinline__ float bfLo(unsigned u) { return __uint_as_float(u << 16); }
__device__ __forceinline__ float bfHi(unsigned u) { return __uint_as_float(u & 0xffff0000u); }

// ---------------------------------------------------------------------------
// MFMA bf16 GEMM: D[M,N] = A[M,K] * BT[N,K]^T + bias[N]  (optional ReLU)
// 128x128 tile, BK=32, 4 waves 2x2 (used for v-GEMMs / ffn1 / offlog).
// ---------------------------------------------------------------------------
template <typename DT, bool RELU>
__global__ __launch_bounds__(256) void gemm_mfma(
    const bf16* __restrict__ A, const bf16* __restrict__ BT,
    const float* __restrict__ bias, DT* __restrict__ D,
    int M, int N, int K)
{
    __shared__ bf16 As[128 * 40];
    __shared__ bf16 Bs[128 * 40];

    int tid = threadIdx.x;
    int lane = tid & 63, w = tid >> 6;
    int wm = w & 1, wn = w >> 1;
    int l15 = lane & 15, quad = lane >> 4;
    int bm = blockIdx.y * 128, bn = blockIdx.x * 128;

    floatx4 acc[4][4];
#pragma unroll
    for (int i = 0; i < 4; i++)
#pragma unroll
        for (int j = 0; j < 4; j++)
            acc[i][j] = (floatx4){0.f, 0.f, 0.f, 0.f};

    int srow = tid >> 2;
    int skc  = (tid & 3) * 8;

    for (int k0 = 0; k0 < K; k0 += 32) {
#pragma unroll
        for (int r = 0; r < 2; r++) {
            int row = srow + r * 64;
            int gm = bm + row;
            int4 va = {0, 0, 0, 0};
            if (gm < M) va = *(const int4*)(A + (size_t)gm * K + k0 + skc);
            *(int4*)(&As[row * 40 + skc]) = va;
            int gn = bn + row;   // N multiple of 128 -> always valid
            int4 vb = *(const int4*)(BT + (size_t)gn * K + k0 + skc);
            *(int4*)(&Bs[row * 40 + skc]) = vb;
        }
        __syncthreads();

        short8 a[4], b[4];
#pragma unroll
        for (int i = 0; i < 4; i++)
            a[i] = *(const short8*)(&As[(wm * 64 + i * 16 + l15) * 40 + quad * 8]);
#pragma unroll
        for (int j = 0; j < 4; j++)
            b[j] = *(const short8*)(&Bs[(wn * 64 + j * 16 + l15) * 40 + quad * 8]);
#pragma unroll
        for (int i = 0; i < 4; i++)
#pragma unroll
            for (int j = 0; j < 4; j++)
                acc[i][j] = __builtin_amdgcn_mfma_f32_16x16x32_bf16(
                    a[i], b[j], acc[i][j], 0, 0, 0);
        __syncthreads();
    }

#pragma unroll
    for (int i = 0; i < 4; i++) {
#pragma unroll
        for (int j = 0; j < 4; j++) {
            int col = bn + wn * 64 + j * 16 + l15;
            float bv = bias[col];
#pragma unroll
            for (int r = 0; r < 4; r++) {
                int row = bm + wm * 64 + i * 16 + quad * 4 + r;
                if (row < M) {
                    float v = acc[i][j][r] + bv;
                    if (RELU) v = fmaxf(v, 0.f);
                    storeD(&D[(size_t)row * N + col], v);
                }
            }
        }
    }
}

// ---------------------------------------------------------------------------
// Fused GEMM + residual + LayerNorm (N = 256 fixed, M multiple of 64):
//   t = A*BT^T + bias ; x = q + t ; q = LN(x)*g + b ; qb = bf16(q)
// 64x256 tile, 512 threads (8 waves, 2x4), full row in one block.
// ---------------------------------------------------------------------------
__global__ __launch_bounds__(512) void gemm_ln(
    const bf16* __restrict__ A, const bf16* __restrict__ BT,
    const float* __restrict__ bias,
    float* __restrict__ qv, bf16* __restrict__ qb,
    const float* __restrict__ g, const float* __restrict__ b,
    int K)
{
    __shared__ bf16 As[64 * 40];
    __shared__ bf16 Bs[256 * 40];
    __shared__ float red[2][64][4];
    __shared__ float stats[2][64];

    int tid = threadIdx.x;
    int lane = tid & 63, w = tid >> 6;        // 8 waves
    int wm = w & 1, wn = w >> 1;              // 2 x 4
    int l15 = lane & 15, quad = lane >> 4;
    int bm = blockIdx.x * 64;

    floatx4 acc[2][4];
#pragma unroll
    for (int i = 0; i < 2; i++)
#pragma unroll
        for (int j = 0; j < 4; j++)
            acc[i][j] = (floatx4){0.f, 0.f, 0.f, 0.f};

    int srow = tid >> 2;          // 0..127
    int skc  = (tid & 3) * 8;

    for (int k0 = 0; k0 < K; k0 += 32) {
        *(int4*)(&Bs[srow * 40 + skc]) =
            *(const int4*)(BT + (size_t)srow * K + k0 + skc);
        *(int4*)(&Bs[(srow + 128) * 40 + skc]) =
            *(const int4*)(BT + (size_t)(srow + 128) * K + k0 + skc);
        if (tid < 256)
            *(int4*)(&As[(tid >> 2) * 40 + skc]) =
                *(const int4*)(A + (size_t)(bm + (tid >> 2)) * K + k0 + skc);
        __syncthreads();

        short8 a[2], bfr[4];
#pragma unroll
        for (int i = 0; i < 2; i++)
            a[i] = *(const short8*)(&As[(wm * 32 + i * 16 + l15) * 40 + quad * 8]);
#pragma unroll
        for (int j = 0; j < 4; j++)
            bfr[j] = *(const short8*)(&Bs[(wn * 64 + j * 16 + l15) * 40 + quad * 8]);
#pragma unroll
        for (int i = 0; i < 2; i++)
#pragma unroll
            for (int j = 0; j < 4; j++)
                acc[i][j] = __builtin_amdgcn_mfma_f32_16x16x32_bf16(
                    a[i], bfr[j], acc[i][j], 0, 0, 0);
        __syncthreads();
    }

    // x = q + (acc + bias); per-row stats; LN; write back q + qb
    float x[2][4][4];
#pragma unroll
    for (int i = 0; i < 2; i++) {
#pragma unroll
        for (int j = 0; j < 4; j++) {
            int col = wn * 64 + j * 16 + l15;
            float bv = bias[col];
#pragma unroll
            for (int r = 0; r < 4; r++) {
                int row = bm + wm * 32 + i * 16 + quad * 4 + r;
                x[i][j][r] = qv[(size_t)row * CDIM + col] + acc[i][j][r] + bv;
            }
        }
    }
#pragma unroll
    for (int i = 0; i < 2; i++) {
#pragma unroll
        for (int r = 0; r < 4; r++) {
            float s = x[i][0][r] + x[i][1][r] + x[i][2][r] + x[i][3][r];
            float sq = x[i][0][r] * x[i][0][r] + x[i][1][r] * x[i][1][r] +
                       x[i][2][r] * x[i][2][r] + x[i][3][r] * x[i][3][r];
#pragma unroll
            for (int m = 1; m < 16; m <<= 1) {
                s += __shfl_xor(s, m);
                sq += __shfl_xor(sq, m);
            }
            if (l15 == 0) {
                int rl = wm * 32 + i * 16 + quad * 4 + r;
                red[0][rl][wn] = s;
                red[1][rl][wn] = sq;
            }
        }
    }
    __syncthreads();
    if (tid < 64) {
        float s = red[0][tid][0] + red[0][tid][1] + red[0][tid][2] + red[0][tid][3];
        float sq = red[1][tid][0] + red[1][tid][1] + red[1][tid][2] + red[1][tid][3];
        float mean = s * (1.f / CDIM);
        float var = fmaxf(sq * (1.f / CDIM) - mean * mean, 0.f);
        stats[0][tid] = mean;
        stats[1][tid] = rsqrtf(var + 1e-5f);
    }
    __syncthreads();
#pragma unroll
    for (int i = 0; i < 2; i++) {
#pragma unroll
        for (int j = 0; j < 4; j++) {
            int col = wn * 64 + j * 16 + l15;
            float gc = g[col], bc = b[col];
#pragma unroll
            for (int r = 0; r < 4; r++) {
                int rl = wm * 32 + i * 16 + quad * 4 + r;
                int row = bm + rl;
                float y = (x[i][j][r] - stats[0][rl]) * stats[1][rl] * gc + bc;
                qv[(size_t)row * CDIM + col] = y;
                qb[(size_t)row * CDIM + col] = __float2bfloat16(y);
            }
        }
    }
}

// ---------------------------------------------------------------------------
// Weight convert+transpose, batched over layers
// ---------------------------------------------------------------------------
__global__ void wt_cvt_kernel(const float* __restrict__ W, bf16* __restrict__ WT,
                              int K, int N)
{
    __shared__ float tile[32][33];
    int l = blockIdx.z;
    const float* Wl = W + (size_t)l * K * N;
    bf16* WTl = WT + (size_t)l * K * N;
    int k0 = blockIdx.x * 32, n0 = blockIdx.y * 32;
    int tx = threadIdx.x, ty = threadIdx.y;
    for (int i = 0; i < 32; i += 8)
        tile[ty + i][tx] = Wl[(size_t)(k0 + ty + i) * N + n0 + tx];
    __syncthreads();
    for (int i = 0; i < 32; i += 8)
        WTl[(size_t)(n0 + ty + i) * K + k0 + tx] = __float2bfloat16(tile[tx][ty + i]);
}

__global__ void pack_offattn_kernel(const float* __restrict__ ow, const float* __restrict__ ob,
                                    const float* __restrict__ aw, const float* __restrict__ ab,
                                    bf16* __restrict__ WT, float* __restrict__ BIAS)
{
    int l = blockIdx.y;
    int n = blockIdx.x;
    int k = threadIdx.x;
    float v = 0.f;
    if (n < 64)      v = ow[((size_t)l * 256 + k) * 64 + n];
    else if (n < 96) v = aw[((size_t)l * 256 + k) * 32 + (n - 64)];
    WT[((size_t)l * 128 + n) * 256 + k] = __float2bfloat16(v);
    if (k == 0) {
        float bv = 0.f;
        if (n < 64)      bv = ob[l * 64 + n];
        else if (n < 96) bv = ab[l * 32 + (n - 64)];
        BIAS[l * 128 + n] = bv;
    }
}

__global__ void feats_cvt_kernel(const float* __restrict__ in, bf16* __restrict__ outT)
{
    __shared__ float tile[32][33];
    int c = blockIdx.z;
    int r0 = blockIdx.x * 32, ch0 = blockIdx.y * 32;
    int tx = threadIdx.x, ty = threadIdx.y;
    for (int i = 0; i < 32; i += 8) {
        int r = r0 + tx, ch = ch0 + ty + i;
        tile[ty + i][tx] = (r < HWF) ? in[((size_t)c * CDIM + ch) * HWF + r] : 0.f;
    }
    __syncthreads();
    for (int i = 0; i < 32; i += 8) {
        int r = r0 + ty + i, ch = ch0 + tx;
        if (r < HWF)
            outT[((size_t)c * HWF + r) * CDIM + ch] = __float2bfloat16(tile[tx][ty + i]);
    }
}

__global__ __launch_bounds__(256) void cvt_bf16_kernel(const float* __restrict__ in,
                                                       bf16* __restrict__ out, int n)
{
    int i = blockIdx.x * 256 + threadIdx.x;
    if (i < n) out[i] = __float2bfloat16(in[i]);
}

__global__ __launch_bounds__(256) void init_q_kernel(const float* __restrict__ in,
                                                     float* __restrict__ q,
                                                     bf16* __restrict__ qb, int n)
{
    int i = blockIdx.x * 256 + threadIdx.x;
    if (i < n) { float v = in[i]; q[i] = v; qb[i] = __float2bfloat16(v); }
}

// ---------------------------------------------------------------------------
__global__ void invert4_kernel(const float* __restrict__ extr, float* __restrict__ ego)
{
    int c = threadIdx.x;
    if (c >= NCAM) return;
    float a[4][8];
    for (int i = 0; i < 4; i++)
        for (int j = 0; j < 4; j++) {
            a[i][j] = extr[c * 16 + i * 4 + j];
            a[i][4 + j] = (i == j) ? 1.f : 0.f;
        }
    for (int col = 0; col < 4; col++) {
        int piv = col;
        float best = fabsf(a[col][col]);
        for (int r = col + 1; r < 4; r++) {
            float v = fabsf(a[r][col]);
            if (v > best) { best = v; piv = r; }
        }
        if (piv != col)
            for (int j = 0; j < 8; j++) {
                float t = a[col][j]; a[col][j] = a[piv][j]; a[piv][j] = t;
            }
        float inv = 1.f / a[col][col];
        for (int j = 0; j < 8; j++) a[col][j] *= inv;
        for (int r = 0; r < 4; r++) {
            if (r == col) continue;
            float f = a[r][col];
            for (int j = 0; j < 8; j++) a[r][j] -= f * a[col][j];
        }
    }
    for (int i = 0; i < 4; i++)
        for (int j = 0; j < 4; j++)
            ego[c * 16 + i * 4 + j] = a[i][4 + j];
}

__global__ __launch_bounds__(256) void refcam_kernel(
    const float* __restrict__ ego, const float* __restrict__ intr,
    float* __restrict__ refcam, float* __restrict__ validb)
{
    int t = blockIdx.x * 256 + threadIdx.x;
    if (t >= NCAM * NQ * NPOINTS) return;
    int p = t & 3;
    int n = (t >> 2) & (NQ - 1);
    int c = t >> 16;

    float gx = ((n & 127) + 0.5f) / 128.0f;
    float gy = ((n >> 7) + 0.5f) / 128.0f;
    float xm = -51.2f + gx * 102.4f;
    float ym = -51.2f + gy * 102.4f;
    float zm = -5.0f + (p + 0.5f) * 2.0f;

    const float* E = ego + c * 16;
    float pc[3];
#pragma unroll
    for (int i = 0; i < 3; i++)
        pc[i] = E[i * 4 + 0] * xm + E[i * 4 + 1] * ym + E[i * 4 + 2] * zm + E[i * 4 + 3];

    const float* I = intr + c * 9;
    float im[3];
#pragma unroll
    for (int i = 0; i < 3; i++)
        im[i] = I[i * 3 + 0] * pc[0] + I[i * 3 + 1] * pc[1] + I[i * 3 + 2] * pc[2];

    float z = im[2];
    float zc = fmaxf(z, 1e-5f);
    float un = im[0] / (zc * (float)WF);
    float vn = im[1] / (zc * (float)HF);
    float val = (z > 1e-5f && un >= 0.f && un <= 1.f && vn >= 0.f && vn <= 1.f) ? 1.f : 0.f;

    size_t idx = ((size_t)c * NQ + n) * NPOINTS + p;
    refcam[idx * 2] = un;
    refcam[idx * 2 + 1] = vn;
    validb[idx] = val;
}

__global__ __launch_bounds__(256) void cnt_kernel(const float* __restrict__ validb,
                                                  float* __restrict__ cnt)
{
    int n = blockIdx.x * 256 + threadIdx.x;
    if (n >= NQ) return;
    float s = 0.f;
    for (int c = 0; c < NCAM; c++)
#pragma unroll
        for (int p = 0; p < NPOINTS; p++)
            s += validb[((size_t)c * NQ + n) * NPOINTS + p];
    cnt[n] = fmaxf(s, 1.f);
}

// ---------------------------------------------------------------------------
// TSA sampling: 4096 blocks (XCD-swizzled), 256 thr = 4 queries x 8 heads x
// 8 ch-quads; 8B loads (4 channels/thread).
// ---------------------------------------------------------------------------
__global__ __launch_bounds__(256) void tsa_sample_kernel(
    const bf16* __restrict__ vgrid, const float* __restrict__ offlog,
    bf16* __restrict__ outA)
{
    int blk = blockIdx.x;
    int qq = (blk & 7) * 512 + (blk >> 3);
    int t = threadIdx.x;
    int n = qq * 4 + (t >> 6);
    int r = t & 63;
    int h = r >> 3;
    int dq = r & 7;
    int col = h * HD + dq * 4;

    const float* fl = offlog + (size_t)n * 128;
    const float* lg = fl + 64 + h * 4;
    float l0 = lg[0], l1 = lg[1], l2 = lg[2], l3 = lg[3];
    float mx = fmaxf(fmaxf(l0, l1), fmaxf(l2, l3));
    float e0 = expf(l0 - mx), e1 = expf(l1 - mx), e2 = expf(l2 - mx), e3 = expf(l3 - mx);
    float inv = 1.f / (e0 + e1 + e2 + e3);
    float w[4] = { e0 * inv, e1 * inv, e2 * inv, e3 * inv };

    const float* of = fl + h * 8;
    float rx = ((n & 127) + 0.5f) / 128.f;
    float ry = ((n >> 7) + 0.5f) / 128.f;

    const bf16* vp = vgrid;
    const bf16* vc = vgrid + (size_t)NQ * CDIM;

    float a0 = 0.f, a1 = 0.f, a2 = 0.f, a3 = 0.f;
#pragma unroll
    for (int p = 0; p < NPOINTS; p++) {
        float lx = rx + of[p * 2] * (1.f / 128.f);
        float ly = ry + of[p * 2 + 1] * (1.f / 128.f);
        float ix = lx * 128.f - 0.5f;
        float iy = ly * 128.f - 0.5f;
        float xf = floorf(ix), yf = floorf(iy);
        float fx = ix - xf, fy = iy - yf;
        int x0 = (int)xf, y0 = (int)yf;
#pragma unroll
        for (int dy = 0; dy < 2; dy++) {
            int yi = y0 + dy;
            if (yi < 0 || yi >= 128) continue;
            float wy = dy ? fy : 1.f - fy;
#pragma unroll
            for (int dx = 0; dx < 2; dx++) {
                int xi = x0 + dx;
                if (xi < 0 || xi >= 128) continue;
                float wgt = w[p] * wy * (dx ? fx : 1.f - fx);
                int pix = (yi * 128 + xi) * CDIM + col;
                uint2 up = *(const uint2*)(vp + pix);
                uint2 uc = *(const uint2*)(vc + pix);
                a0 += wgt * (bfLo(up.x) + bfLo(uc.x));
                a1 += wgt * (bfHi(up.x) + bfHi(uc.x));
                a2 += wgt * (bfLo(up.y) + bfLo(uc.y));
                a3 += wgt * (bfHi(up.y) + bfHi(uc.y));
            }
        }
    }
    union { bf16 b[4]; uint2 u; } pk;
    pk.b[0] = __float2bfloat16(0.5f * a0);
    pk.b[1] = __float2bfloat16(0.5f * a1);
    pk.b[2] = __float2bfloat16(0.5f * a2);
    pk.b[3] = __float2bfloat16(0.5f * a3);
    *(uint2*)(outA + (size_t)n * CDIM + col) = pk.u;
}

// ---------------------------------------------------------------------------
// SCA sampling: same mapping as TSA.
// ---------------------------------------------------------------------------
__global__ __launch_bounds__(256) void sca_sample_kernel(
    const bf16* __restrict__ vimg, const float* __restrict__ offlog,
    const float* __restrict__ refcam, const float* __restrict__ validb,
    const float* __restrict__ cnt, bf16* __restrict__ outA)
{
    int blk = blockIdx.x;
    int qq = (blk & 7) * 512 + (blk >> 3);
    int t = threadIdx.x;
    int n = qq * 4 + (t >> 6);
    int r = t & 63;
    int h = r >> 3;
    int dq = r & 7;
    int col = h * HD + dq * 4;

    const float* fl = offlog + (size_t)n * 128;
    const float* lg = fl + 64 + h * 4;
    float l0 = lg[0], l1 = lg[1], l2 = lg[2], l3 = lg[3];
    float mx = fmaxf(fmaxf(l0, l1), fmaxf(l2, l3));
    float e0 = expf(l0 - mx), e1 = expf(l1 - mx), e2 = expf(l2 - mx), e3 = expf(l3 - mx);
    float inv = 1.f / (e0 + e1 + e2 + e3);
    float w[4] = { e0 * inv, e1 * inv, e2 * inv, e3 * inv };

    const float* of = fl + h * 8;
    float ox[4], oy[4];
#pragma unroll
    for (int p = 0; p < NPOINTS; p++) {
        ox[p] = of[p * 2] * (1.f / (float)WF);
        oy[p] = of[p * 2 + 1] * (1.f / (float)HF);
    }

    float a0 = 0.f, a1 = 0.f, a2 = 0.f, a3 = 0.f;
    for (int c = 0; c < NCAM; c++) {
        const bf16* vb = vimg + (size_t)c * HWF * CDIM;
        size_t base = ((size_t)c * NQ + n) * NPOINTS;
#pragma unroll
        for (int p = 0; p < NPOINTS; p++) {
            float vl = validb[base + p];
            if (vl == 0.f) continue;          // uniform across the wave (same n)
            float lx = refcam[(base + p) * 2] + ox[p];
            float ly = refcam[(base + p) * 2 + 1] + oy[p];
            float ix = lx * (float)WF - 0.5f;
            float iy = ly * (float)HF - 0.5f;
            float xf = floorf(ix), yf = floorf(iy);
            float fx = ix - xf, fy = iy - yf;
            int x0 = (int)xf, y0 = (int)yf;
            float wp_ = w[p] * vl;
#pragma unroll
            for (int dy = 0; dy < 2; dy++) {
                int yi = y0 + dy;
                if (yi < 0 || yi >= HF) continue;
                float wy = dy ? fy : 1.f - fy;
#pragma unroll
                for (int dx = 0; dx < 2; dx++) {
                    int xi = x0 + dx;
                    if (xi < 0 || xi >= WF) continue;
                    float wgt = wp_ * wy * (dx ? fx : 1.f - fx);
                    int pix = (yi * WF + xi) * CDIM + col;
                    uint2 u = *(const uint2*)(vb + pix);
                    a0 += wgt * bfLo(u.x);
                    a1 += wgt * bfHi(u.x);
                    a2 += wgt * bfLo(u.y);
                    a3 += wgt * bfHi(u.y);
                }
            }
        }
    }
    float ic = 1.f / cnt[n];
    union { bf16 b[4]; uint2 u; } pk;
    pk.b[0] = __float2bfloat16(a0 * ic);
    pk.b[1] = __float2bfloat16(a1 * ic);
    pk.b[2] = __float2bfloat16(a2 * ic);
    pk.b[3] = __float2bfloat16(a3 * ic);
    *(uint2*)(outA + (size_t)n * CDIM + col) = pk.u;
}

// ---------------------------------------------------------------------------
__global__ void out_transpose_kernel(const float* __restrict__ q, float* __restrict__ out)
{
    __shared__ float tile[32][33];
    int n0 = blockIdx.x * 32;
    int c0 = blockIdx.y * 32;
    int tx = threadIdx.x, ty = threadIdx.y;
    for (int i = 0; i < 32; i += 8)
        tile[ty + i][tx] = q[(size_t)(n0 + ty + i) * CDIM + c0 + tx];
    __syncthreads();
    for (int i = 0; i < 32; i += 8)
        out[(size_t)(c0 + ty + i) * NQ + n0 + tx] = tile[tx][ty + i];
}

// ---------------------------------------------------------------------------
// Host launcher
// ---------------------------------------------------------------------------
extern "C" void kernel_launch(void* const* d_in, const int* in_sizes, int n_in,
                              void* d_out, int out_size, void* d_ws, size_t ws_size,
                              hipStream_t stream)
{
    const float* image_feats = (const float*)d_in[0];
    const float* intr        = (const float*)d_in[1];
    const float* extr        = (const float*)d_in[2];
    const float* prev_bev    = (const float*)d_in[3];
    const float* bev_embed   = (const float*)d_in[4];
    const float* tsa_vw = (const float*)d_in[5];
    const float* tsa_vb = (const float*)d_in[6];
    const float* tsa_ow = (const float*)d_in[7];
    const float* tsa_ob = (const float*)d_in[8];
    const float* tsa_aw = (const float*)d_in[9];
    const float* tsa_ab = (const float*)d_in[10];
    const float* tsa_pw = (const float*)d_in[11];
    const float* tsa_pb = (const float*)d_in[12];
    const float* sca_vw = (const float*)d_in[13];
    const float* sca_vb = (const float*)d_in[14];
    const float* sca_ow = (const float*)d_in[15];
    const float* sca_ob = (const float*)d_in[16];
    const float* sca_aw = (const float*)d_in[17];
    const float* sca_ab = (const float*)d_in[18];
    const float* sca_pw = (const float*)d_in[19];
    const float* sca_pb = (const float*)d_in[20];
    const float* ffn_w1 = (const float*)d_in[21];
    const float* ffn_b1 = (const float*)d_in[22];
    const float* ffn_w2 = (const float*)d_in[23];
    const float* ffn_b2 = (const float*)d_in[24];
    const float* ln1_g  = (const float*)d_in[25];
    const float* ln1_b  = (const float*)d_in[26];
    const float* ln2_g  = (const float*)d_in[27];
    const float* ln2_b  = (const float*)d_in[28];
    const float* ln3_g  = (const float*)d_in[29];
    const float* ln3_b  = (const float*)d_in[30];

    // --- workspace layout ---
    char* wp = (char*)d_ws;
    auto alloc = [&](size_t bytes) -> void* {
        void* r = (void*)wp;
        wp += (bytes + 255) & ~(size_t)255;
        return r;
    };
    float* q      = (float*)alloc((size_t)NQ * CDIM * 4);
    bf16*  prevbf = (bf16*) alloc((size_t)NQ * CDIM * 2);  // qb must follow contiguously
    bf16*  qb     = (bf16*) alloc((size_t)NQ * CDIM * 2);
    bf16*  attnA  = (bf16*) alloc((size_t)NQ * CDIM * 2);
    float* offlog = (float*)alloc((size_t)NQ * 128 * 4);
    float* refcam = (float*)alloc((size_t)NCAM * NQ * NPOINTS * 2 * 4);
    float* validb = (float*)alloc((size_t)NCAM * NQ * NPOINTS * 4);
    float* cnt    = (float*)alloc((size_t)NQ * 4);
    float* ego    = (float*)alloc(128 * 4);
    bf16*  featsT = (bf16*) alloc((size_t)NFEAT * CDIM * 2);
    bf16*  vwT  = (bf16*)alloc((size_t)NLAYERS * 65536 * 2);
    bf16*  pwT  = (bf16*)alloc((size_t)NLAYERS * 65536 * 2);
    bf16*  svwT = (bf16*)alloc((size_t)NLAYERS * 65536 * 2);
    bf16*  spwT = (bf16*)alloc((size_t)NLAYERS * 65536 * 2);
    bf16*  w1T  = (bf16*)alloc((size_t)NLAYERS * 131072 * 2);
    bf16*  w2T  = (bf16*)alloc((size_t)NLAYERS * 131072 * 2);
    bf16*  towT = (bf16*)alloc((size_t)NLAYERS * 32768 * 2);
    bf16*  sowT = (bf16*)alloc((size_t)NLAYERS * 32768 * 2);
    float* tobF = (float*)alloc((size_t)NLAYERS * 128 * 4);
    float* sobF = (float*)alloc((size_t)NLAYERS * 128 * 4);
    bf16*  big  = (bf16*) alloc((size_t)NFEAT * CDIM * 2);     // union

    bf16* vgrid  = big;                         // TSA: [vprev; vcur]
    bf16* vimg   = big;                         // SCA
    bf16* hidden = big;                         // FFN

    dim3 blk32(32, 8);

    // --- prep ---
    init_q_kernel<<<(NQ * CDIM + 255) / 256, 256, 0, stream>>>(bev_embed, q, qb, NQ * CDIM);
    cvt_bf16_kernel<<<(NQ * CDIM + 255) / 256, 256, 0, stream>>>(prev_bev, prevbf, NQ * CDIM);
    invert4_kernel<<<1, 64, 0, stream>>>(extr, ego);
    refcam_kernel<<<(NCAM * NQ * NPOINTS + 255) / 256, 256, 0, stream>>>(ego, intr, refcam, validb);
    cnt_kernel<<<(NQ + 255) / 256, 256, 0, stream>>>(validb, cnt);
    {
        dim3 g((HWF + 31) / 32, CDIM / 32, NCAM);
        feats_cvt_kernel<<<g, blk32, 0, stream>>>(image_feats, featsT);
    }
    wt_cvt_kernel<<<dim3(8, 8,  NLAYERS), blk32, 0, stream>>>(tsa_vw, vwT,  256, 256);
    wt_cvt_kernel<<<dim3(8, 8,  NLAYERS), blk32, 0, stream>>>(tsa_pw, pwT,  256, 256);
    wt_cvt_kernel<<<dim3(8, 8,  NLAYERS), blk32, 0, stream>>>(sca_vw, svwT, 256, 256);
    wt_cvt_kernel<<<dim3(8, 8,  NLAYERS), blk32, 0, stream>>>(sca_pw, spwT, 256, 256);
    wt_cvt_kernel<<<dim3(8, 16, NLAYERS), blk32, 0, stream>>>(ffn_w1, w1T,  256, 512);
    wt_cvt_kernel<<<dim3(16, 8, NLAYERS), blk32, 0, stream>>>(ffn_w2, w2T,  512, 256);
    pack_offattn_kernel<<<dim3(128, NLAYERS), 256, 0, stream>>>(tsa_ow, tsa_ob, tsa_aw, tsa_ab, towT, tobF);
    pack_offattn_kernel<<<dim3(128, NLAYERS), 256, 0, stream>>>(sca_ow, sca_ob, sca_aw, sca_ab, sowT, sobF);

    for (int l = 0; l < NLAYERS; l++) {
        // ---- TSA ----
        gemm_mfma<bf16, false><<<dim3(2, 2 * NQ / 128), 256, 0, stream>>>(
            prevbf, vwT + (size_t)l * 65536, tsa_vb + l * CDIM,
            vgrid, 2 * NQ, CDIM, CDIM);           // [prevbf;qb] -> [vprev;vcur]
        gemm_mfma<float, false><<<dim3(1, NQ / 128), 256, 0, stream>>>(
            qb, towT + (size_t)l * 32768, tobF + l * 128, offlog, NQ, 128, CDIM);
        tsa_sample_kernel<<<NQ / 4, 256, 0, stream>>>(vgrid, offlog, attnA);
        gemm_ln<<<NQ / 64, 512, 0, stream>>>(
            attnA, pwT + (size_t)l * 65536, tsa_pb + l * CDIM,
            q, qb, ln1_g + l * CDIM, ln1_b + l * CDIM, CDIM);

        // ---- SCA ----
        gemm_mfma<bf16, false><<<dim3(2, (NFEAT + 127) / 128), 256, 0, stream>>>(
            featsT, svwT + (size_t)l * 65536, sca_vb + l * CDIM, vimg, NFEAT, CDIM, CDIM);
        gemm_mfma<float, false><<<dim3(1, NQ / 128), 256, 0, stream>>>(
            qb, sowT + (size_t)l * 32768, sobF + l * 128, offlog, NQ, 128, CDIM);
        sca_sample_kernel<<<NQ / 4, 256, 0, stream>>>(vimg, offlog, refcam, validb, cnt, attnA);
        gemm_ln<<<NQ / 64, 512, 0, stream>>>(
            attnA, spwT + (size_t)l * 65536, sca_pb + l * CDIM,
            q, qb, ln2_g + l * CDIM, ln2_b + l * CDIM, CDIM);

        // ---- FFN ----
        gemm_mfma<bf16, true><<<dim3(4, NQ / 128), 256, 0, stream>>>(
            qb, w1T + (size_t)l * 131072, ffn_b1 + l * 512, hidden, NQ, 512, CDIM);
        gemm_ln<<<NQ / 64, 512, 0, stream>>>(
            hidden, w2T + (size_t)l * 131072, ffn_b2 + l * CDIM,
            q, qb, ln3_g + l * CDIM, ln3_b + l * CDIM, 512);
    }

    {
        dim3 g(NQ / 32, CDIM / 32);
        out_transpose_kernel<<<g, blk32, 0, stream>>>(q, (float*)d_out);
    }
}

// Round 7
// 1303.214 us; speedup vs baseline: 4.2079x; 1.0806x over previous
//
#include <hip/hip_runtime.h>
#include <hip/hip_bf16.h>
#include <math.h>

typedef __hip_bfloat16 bf16;

#define NQ      16384
#define CDIM    256
#define NHEADS  8
#define NPOINTS 4
#define NCAM    6
#define HF      58
#define WF      100
#define HWF     (HF*WF)        /* 5800 */
#define NFEAT   (NCAM*HWF)     /* 34800 */
#define HD      32
#define NLAYERS 6

typedef __attribute__((ext_vector_type(8))) short short8;
typedef __attribute__((ext_vector_type(4))) float floatx4;

__device__ __forceinline__ float toF(float x) { return x; }
__device__ __forceinline__ float toF(bf16 x) { return __bfloat162float(x); }
__device__ __forceinline__ void storeD(float* p, float v) { *p = v; }
__device__ __forceinline__ void storeD(bf16* p, float v) { *p = __float2bfloat16(v); }

__device__ __forceinline__ float bfLo(unsigned u) { return __uint_as_float(u << 16); }
__device__ __forceinline__ float bfHi(unsigned u) { return __uint_as_float(u & 0xffff0000u); }

// ---------------------------------------------------------------------------
// MFMA bf16 GEMM: D[M,N] = A[M,K] * BT[N,K]^T + bias[N]  (optional ReLU)
// 128x128 tile, BK=32, 4 waves 2x2.
// LAYOUT 0: row-major D.  LAYOUT 1 (vgrid): D index =
//   ((row%NQ)*64 + col/4)*8 + (row>=NQ)*4 + col%4  -- prev/cur interleaved.
// ---------------------------------------------------------------------------
template <typename DT, bool RELU, int LAYOUT>
__global__ __launch_bounds__(256) void gemm_mfma(
    const bf16* __restrict__ A, const bf16* __restrict__ BT,
    const float* __restrict__ bias, DT* __restrict__ D,
    int M, int N, int K)
{
    __shared__ bf16 As[128 * 40];
    __shared__ bf16 Bs[128 * 40];

    int tid = threadIdx.x;
    int lane = tid & 63, w = tid >> 6;
    int wm = w & 1, wn = w >> 1;
    int l15 = lane & 15, quad = lane >> 4;
    int bm = blockIdx.y * 128, bn = blockIdx.x * 128;

    floatx4 acc[4][4];
#pragma unroll
    for (int i = 0; i < 4; i++)
#pragma unroll
        for (int j = 0; j < 4; j++)
            acc[i][j] = (floatx4){0.f, 0.f, 0.f, 0.f};

    int srow = tid >> 2;
    int skc  = (tid & 3) * 8;

    for (int k0 = 0; k0 < K; k0 += 32) {
#pragma unroll
        for (int r = 0; r < 2; r++) {
            int row = srow + r * 64;
            int gm = bm + row;
            int4 va = {0, 0, 0, 0};
            if (gm < M) va = *(const int4*)(A + (size_t)gm * K + k0 + skc);
            *(int4*)(&As[row * 40 + skc]) = va;
            int gn = bn + row;   // N multiple of 128 -> always valid
            int4 vb = *(const int4*)(BT + (size_t)gn * K + k0 + skc);
            *(int4*)(&Bs[row * 40 + skc]) = vb;
        }
        __syncthreads();

        short8 a[4], b[4];
#pragma unroll
        for (int i = 0; i < 4; i++)
            a[i] = *(const short8*)(&As[(wm * 64 + i * 16 + l15) * 40 + quad * 8]);
#pragma unroll
        for (int j = 0; j < 4; j++)
            b[j] = *(const short8*)(&Bs[(wn * 64 + j * 16 + l15) * 40 + quad * 8]);
#pragma unroll
        for (int i = 0; i < 4; i++)
#pragma unroll
            for (int j = 0; j < 4; j++)
                acc[i][j] = __builtin_amdgcn_mfma_f32_16x16x32_bf16(
                    a[i], b[j], acc[i][j], 0, 0, 0);
        __syncthreads();
    }

#pragma unroll
    for (int i = 0; i < 4; i++) {
#pragma unroll
        for (int j = 0; j < 4; j++) {
            int col = bn + wn * 64 + j * 16 + l15;
            float bv = bias[col];
#pragma unroll
            for (int r = 0; r < 4; r++) {
                int row = bm + wm * 64 + i * 16 + quad * 4 + r;
                if (row < M) {
                    float v = acc[i][j][r] + bv;
                    if (RELU) v = fmaxf(v, 0.f);
                    if (LAYOUT == 1) {
                        int n = row & (NQ - 1);
                        int cur = row >= NQ;
                        size_t idx = ((size_t)n * 64 + (col >> 2)) * 8 + cur * 4 + (col & 3);
                        storeD(&D[idx], v);
                    } else {
                        storeD(&D[(size_t)row * N + col], v);
                    }
                }
            }
        }
    }
}

// ---------------------------------------------------------------------------
// Fused GEMM + residual + LayerNorm (N = 256, M mult of 64):
//   t = A*BT^T + bias ; x = q + t ; q = LN(x)*g + b ; qb = bf16(q)
// ---------------------------------------------------------------------------
__global__ __launch_bounds__(512) void gemm_ln(
    const bf16* __restrict__ A, const bf16* __restrict__ BT,
    const float* __restrict__ bias,
    float* __restrict__ qv, bf16* __restrict__ qb,
    const float* __restrict__ g, const float* __restrict__ b,
    int K)
{
    __shared__ bf16 As[64 * 40];
    __shared__ bf16 Bs[256 * 40];
    __shared__ float red[2][64][4];
    __shared__ float stats[2][64];

    int tid = threadIdx.x;
    int lane = tid & 63, w = tid >> 6;
    int wm = w & 1, wn = w >> 1;              // 2 x 4
    int l15 = lane & 15, quad = lane >> 4;
    int bm = blockIdx.x * 64;

    floatx4 acc[2][4];
#pragma unroll
    for (int i = 0; i < 2; i++)
#pragma unroll
        for (int j = 0; j < 4; j++)
            acc[i][j] = (floatx4){0.f, 0.f, 0.f, 0.f};

    int srow = tid >> 2;
    int skc  = (tid & 3) * 8;

    for (int k0 = 0; k0 < K; k0 += 32) {
        *(int4*)(&Bs[srow * 40 + skc]) =
            *(const int4*)(BT + (size_t)srow * K + k0 + skc);
        *(int4*)(&Bs[(srow + 128) * 40 + skc]) =
            *(const int4*)(BT + (size_t)(srow + 128) * K + k0 + skc);
        if (tid < 256)
            *(int4*)(&As[(tid >> 2) * 40 + skc]) =
                *(const int4*)(A + (size_t)(bm + (tid >> 2)) * K + k0 + skc);
        __syncthreads();

        short8 a[2], bfr[4];
#pragma unroll
        for (int i = 0; i < 2; i++)
            a[i] = *(const short8*)(&As[(wm * 32 + i * 16 + l15) * 40 + quad * 8]);
#pragma unroll
        for (int j = 0; j < 4; j++)
            bfr[j] = *(const short8*)(&Bs[(wn * 64 + j * 16 + l15) * 40 + quad * 8]);
#pragma unroll
        for (int i = 0; i < 2; i++)
#pragma unroll
            for (int j = 0; j < 4; j++)
                acc[i][j] = __builtin_amdgcn_mfma_f32_16x16x32_bf16(
                    a[i], bfr[j], acc[i][j], 0, 0, 0);
        __syncthreads();
    }

    float x[2][4][4];
#pragma unroll
    for (int i = 0; i < 2; i++) {
#pragma unroll
        for (int j = 0; j < 4; j++) {
            int col = wn * 64 + j * 16 + l15;
            float bv = bias[col];
#pragma unroll
            for (int r = 0; r < 4; r++) {
                int row = bm + wm * 32 + i * 16 + quad * 4 + r;
                x[i][j][r] = qv[(size_t)row * CDIM + col] + acc[i][j][r] + bv;
            }
        }
    }
#pragma unroll
    for (int i = 0; i < 2; i++) {
#pragma unroll
        for (int r = 0; r < 4; r++) {
            float s = x[i][0][r] + x[i][1][r] + x[i][2][r] + x[i][3][r];
            float sq = x[i][0][r] * x[i][0][r] + x[i][1][r] * x[i][1][r] +
                       x[i][2][r] * x[i][2][r] + x[i][3][r] * x[i][3][r];
#pragma unroll
            for (int m = 1; m < 16; m <<= 1) {
                s += __shfl_xor(s, m);
                sq += __shfl_xor(sq, m);
            }
            if (l15 == 0) {
                int rl = wm * 32 + i * 16 + quad * 4 + r;
                red[0][rl][wn] = s;
                red[1][rl][wn] = sq;
            }
        }
    }
    __syncthreads();
    if (tid < 64) {
        float s = red[0][tid][0] + red[0][tid][1] + red[0][tid][2] + red[0][tid][3];
        float sq = red[1][tid][0] + red[1][tid][1] + red[1][tid][2] + red[1][tid][3];
        float mean = s * (1.f / CDIM);
        float var = fmaxf(sq * (1.f / CDIM) - mean * mean, 0.f);
        stats[0][tid] = mean;
        stats[1][tid] = rsqrtf(var + 1e-5f);
    }
    __syncthreads();
#pragma unroll
    for (int i = 0; i < 2; i++) {
#pragma unroll
        for (int j = 0; j < 4; j++) {
            int col = wn * 64 + j * 16 + l15;
            float gc = g[col], bc = b[col];
#pragma unroll
            for (int r = 0; r < 4; r++) {
                int rl = wm * 32 + i * 16 + quad * 4 + r;
                int row = bm + rl;
                float y = (x[i][j][r] - stats[0][rl]) * stats[1][rl] * gc + bc;
                qv[(size_t)row * CDIM + col] = y;
                qb[(size_t)row * CDIM + col] = __float2bfloat16(y);
            }
        }
    }
}

// ---------------------------------------------------------------------------
// Weight convert+transpose helpers
// ---------------------------------------------------------------------------
__global__ void wt_cvt4_kernel(const float* __restrict__ w0, const float* __restrict__ w1,
                               const float* __restrict__ w2, const float* __restrict__ w3,
                               bf16* __restrict__ o0, bf16* __restrict__ o1,
                               bf16* __restrict__ o2, bf16* __restrict__ o3)
{
    __shared__ float tile[32][33];
    int z = blockIdx.z;
    int which = z & 3, l = z >> 2;
    const float* W; bf16* WT;
    switch (which) {
        case 0: W = w0; WT = o0; break;
        case 1: W = w1; WT = o1; break;
        case 2: W = w2; WT = o2; break;
        default: W = w3; WT = o3; break;
    }
    const float* Wl = W + (size_t)l * 65536;
    bf16* WTl = WT + (size_t)l * 65536;
    int k0 = blockIdx.x * 32, n0 = blockIdx.y * 32;
    int tx = threadIdx.x, ty = threadIdx.y;
    for (int i = 0; i < 32; i += 8)
        tile[ty + i][tx] = Wl[(size_t)(k0 + ty + i) * 256 + n0 + tx];
    __syncthreads();
    for (int i = 0; i < 32; i += 8)
        WTl[(size_t)(n0 + ty + i) * 256 + k0 + tx] = __float2bfloat16(tile[tx][ty + i]);
}

__global__ void wt_cvt_kernel(const float* __restrict__ W, bf16* __restrict__ WT,
                              int K, int N)
{
    __shared__ float tile[32][33];
    int l = blockIdx.z;
    const float* Wl = W + (size_t)l * K * N;
    bf16* WTl = WT + (size_t)l * K * N;
    int k0 = blockIdx.x * 32, n0 = blockIdx.y * 32;
    int tx = threadIdx.x, ty = threadIdx.y;
    for (int i = 0; i < 32; i += 8)
        tile[ty + i][tx] = Wl[(size_t)(k0 + ty + i) * N + n0 + tx];
    __syncthreads();
    for (int i = 0; i < 32; i += 8)
        WTl[(size_t)(n0 + ty + i) * K + k0 + tx] = __float2bfloat16(tile[tx][ty + i]);
}

__global__ void pack_offattn_kernel(const float* __restrict__ ow, const float* __restrict__ ob,
                                    const float* __restrict__ aw, const float* __restrict__ ab,
                                    bf16* __restrict__ WT, float* __restrict__ BIAS)
{
    int l = blockIdx.y;
    int n = blockIdx.x;
    int k = threadIdx.x;
    float v = 0.f;
    if (n < 64)      v = ow[((size_t)l * 256 + k) * 64 + n];
    else if (n < 96) v = aw[((size_t)l * 256 + k) * 32 + (n - 64)];
    WT[((size_t)l * 128 + n) * 256 + k] = __float2bfloat16(v);
    if (k == 0) {
        float bv = 0.f;
        if (n < 64)      bv = ob[l * 64 + n];
        else if (n < 96) bv = ab[l * 32 + (n - 64)];
        BIAS[l * 128 + n] = bv;
    }
}

__global__ void feats_cvt_kernel(const float* __restrict__ in, bf16* __restrict__ outT)
{
    __shared__ float tile[32][33];
    int c = blockIdx.z;
    int r0 = blockIdx.x * 32, ch0 = blockIdx.y * 32;
    int tx = threadIdx.x, ty = threadIdx.y;
    for (int i = 0; i < 32; i += 8) {
        int r = r0 + tx, ch = ch0 + ty + i;
        tile[ty + i][tx] = (r < HWF) ? in[((size_t)c * CDIM + ch) * HWF + r] : 0.f;
    }
    __syncthreads();
    for (int i = 0; i < 32; i += 8) {
        int r = r0 + ty + i, ch = ch0 + tx;
        if (r < HWF)
            outT[((size_t)c * HWF + r) * CDIM + ch] = __float2bfloat16(tile[tx][ty + i]);
    }
}

__global__ __launch_bounds__(256) void cvt_bf16_kernel(const float* __restrict__ in,
                                                       bf16* __restrict__ out, int n)
{
    int i = blockIdx.x * 256 + threadIdx.x;
    if (i < n) out[i] = __float2bfloat16(in[i]);
}

__global__ __launch_bounds__(256) void init_q_kernel(const float* __restrict__ in,
                                                     float* __restrict__ q,
                                                     bf16* __restrict__ qb, int n)
{
    int i = blockIdx.x * 256 + threadIdx.x;
    if (i < n) { float v = in[i]; q[i] = v; qb[i] = __float2bfloat16(v); }
}

// ---------------------------------------------------------------------------
__global__ void invert4_kernel(const float* __restrict__ extr, float* __restrict__ ego)
{
    int c = threadIdx.x;
    if (c >= NCAM) return;
    float a[4][8];
    for (int i = 0; i < 4; i++)
        for (int j = 0; j < 4; j++) {
            a[i][j] = extr[c * 16 + i * 4 + j];
            a[i][4 + j] = (i == j) ? 1.f : 0.f;
        }
    for (int col = 0; col < 4; col++) {
        int piv = col;
        float best = fabsf(a[col][col]);
        for (int r = col + 1; r < 4; r++) {
            float v = fabsf(a[r][col]);
            if (v > best) { best = v; piv = r; }
        }
        if (piv != col)
            for (int j = 0; j < 8; j++) {
                float t = a[col][j]; a[col][j] = a[piv][j]; a[piv][j] = t;
            }
        float inv = 1.f / a[col][col];
        for (int j = 0; j < 8; j++) a[col][j] *= inv;
        for (int r = 0; r < 4; r++) {
            if (r == col) continue;
            float f = a[r][col];
            for (int j = 0; j < 8; j++) a[r][j] -= f * a[col][j];
        }
    }
    for (int i = 0; i < 4; i++)
        for (int j = 0; j < 4; j++)
            ego[c * 16 + i * 4 + j] = a[i][4 + j];
}

__global__ __launch_bounds__(256) void refcam_kernel(
    const float* __restrict__ ego, const float* __restrict__ intr,
    float* __restrict__ refcam, float* __restrict__ validb)
{
    int t = blockIdx.x * 256 + threadIdx.x;
    if (t >= NCAM * NQ * NPOINTS) return;
    int p = t & 3;
    int n = (t >> 2) & (NQ - 1);
    int c = t >> 16;

    float gx = ((n & 127) + 0.5f) / 128.0f;
    float gy = ((n >> 7) + 0.5f) / 128.0f;
    float xm = -51.2f + gx * 102.4f;
    float ym = -51.2f + gy * 102.4f;
    float zm = -5.0f + (p + 0.5f) * 2.0f;

    const float* E = ego + c * 16;
    float pc[3];
#pragma unroll
    for (int i = 0; i < 3; i++)
        pc[i] = E[i * 4 + 0] * xm + E[i * 4 + 1] * ym + E[i * 4 + 2] * zm + E[i * 4 + 3];

    const float* I = intr + c * 9;
    float im[3];
#pragma unroll
    for (int i = 0; i < 3; i++)
        im[i] = I[i * 3 + 0] * pc[0] + I[i * 3 + 1] * pc[1] + I[i * 3 + 2] * pc[2];

    float z = im[2];
    float zc = fmaxf(z, 1e-5f);
    float un = im[0] / (zc * (float)WF);
    float vn = im[1] / (zc * (float)HF);
    float val = (z > 1e-5f && un >= 0.f && un <= 1.f && vn >= 0.f && vn <= 1.f) ? 1.f : 0.f;

    size_t idx = ((size_t)c * NQ + n) * NPOINTS + p;
    refcam[idx * 2] = un;
    refcam[idx * 2 + 1] = vn;
    validb[idx] = val;
}

// ---------------------------------------------------------------------------
// TSA sampling: 4096 blocks (XCD-swizzled), 256 thr = 4 queries x 8 heads x
// 8 ch-quads. vgrid interleaved: one 16B load = 4ch prev + 4ch cur.
// ---------------------------------------------------------------------------
__global__ __launch_bounds__(256) void tsa_sample_kernel(
    const bf16* __restrict__ vgrid, const float* __restrict__ offlog,
    bf16* __restrict__ outA)
{
    int blk = blockIdx.x;
    int qq = (blk & 7) * 512 + (blk >> 3);
    int t = threadIdx.x;
    int n = qq * 4 + (t >> 6);
    int r = t & 63;
    int h = r >> 3;
    int dq = r & 7;
    int col = h * HD + dq * 4;
    int q8 = h * 8 + dq;                 // col >> 2

    const float* fl = offlog + (size_t)n * 128;
    const float* lg = fl + 64 + h * 4;
    float l0 = lg[0], l1 = lg[1], l2 = lg[2], l3 = lg[3];
    float mx = fmaxf(fmaxf(l0, l1), fmaxf(l2, l3));
    float e0 = expf(l0 - mx), e1 = expf(l1 - mx), e2 = expf(l2 - mx), e3 = expf(l3 - mx);
    float inv = 1.f / (e0 + e1 + e2 + e3);
    float w[4] = { e0 * inv, e1 * inv, e2 * inv, e3 * inv };

    const float* of = fl + h * 8;
    float rx = ((n & 127) + 0.5f) / 128.f;
    float ry = ((n >> 7) + 0.5f) / 128.f;

    float a0 = 0.f, a1 = 0.f, a2 = 0.f, a3 = 0.f;
#pragma unroll
    for (int p = 0; p < NPOINTS; p++) {
        float lx = rx + of[p * 2] * (1.f / 128.f);
        float ly = ry + of[p * 2 + 1] * (1.f / 128.f);
        float ix = lx * 128.f - 0.5f;
        float iy = ly * 128.f - 0.5f;
        float xf = floorf(ix), yf = floorf(iy);
        float fx = ix - xf, fy = iy - yf;
        int x0 = (int)xf, y0 = (int)yf;
#pragma unroll
        for (int dy = 0; dy < 2; dy++) {
            int yi = y0 + dy;
            if (yi < 0 || yi >= 128) continue;
            float wy = dy ? fy : 1.f - fy;
#pragma unroll
            for (int dx = 0; dx < 2; dx++) {
                int xi = x0 + dx;
                if (xi < 0 || xi >= 128) continue;
                float wgt = w[p] * wy * (dx ? fx : 1.f - fx);
                size_t idx = ((size_t)(yi * 128 + xi) * 64 + q8) * 8;
                uint4 v = *(const uint4*)(vgrid + idx);   // prev(4ch) | cur(4ch)
                a0 += wgt * (bfLo(v.x) + bfLo(v.z));
                a1 += wgt * (bfHi(v.x) + bfHi(v.z));
                a2 += wgt * (bfLo(v.y) + bfLo(v.w));
                a3 += wgt * (bfHi(v.y) + bfHi(v.w));
            }
        }
    }
    union { bf16 b[4]; uint2 u; } pk;
    pk.b[0] = __float2bfloat16(0.5f * a0);
    pk.b[1] = __float2bfloat16(0.5f * a1);
    pk.b[2] = __float2bfloat16(0.5f * a2);
    pk.b[3] = __float2bfloat16(0.5f * a3);
    *(uint2*)(outA + (size_t)n * CDIM + col) = pk.u;
}

// ---------------------------------------------------------------------------
// SCA sampling: 2048 blocks (XCD-swizzled), 256 thr = 8 queries x 8 heads x
// 4 ch-octs; 16B loads (8 channels/thread). cnt computed inline.
// ---------------------------------------------------------------------------
__global__ __launch_bounds__(256) void sca_sample_kernel(
    const bf16* __restrict__ vimg, const float* __restrict__ offlog,
    const float* __restrict__ refcam, const float* __restrict__ validb,
    bf16* __restrict__ outA)
{
    int blk = blockIdx.x;
    int qo = (blk & 7) * 256 + (blk >> 3);
    int t = threadIdx.x;
    int n = qo * 8 + (t >> 5);
    int r = t & 31;
    int h = r >> 2;
    int d8 = r & 3;
    int col = h * HD + d8 * 8;

    const float* fl = offlog + (size_t)n * 128;
    const float* lg = fl + 64 + h * 4;
    float l0 = lg[0], l1 = lg[1], l2 = lg[2], l3 = lg[3];
    float mx = fmaxf(fmaxf(l0, l1), fmaxf(l2, l3));
    float e0 = expf(l0 - mx), e1 = expf(l1 - mx), e2 = expf(l2 - mx), e3 = expf(l3 - mx);
    float inv = 1.f / (e0 + e1 + e2 + e3);
    float w[4] = { e0 * inv, e1 * inv, e2 * inv, e3 * inv };

    const float* of = fl + h * 8;
    float ox[4], oy[4];
#pragma unroll
    for (int p = 0; p < NPOINTS; p++) {
        ox[p] = of[p * 2] * (1.f / (float)WF);
        oy[p] = of[p * 2 + 1] * (1.f / (float)HF);
    }

    float a0 = 0.f, a1 = 0.f, a2 = 0.f, a3 = 0.f;
    float a4 = 0.f, a5 = 0.f, a6 = 0.f, a7 = 0.f;
    float vsum = 0.f;
    for (int c = 0; c < NCAM; c++) {
        const bf16* vb = vimg + (size_t)c * HWF * CDIM;
        size_t base = ((size_t)c * NQ + n) * NPOINTS;
#pragma unroll
        for (int p = 0; p < NPOINTS; p++) {
            float vl = validb[base + p];
            vsum += vl;
            if (vl == 0.f) continue;          // uniform across the wave (same n)
            float lx = refcam[(base + p) * 2] + ox[p];
            float ly = refcam[(base + p) * 2 + 1] + oy[p];
            float ix = lx * (float)WF - 0.5f;
            float iy = ly * (float)HF - 0.5f;
            float xf = floorf(ix), yf = floorf(iy);
            float fx = ix - xf, fy = iy - yf;
            int x0 = (int)xf, y0 = (int)yf;
            float wp_ = w[p] * vl;
#pragma unroll
            for (int dy = 0; dy < 2; dy++) {
                int yi = y0 + dy;
                if (yi < 0 || yi >= HF) continue;
                float wy = dy ? fy : 1.f - fy;
#pragma unroll
                for (int dx = 0; dx < 2; dx++) {
                    int xi = x0 + dx;
                    if (xi < 0 || xi >= WF) continue;
                    float wgt = wp_ * wy * (dx ? fx : 1.f - fx);
                    uint4 u = *(const uint4*)(vb + (size_t)(yi * WF + xi) * CDIM + col);
                    a0 += wgt * bfLo(u.x);
                    a1 += wgt * bfHi(u.x);
                    a2 += wgt * bfLo(u.y);
                    a3 += wgt * bfHi(u.y);
                    a4 += wgt * bfLo(u.z);
                    a5 += wgt * bfHi(u.z);
                    a6 += wgt * bfLo(u.w);
                    a7 += wgt * bfHi(u.w);
                }
            }
        }
    }
    float ic = 1.f / fmaxf(vsum, 1.f);
    union { bf16 b[8]; uint4 u; } pk;
    pk.b[0] = __float2bfloat16(a0 * ic);
    pk.b[1] = __float2bfloat16(a1 * ic);
    pk.b[2] = __float2bfloat16(a2 * ic);
    pk.b[3] = __float2bfloat16(a3 * ic);
    pk.b[4] = __float2bfloat16(a4 * ic);
    pk.b[5] = __float2bfloat16(a5 * ic);
    pk.b[6] = __float2bfloat16(a6 * ic);
    pk.b[7] = __float2bfloat16(a7 * ic);
    *(uint4*)(outA + (size_t)n * CDIM + col) = pk.u;
}

// ---------------------------------------------------------------------------
__global__ void out_transpose_kernel(const float* __restrict__ q, float* __restrict__ out)
{
    __shared__ float tile[32][33];
    int n0 = blockIdx.x * 32;
    int c0 = blockIdx.y * 32;
    int tx = threadIdx.x, ty = threadIdx.y;
    for (int i = 0; i < 32; i += 8)
        tile[ty + i][tx] = q[(size_t)(n0 + ty + i) * CDIM + c0 + tx];
    __syncthreads();
    for (int i = 0; i < 32; i += 8)
        out[(size_t)(c0 + ty + i) * NQ + n0 + tx] = tile[tx][ty + i];
}

// ---------------------------------------------------------------------------
// Host launcher
// ---------------------------------------------------------------------------
extern "C" void kernel_launch(void* const* d_in, const int* in_sizes, int n_in,
                              void* d_out, int out_size, void* d_ws, size_t ws_size,
                              hipStream_t stream)
{
    const float* image_feats = (const float*)d_in[0];
    const float* intr        = (const float*)d_in[1];
    const float* extr        = (const float*)d_in[2];
    const float* prev_bev    = (const float*)d_in[3];
    const float* bev_embed   = (const float*)d_in[4];
    const float* tsa_vw = (const float*)d_in[5];
    const float* tsa_vb = (const float*)d_in[6];
    const float* tsa_ow = (const float*)d_in[7];
    const float* tsa_ob = (const float*)d_in[8];
    const float* tsa_aw = (const float*)d_in[9];
    const float* tsa_ab = (const float*)d_in[10];
    const float* tsa_pw = (const float*)d_in[11];
    const float* tsa_pb = (const float*)d_in[12];
    const float* sca_vw = (const float*)d_in[13];
    const float* sca_vb = (const float*)d_in[14];
    const float* sca_ow = (const float*)d_in[15];
    const float* sca_ob = (const float*)d_in[16];
    const float* sca_aw = (const float*)d_in[17];
    const float* sca_ab = (const float*)d_in[18];
    const float* sca_pw = (const float*)d_in[19];
    const float* sca_pb = (const float*)d_in[20];
    const float* ffn_w1 = (const float*)d_in[21];
    const float* ffn_b1 = (const float*)d_in[22];
    const float* ffn_w2 = (const float*)d_in[23];
    const float* ffn_b2 = (const float*)d_in[24];
    const float* ln1_g  = (const float*)d_in[25];
    const float* ln1_b  = (const float*)d_in[26];
    const float* ln2_g  = (const float*)d_in[27];
    const float* ln2_b  = (const float*)d_in[28];
    const float* ln3_g  = (const float*)d_in[29];
    const float* ln3_b  = (const float*)d_in[30];

    // --- workspace layout ---
    char* wp = (char*)d_ws;
    auto alloc = [&](size_t bytes) -> void* {
        void* r = (void*)wp;
        wp += (bytes + 255) & ~(size_t)255;
        return r;
    };
    float* q      = (float*)alloc((size_t)NQ * CDIM * 4);
    bf16*  prevbf = (bf16*) alloc((size_t)NQ * CDIM * 2);  // qb must follow contiguously
    bf16*  qb     = (bf16*) alloc((size_t)NQ * CDIM * 2);
    bf16*  attnA  = (bf16*) alloc((size_t)NQ * CDIM * 2);
    float* offlog = (float*)alloc((size_t)NQ * 128 * 4);
    float* refcam = (float*)alloc((size_t)NCAM * NQ * NPOINTS * 2 * 4);
    float* validb = (float*)alloc((size_t)NCAM * NQ * NPOINTS * 4);
    float* ego    = (float*)alloc(128 * 4);
    bf16*  featsT = (bf16*) alloc((size_t)NFEAT * CDIM * 2);
    bf16*  vwT  = (bf16*)alloc((size_t)NLAYERS * 65536 * 2);
    bf16*  pwT  = (bf16*)alloc((size_t)NLAYERS * 65536 * 2);
    bf16*  svwT = (bf16*)alloc((size_t)NLAYERS * 65536 * 2);
    bf16*  spwT = (bf16*)alloc((size_t)NLAYERS * 65536 * 2);
    bf16*  w1T  = (bf16*)alloc((size_t)NLAYERS * 131072 * 2);
    bf16*  w2T  = (bf16*)alloc((size_t)NLAYERS * 131072 * 2);
    bf16*  towT = (bf16*)alloc((size_t)NLAYERS * 32768 * 2);
    bf16*  sowT = (bf16*)alloc((size_t)NLAYERS * 32768 * 2);
    float* tobF = (float*)alloc((size_t)NLAYERS * 128 * 4);
    float* sobF = (float*)alloc((size_t)NLAYERS * 128 * 4);
    bf16*  big  = (bf16*) alloc((size_t)NFEAT * CDIM * 2);     // union

    bf16* vgrid  = big;                         // TSA: prev/cur interleaved
    bf16* vimg   = big;                         // SCA
    bf16* hidden = big;                         // FFN

    dim3 blk32(32, 8);

    // --- prep ---
    init_q_kernel<<<(NQ * CDIM + 255) / 256, 256, 0, stream>>>(bev_embed, q, qb, NQ * CDIM);
    cvt_bf16_kernel<<<(NQ * CDIM + 255) / 256, 256, 0, stream>>>(prev_bev, prevbf, NQ * CDIM);
    invert4_kernel<<<1, 64, 0, stream>>>(extr, ego);
    refcam_kernel<<<(NCAM * NQ * NPOINTS + 255) / 256, 256, 0, stream>>>(ego, intr, refcam, validb);
    {
        dim3 g((HWF + 31) / 32, CDIM / 32, NCAM);
        feats_cvt_kernel<<<g, blk32, 0, stream>>>(image_feats, featsT);
    }
    wt_cvt4_kernel<<<dim3(8, 8, 4 * NLAYERS), blk32, 0, stream>>>(
        tsa_vw, tsa_pw, sca_vw, sca_pw, vwT, pwT, svwT, spwT);
    wt_cvt_kernel<<<dim3(8, 16, NLAYERS), blk32, 0, stream>>>(ffn_w1, w1T, 256, 512);
    wt_cvt_kernel<<<dim3(16, 8, NLAYERS), blk32, 0, stream>>>(ffn_w2, w2T, 512, 256);
    pack_offattn_kernel<<<dim3(128, NLAYERS), 256, 0, stream>>>(tsa_ow, tsa_ob, tsa_aw, tsa_ab, towT, tobF);
    pack_offattn_kernel<<<dim3(128, NLAYERS), 256, 0, stream>>>(sca_ow, sca_ob, sca_aw, sca_ab, sowT, sobF);

    for (int l = 0; l < NLAYERS; l++) {
        // ---- TSA ----
        gemm_mfma<bf16, false, 1><<<dim3(2, 2 * NQ / 128), 256, 0, stream>>>(
            prevbf, vwT + (size_t)l * 65536, tsa_vb + l * CDIM,
            vgrid, 2 * NQ, CDIM, CDIM);           // [prevbf;qb] -> interleaved vgrid
        gemm_mfma<float, false, 0><<<dim3(1, NQ / 128), 256, 0, stream>>>(
            qb, towT + (size_t)l * 32768, tobF + l * 128, offlog, NQ, 128, CDIM);
        tsa_sample_kernel<<<NQ / 4, 256, 0, stream>>>(vgrid, offlog, attnA);
        gemm_ln<<<NQ / 64, 512, 0, stream>>>(
            attnA, pwT + (size_t)l * 65536, tsa_pb + l * CDIM,
            q, qb, ln1_g + l * CDIM, ln1_b + l * CDIM, CDIM);

        // ---- SCA ----
        gemm_mfma<bf16, false, 0><<<dim3(2, (NFEAT + 127) / 128), 256, 0, stream>>>(
            featsT, svwT + (size_t)l * 65536, sca_vb + l * CDIM, vimg, NFEAT, CDIM, CDIM);
        gemm_mfma<float, false, 0><<<dim3(1, NQ / 128), 256, 0, stream>>>(
            qb, sowT + (size_t)l * 32768, sobF + l * 128, offlog, NQ, 128, CDIM);
        sca_sample_kernel<<<NQ / 8, 256, 0, stream>>>(vimg, offlog, refcam, validb, attnA);
        gemm_ln<<<NQ / 64, 512, 0, stream>>>(
            attnA, spwT + (size_t)l * 65536, sca_pb + l * CDIM,
            q, qb, ln2_g + l * CDIM, ln2_b + l * CDIM, CDIM);

        // ---- FFN ----
        gemm_mfma<bf16, true, 0><<<dim3(4, NQ / 128), 256, 0, stream>>>(
            qb, w1T + (size_t)l * 131072, ffn_b1 + l * 512, hidden, NQ, 512, CDIM);
        gemm_ln<<<NQ / 64, 512, 0, stream>>>(
            hidden, w2T + (size_t)l * 131072, ffn_b2 + l * CDIM,
            q, qb, ln3_g + l * CDIM, ln3_b + l * CDIM, 512);
    }

    {
        dim3 g(NQ / 32, CDIM / 32);
        out_transpose_kernel<<<g, blk32, 0, stream>>>(q, (float*)d_out);
    }
}

// Round 8
// 1187.429 us; speedup vs baseline: 4.6182x; 1.0975x over previous
//
#include <hip/hip_runtime.h>
#include <hip/hip_bf16.h>
#include <math.h>

typedef __hip_bfloat16 bf16;

#define NQ      16384
#define CDIM    256
#define NHEADS  8
#define NPOINTS 4
#define NCAM    6
#define HF      58
#define WF      100
#define HWF     (HF*WF)        /* 5800 */
#define NFEAT   (NCAM*HWF)     /* 34800 */
#define HD      32
#define NLAYERS 6

typedef __attribute__((ext_vector_type(8))) short short8;
typedef __attribute__((ext_vector_type(4))) float floatx4;

__device__ __forceinline__ float toF(float x) { return x; }
__device__ __forceinline__ float toF(bf16 x) { return __bfloat162float(x); }
__device__ __forceinline__ void storeD(float* p, float v) { *p = v; }
__device__ __forceinline__ void storeD(bf16* p, float v) { *p = __float2bfloat16(v); }

__device__ __forceinline__ float bfLo(unsigned u) { return __uint_as_float(u << 16); }
__device__ __forceinline__ float bfHi(unsigned u) { return __uint_as_float(u & 0xffff0000u); }

// ---------------------------------------------------------------------------
// MFMA bf16 GEMM: D[M,N] = A[M,K] * BT[N,K]^T + bias[N]  (optional ReLU)
// 128x128 tile, BK=32, 4 waves 2x2. Batched over blockIdx.z via strides.
// ---------------------------------------------------------------------------
template <typename DT, bool RELU>
__global__ __launch_bounds__(256) void gemm_mfma(
    const bf16* __restrict__ A, const bf16* __restrict__ BT,
    const float* __restrict__ bias, DT* __restrict__ D,
    int M, int N, int K, size_t sB, size_t sBias, size_t sD)
{
    int z = blockIdx.z;
    BT += (size_t)z * sB;
    bias += (size_t)z * sBias;
    D += (size_t)z * sD;

    __shared__ bf16 As[128 * 40];
    __shared__ bf16 Bs[128 * 40];

    int tid = threadIdx.x;
    int lane = tid & 63, w = tid >> 6;
    int wm = w & 1, wn = w >> 1;
    int l15 = lane & 15, quad = lane >> 4;
    int bm = blockIdx.y * 128, bn = blockIdx.x * 128;

    floatx4 acc[4][4];
#pragma unroll
    for (int i = 0; i < 4; i++)
#pragma unroll
        for (int j = 0; j < 4; j++)
            acc[i][j] = (floatx4){0.f, 0.f, 0.f, 0.f};

    int srow = tid >> 2;
    int skc  = (tid & 3) * 8;

    for (int k0 = 0; k0 < K; k0 += 32) {
#pragma unroll
        for (int r = 0; r < 2; r++) {
            int row = srow + r * 64;
            int gm = bm + row;
            int4 va = {0, 0, 0, 0};
            if (gm < M) va = *(const int4*)(A + (size_t)gm * K + k0 + skc);
            *(int4*)(&As[row * 40 + skc]) = va;
            int gn = bn + row;   // N multiple of 128 -> always valid
            int4 vb = *(const int4*)(BT + (size_t)gn * K + k0 + skc);
            *(int4*)(&Bs[row * 40 + skc]) = vb;
        }
        __syncthreads();

        short8 a[4], b[4];
#pragma unroll
        for (int i = 0; i < 4; i++)
            a[i] = *(const short8*)(&As[(wm * 64 + i * 16 + l15) * 40 + quad * 8]);
#pragma unroll
        for (int j = 0; j < 4; j++)
            b[j] = *(const short8*)(&Bs[(wn * 64 + j * 16 + l15) * 40 + quad * 8]);
#pragma unroll
        for (int i = 0; i < 4; i++)
#pragma unroll
            for (int j = 0; j < 4; j++)
                acc[i][j] = __builtin_amdgcn_mfma_f32_16x16x32_bf16(
                    a[i], b[j], acc[i][j], 0, 0, 0);
        __syncthreads();
    }

#pragma unroll
    for (int i = 0; i < 4; i++) {
#pragma unroll
        for (int j = 0; j < 4; j++) {
            int col = bn + wn * 64 + j * 16 + l15;
            float bv = bias[col];
#pragma unroll
            for (int r = 0; r < 4; r++) {
                int row = bm + wm * 64 + i * 16 + quad * 4 + r;
                if (row < M) {
                    float v = acc[i][j][r] + bv;
                    if (RELU) v = fmaxf(v, 0.f);
                    storeD(&D[(size_t)row * N + col], v);
                }
            }
        }
    }
}

// ---------------------------------------------------------------------------
// TSA fused GEMM: A = [prevbf; qb] (M = 2*NQ), packed BT (384 rows x K=256):
//   rows 0..255  = tsa_vw^T  -> vgrid (prev/cur interleaved bf16)
//   rows 256..383 = [ow|aw|0] -> offlog (fp32, qb rows only)
// grid (3, 256): bn3 = 0,1 -> v columns; bn3 = 2 -> offlog (bm >= NQ only).
// ---------------------------------------------------------------------------
__global__ __launch_bounds__(256) void gemm_tsa(
    const bf16* __restrict__ A, const bf16* __restrict__ BT,
    const float* __restrict__ bias,
    bf16* __restrict__ vgrid, float* __restrict__ offlog)
{
    int bn3 = blockIdx.x;
    int bm = blockIdx.y * 128;
    if (bn3 == 2 && bm < NQ) return;
    int bn = bn3 * 128;

    __shared__ bf16 As[128 * 40];
    __shared__ bf16 Bs[128 * 40];

    int tid = threadIdx.x;
    int lane = tid & 63, w = tid >> 6;
    int wm = w & 1, wn = w >> 1;
    int l15 = lane & 15, quad = lane >> 4;

    floatx4 acc[4][4];
#pragma unroll
    for (int i = 0; i < 4; i++)
#pragma unroll
        for (int j = 0; j < 4; j++)
            acc[i][j] = (floatx4){0.f, 0.f, 0.f, 0.f};

    int srow = tid >> 2;
    int skc  = (tid & 3) * 8;

    for (int k0 = 0; k0 < 256; k0 += 32) {
#pragma unroll
        for (int r = 0; r < 2; r++) {
            int row = srow + r * 64;
            *(int4*)(&As[row * 40 + skc]) =
                *(const int4*)(A + (size_t)(bm + row) * 256 + k0 + skc);
            *(int4*)(&Bs[row * 40 + skc]) =
                *(const int4*)(BT + (size_t)(bn + row) * 256 + k0 + skc);
        }
        __syncthreads();

        short8 a[4], b[4];
#pragma unroll
        for (int i = 0; i < 4; i++)
            a[i] = *(const short8*)(&As[(wm * 64 + i * 16 + l15) * 40 + quad * 8]);
#pragma unroll
        for (int j = 0; j < 4; j++)
            b[j] = *(const short8*)(&Bs[(wn * 64 + j * 16 + l15) * 40 + quad * 8]);
#pragma unroll
        for (int i = 0; i < 4; i++)
#pragma unroll
            for (int j = 0; j < 4; j++)
                acc[i][j] = __builtin_amdgcn_mfma_f32_16x16x32_bf16(
                    a[i], b[j], acc[i][j], 0, 0, 0);
        __syncthreads();
    }

#pragma unroll
    for (int i = 0; i < 4; i++) {
#pragma unroll
        for (int j = 0; j < 4; j++) {
            int col = bn + wn * 64 + j * 16 + l15;
            float bv = bias[col];
#pragma unroll
            for (int r = 0; r < 4; r++) {
                int row = bm + wm * 64 + i * 16 + quad * 4 + r;
                float v = acc[i][j][r] + bv;
                if (bn3 < 2) {
                    int n = row & (NQ - 1);
                    int cur = row >= NQ;
                    size_t idx = ((size_t)n * 64 + (col >> 2)) * 8 + cur * 4 + (col & 3);
                    vgrid[idx] = __float2bfloat16(v);
                } else {
                    offlog[(size_t)(row - NQ) * 128 + (col - 256)] = v;
                }
            }
        }
    }
}

// ---------------------------------------------------------------------------
// Fused GEMM + residual + LayerNorm (N = 256, M mult of 64)
// ---------------------------------------------------------------------------
__global__ __launch_bounds__(512) void gemm_ln(
    const bf16* __restrict__ A, const bf16* __restrict__ BT,
    const float* __restrict__ bias,
    float* __restrict__ qv, bf16* __restrict__ qb,
    const float* __restrict__ g, const float* __restrict__ b,
    int K)
{
    __shared__ bf16 As[64 * 40];
    __shared__ bf16 Bs[256 * 40];
    __shared__ float red[2][64][4];
    __shared__ float stats[2][64];

    int tid = threadIdx.x;
    int lane = tid & 63, w = tid >> 6;
    int wm = w & 1, wn = w >> 1;              // 2 x 4
    int l15 = lane & 15, quad = lane >> 4;
    int bm = blockIdx.x * 64;

    floatx4 acc[2][4];
#pragma unroll
    for (int i = 0; i < 2; i++)
#pragma unroll
        for (int j = 0; j < 4; j++)
            acc[i][j] = (floatx4){0.f, 0.f, 0.f, 0.f};

    int srow = tid >> 2;
    int skc  = (tid & 3) * 8;

    for (int k0 = 0; k0 < K; k0 += 32) {
        *(int4*)(&Bs[srow * 40 + skc]) =
            *(const int4*)(BT + (size_t)srow * K + k0 + skc);
        *(int4*)(&Bs[(srow + 128) * 40 + skc]) =
            *(const int4*)(BT + (size_t)(srow + 128) * K + k0 + skc);
        if (tid < 256)
            *(int4*)(&As[(tid >> 2) * 40 + skc]) =
                *(const int4*)(A + (size_t)(bm + (tid >> 2)) * K + k0 + skc);
        __syncthreads();

        short8 a[2], bfr[4];
#pragma unroll
        for (int i = 0; i < 2; i++)
            a[i] = *(const short8*)(&As[(wm * 32 + i * 16 + l15) * 40 + quad * 8]);
#pragma unroll
        for (int j = 0; j < 4; j++)
            bfr[j] = *(const short8*)(&Bs[(wn * 64 + j * 16 + l15) * 40 + quad * 8]);
#pragma unroll
        for (int i = 0; i < 2; i++)
#pragma unroll
            for (int j = 0; j < 4; j++)
                acc[i][j] = __builtin_amdgcn_mfma_f32_16x16x32_bf16(
                    a[i], bfr[j], acc[i][j], 0, 0, 0);
        __syncthreads();
    }

    float x[2][4][4];
#pragma unroll
    for (int i = 0; i < 2; i++) {
#pragma unroll
        for (int j = 0; j < 4; j++) {
            int col = wn * 64 + j * 16 + l15;
            float bv = bias[col];
#pragma unroll
            for (int r = 0; r < 4; r++) {
                int row = bm + wm * 32 + i * 16 + quad * 4 + r;
                x[i][j][r] = qv[(size_t)row * CDIM + col] + acc[i][j][r] + bv;
            }
        }
    }
#pragma unroll
    for (int i = 0; i < 2; i++) {
#pragma unroll
        for (int r = 0; r < 4; r++) {
            float s = x[i][0][r] + x[i][1][r] + x[i][2][r] + x[i][3][r];
            float sq = x[i][0][r] * x[i][0][r] + x[i][1][r] * x[i][1][r] +
                       x[i][2][r] * x[i][2][r] + x[i][3][r] * x[i][3][r];
#pragma unroll
            for (int m = 1; m < 16; m <<= 1) {
                s += __shfl_xor(s, m);
                sq += __shfl_xor(sq, m);
            }
            if (l15 == 0) {
                int rl = wm * 32 + i * 16 + quad * 4 + r;
                red[0][rl][wn] = s;
                red[1][rl][wn] = sq;
            }
        }
    }
    __syncthreads();
    if (tid < 64) {
        float s = red[0][tid][0] + red[0][tid][1] + red[0][tid][2] + red[0][tid][3];
        float sq = red[1][tid][0] + red[1][tid][1] + red[1][tid][2] + red[1][tid][3];
        float mean = s * (1.f / CDIM);
        float var = fmaxf(sq * (1.f / CDIM) - mean * mean, 0.f);
        stats[0][tid] = mean;
        stats[1][tid] = rsqrtf(var + 1e-5f);
    }
    __syncthreads();
#pragma unroll
    for (int i = 0; i < 2; i++) {
#pragma unroll
        for (int j = 0; j < 4; j++) {
            int col = wn * 64 + j * 16 + l15;
            float gc = g[col], bc = b[col];
#pragma unroll
            for (int r = 0; r < 4; r++) {
                int rl = wm * 32 + i * 16 + quad * 4 + r;
                int row = bm + rl;
                float y = (x[i][j][r] - stats[0][rl]) * stats[1][rl] * gc + bc;
                qv[(size_t)row * CDIM + col] = y;
                qb[(size_t)row * CDIM + col] = __float2bfloat16(y);
            }
        }
    }
}

// ---------------------------------------------------------------------------
// Weight convert+transpose, batched over layers (blockIdx.z)
// ---------------------------------------------------------------------------
__global__ void wt_cvt_kernel(const float* __restrict__ W, bf16* __restrict__ WT,
                              int K, int N)
{
    __shared__ float tile[32][33];
    int l = blockIdx.z;
    const float* Wl = W + (size_t)l * K * N;
    bf16* WTl = WT + (size_t)l * K * N;
    int k0 = blockIdx.x * 32, n0 = blockIdx.y * 32;
    int tx = threadIdx.x, ty = threadIdx.y;
    for (int i = 0; i < 32; i += 8)
        tile[ty + i][tx] = Wl[(size_t)(k0 + ty + i) * N + n0 + tx];
    __syncthreads();
    for (int i = 0; i < 32; i += 8)
        WTl[(size_t)(n0 + ty + i) * K + k0 + tx] = __float2bfloat16(tile[tx][ty + i]);
}

// Pack TSA fused weights: 384 rows = [vw^T(256) | ow(64) | aw(32) | 0(32)]
__global__ void pack_tsa_kernel(const float* __restrict__ vw, const float* __restrict__ vb,
                                const float* __restrict__ ow, const float* __restrict__ ob,
                                const float* __restrict__ aw, const float* __restrict__ ab,
                                bf16* __restrict__ WT, float* __restrict__ BIAS)
{
    int n = blockIdx.x;      // 0..383
    int l = blockIdx.y;
    int k = threadIdx.x;     // 0..255
    float v = 0.f;
    if (n < 256)      v = vw[((size_t)l * 256 + k) * 256 + n];
    else if (n < 320) v = ow[((size_t)l * 256 + k) * 64 + (n - 256)];
    else if (n < 352) v = aw[((size_t)l * 256 + k) * 32 + (n - 320)];
    WT[((size_t)l * 384 + n) * 256 + k] = __float2bfloat16(v);
    if (k == 0) {
        float bv = 0.f;
        if (n < 256)      bv = vb[l * 256 + n];
        else if (n < 320) bv = ob[l * 64 + (n - 256)];
        else if (n < 352) bv = ab[l * 32 + (n - 320)];
        BIAS[l * 384 + n] = bv;
    }
}

__global__ void pack_offattn_kernel(const float* __restrict__ ow, const float* __restrict__ ob,
                                    const float* __restrict__ aw, const float* __restrict__ ab,
                                    bf16* __restrict__ WT, float* __restrict__ BIAS)
{
    int l = blockIdx.y;
    int n = blockIdx.x;
    int k = threadIdx.x;
    float v = 0.f;
    if (n < 64)      v = ow[((size_t)l * 256 + k) * 64 + n];
    else if (n < 96) v = aw[((size_t)l * 256 + k) * 32 + (n - 64)];
    WT[((size_t)l * 128 + n) * 256 + k] = __float2bfloat16(v);
    if (k == 0) {
        float bv = 0.f;
        if (n < 64)      bv = ob[l * 64 + n];
        else if (n < 96) bv = ab[l * 32 + (n - 64)];
        BIAS[l * 128 + n] = bv;
    }
}

__global__ void feats_cvt_kernel(const float* __restrict__ in, bf16* __restrict__ outT)
{
    __shared__ float tile[32][33];
    int c = blockIdx.z;
    int r0 = blockIdx.x * 32, ch0 = blockIdx.y * 32;
    int tx = threadIdx.x, ty = threadIdx.y;
    for (int i = 0; i < 32; i += 8) {
        int r = r0 + tx, ch = ch0 + ty + i;
        tile[ty + i][tx] = (r < HWF) ? in[((size_t)c * CDIM + ch) * HWF + r] : 0.f;
    }
    __syncthreads();
    for (int i = 0; i < 32; i += 8) {
        int r = r0 + ty + i, ch = ch0 + tx;
        if (r < HWF)
            outT[((size_t)c * HWF + r) * CDIM + ch] = __float2bfloat16(tile[tx][ty + i]);
    }
}

__global__ __launch_bounds__(256) void cvt_bf16_kernel(const float* __restrict__ in,
                                                       bf16* __restrict__ out, int n)
{
    int i = blockIdx.x * 256 + threadIdx.x;
    if (i < n) out[i] = __float2bfloat16(in[i]);
}

__global__ __launch_bounds__(256) void init_q_kernel(const float* __restrict__ in,
                                                     float* __restrict__ q,
                                                     bf16* __restrict__ qb, int n)
{
    int i = blockIdx.x * 256 + threadIdx.x;
    if (i < n) { float v = in[i]; q[i] = v; qb[i] = __float2bfloat16(v); }
}

// ---------------------------------------------------------------------------
__global__ void invert4_kernel(const float* __restrict__ extr, float* __restrict__ ego)
{
    int c = threadIdx.x;
    if (c >= NCAM) return;
    float a[4][8];
    for (int i = 0; i < 4; i++)
        for (int j = 0; j < 4; j++) {
            a[i][j] = extr[c * 16 + i * 4 + j];
            a[i][4 + j] = (i == j) ? 1.f : 0.f;
        }
    for (int col = 0; col < 4; col++) {
        int piv = col;
        float best = fabsf(a[col][col]);
        for (int r = col + 1; r < 4; r++) {
            float v = fabsf(a[r][col]);
            if (v > best) { best = v; piv = r; }
        }
        if (piv != col)
            for (int j = 0; j < 8; j++) {
                float t = a[col][j]; a[col][j] = a[piv][j]; a[piv][j] = t;
            }
        float inv = 1.f / a[col][col];
        for (int j = 0; j < 8; j++) a[col][j] *= inv;
        for (int r = 0; r < 4; r++) {
            if (r == col) continue;
            float f = a[r][col];
            for (int j = 0; j < 8; j++) a[r][j] -= f * a[col][j];
        }
    }
    for (int i = 0; i < 4; i++)
        for (int j = 0; j < 4; j++)
            ego[c * 16 + i * 4 + j] = a[i][4 + j];
}

__global__ __launch_bounds__(256) void refcam_kernel(
    const float* __restrict__ ego, const float* __restrict__ intr,
    float* __restrict__ refcam, float* __restrict__ validb)
{
    int t = blockIdx.x * 256 + threadIdx.x;
    if (t >= NCAM * NQ * NPOINTS) return;
    int p = t & 3;
    int n = (t >> 2) & (NQ - 1);
    int c = t >> 16;

    float gx = ((n & 127) + 0.5f) / 128.0f;
    float gy = ((n >> 7) + 0.5f) / 128.0f;
    float xm = -51.2f + gx * 102.4f;
    float ym = -51.2f + gy * 102.4f;
    float zm = -5.0f + (p + 0.5f) * 2.0f;

    const float* E = ego + c * 16;
    float pc[3];
#pragma unroll
    for (int i = 0; i < 3; i++)
        pc[i] = E[i * 4 + 0] * xm + E[i * 4 + 1] * ym + E[i * 4 + 2] * zm + E[i * 4 + 3];

    const float* I = intr + c * 9;
    float im[3];
#pragma unroll
    for (int i = 0; i < 3; i++)
        im[i] = I[i * 3 + 0] * pc[0] + I[i * 3 + 1] * pc[1] + I[i * 3 + 2] * pc[2];

    float z = im[2];
    float zc = fmaxf(z, 1e-5f);
    float un = im[0] / (zc * (float)WF);
    float vn = im[1] / (zc * (float)HF);
    float val = (z > 1e-5f && un >= 0.f && un <= 1.f && vn >= 0.f && vn <= 1.f) ? 1.f : 0.f;

    size_t idx = ((size_t)c * NQ + n) * NPOINTS + p;
    refcam[idx * 2] = un;
    refcam[idx * 2 + 1] = vn;
    validb[idx] = val;
}

// ---------------------------------------------------------------------------
// TSA sampling: 4096 blocks (XCD-swizzled), 256 thr = 4 queries x 8 heads x
// 8 ch-quads. vgrid interleaved: one 16B load = 4ch prev + 4ch cur.
// ---------------------------------------------------------------------------
__global__ __launch_bounds__(256) void tsa_sample_kernel(
    const bf16* __restrict__ vgrid, const float* __restrict__ offlog,
    bf16* __restrict__ outA)
{
    int blk = blockIdx.x;
    int qq = (blk & 7) * 512 + (blk >> 3);
    int t = threadIdx.x;
    int n = qq * 4 + (t >> 6);
    int r = t & 63;
    int h = r >> 3;
    int dq = r & 7;
    int col = h * HD + dq * 4;
    int q8 = h * 8 + dq;                 // col >> 2

    const float* fl = offlog + (size_t)n * 128;
    const float* lg = fl + 64 + h * 4;
    float l0 = lg[0], l1 = lg[1], l2 = lg[2], l3 = lg[3];
    float mx = fmaxf(fmaxf(l0, l1), fmaxf(l2, l3));
    float e0 = expf(l0 - mx), e1 = expf(l1 - mx), e2 = expf(l2 - mx), e3 = expf(l3 - mx);
    float inv = 1.f / (e0 + e1 + e2 + e3);
    float w[4] = { e0 * inv, e1 * inv, e2 * inv, e3 * inv };

    const float* of = fl + h * 8;
    float rx = ((n & 127) + 0.5f) / 128.f;
    float ry = ((n >> 7) + 0.5f) / 128.f;

    float a0 = 0.f, a1 = 0.f, a2 = 0.f, a3 = 0.f;
#pragma unroll
    for (int p = 0; p < NPOINTS; p++) {
        float lx = rx + of[p * 2] * (1.f / 128.f);
        float ly = ry + of[p * 2 + 1] * (1.f / 128.f);
        float ix = lx * 128.f - 0.5f;
        float iy = ly * 128.f - 0.5f;
        float xf = floorf(ix), yf = floorf(iy);
        float fx = ix - xf, fy = iy - yf;
        int x0 = (int)xf, y0 = (int)yf;
#pragma unroll
        for (int dy = 0; dy < 2; dy++) {
            int yi = y0 + dy;
            if (yi < 0 || yi >= 128) continue;
            float wy = dy ? fy : 1.f - fy;
#pragma unroll
            for (int dx = 0; dx < 2; dx++) {
                int xi = x0 + dx;
                if (xi < 0 || xi >= 128) continue;
                float wgt = w[p] * wy * (dx ? fx : 1.f - fx);
                size_t idx = ((size_t)(yi * 128 + xi) * 64 + q8) * 8;
                uint4 v = *(const uint4*)(vgrid + idx);   // prev(4ch) | cur(4ch)
                a0 += wgt * (bfLo(v.x) + bfLo(v.z));
                a1 += wgt * (bfHi(v.x) + bfHi(v.z));
                a2 += wgt * (bfLo(v.y) + bfLo(v.w));
                a3 += wgt * (bfHi(v.y) + bfHi(v.w));
            }
        }
    }
    union { bf16 b[4]; uint2 u; } pk;
    pk.b[0] = __float2bfloat16(0.5f * a0);
    pk.b[1] = __float2bfloat16(0.5f * a1);
    pk.b[2] = __float2bfloat16(0.5f * a2);
    pk.b[3] = __float2bfloat16(0.5f * a3);
    *(uint2*)(outA + (size_t)n * CDIM + col) = pk.u;
}

// ---------------------------------------------------------------------------
// SCA sampling: 2048 blocks (XCD-swizzled), 256 thr = 8 queries x 8 heads x
// 4 ch-octs; 16B loads. cnt computed inline.
// ---------------------------------------------------------------------------
__global__ __launch_bounds__(256) void sca_sample_kernel(
    const bf16* __restrict__ vimg, const float* __restrict__ offlog,
    const float* __restrict__ refcam, const float* __restrict__ validb,
    bf16* __restrict__ outA)
{
    int blk = blockIdx.x;
    int qo = (blk & 7) * 256 + (blk >> 3);
    int t = threadIdx.x;
    int n = qo * 8 + (t >> 5);
    int r = t & 31;
    int h = r >> 2;
    int d8 = r & 3;
    int col = h * HD + d8 * 8;

    const float* fl = offlog + (size_t)n * 128;
    const float* lg = fl + 64 + h * 4;
    float l0 = lg[0], l1 = lg[1], l2 = lg[2], l3 = lg[3];
    float mx = fmaxf(fmaxf(l0, l1), fmaxf(l2, l3));
    float e0 = expf(l0 - mx), e1 = expf(l1 - mx), e2 = expf(l2 - mx), e3 = expf(l3 - mx);
    float inv = 1.f / (e0 + e1 + e2 + e3);
    float w[4] = { e0 * inv, e1 * inv, e2 * inv, e3 * inv };

    const float* of = fl + h * 8;
    float ox[4], oy[4];
#pragma unroll
    for (int p = 0; p < NPOINTS; p++) {
        ox[p] = of[p * 2] * (1.f / (float)WF);
        oy[p] = of[p * 2 + 1] * (1.f / (float)HF);
    }

    float a0 = 0.f, a1 = 0.f, a2 = 0.f, a3 = 0.f;
    float a4 = 0.f, a5 = 0.f, a6 = 0.f, a7 = 0.f;
    float vsum = 0.f;
    for (int c = 0; c < NCAM; c++) {
        const bf16* vb = vimg + (size_t)c * HWF * CDIM;
        size_t base = ((size_t)c * NQ + n) * NPOINTS;
#pragma unroll
        for (int p = 0; p < NPOINTS; p++) {
            float vl = validb[base + p];
            vsum += vl;
            if (vl == 0.f) continue;
            float lx = refcam[(base + p) * 2] + ox[p];
            float ly = refcam[(base + p) * 2 + 1] + oy[p];
            float ix = lx * (float)WF - 0.5f;
            float iy = ly * (float)HF - 0.5f;
            float xf = floorf(ix), yf = floorf(iy);
            float fx = ix - xf, fy = iy - yf;
            int x0 = (int)xf, y0 = (int)yf;
            float wp_ = w[p] * vl;
#pragma unroll
            for (int dy = 0; dy < 2; dy++) {
                int yi = y0 + dy;
                if (yi < 0 || yi >= HF) continue;
                float wy = dy ? fy : 1.f - fy;
#pragma unroll
                for (int dx = 0; dx < 2; dx++) {
                    int xi = x0 + dx;
                    if (xi < 0 || xi >= WF) continue;
                    float wgt = wp_ * wy * (dx ? fx : 1.f - fx);
                    uint4 u = *(const uint4*)(vb + (size_t)(yi * WF + xi) * CDIM + col);
                    a0 += wgt * bfLo(u.x);
                    a1 += wgt * bfHi(u.x);
                    a2 += wgt * bfLo(u.y);
                    a3 += wgt * bfHi(u.y);
                    a4 += wgt * bfLo(u.z);
                    a5 += wgt * bfHi(u.z);
                    a6 += wgt * bfLo(u.w);
                    a7 += wgt * bfHi(u.w);
                }
            }
        }
    }
    float ic = 1.f / fmaxf(vsum, 1.f);
    union { bf16 b[8]; uint4 u; } pk;
    pk.b[0] = __float2bfloat16(a0 * ic);
    pk.b[1] = __float2bfloat16(a1 * ic);
    pk.b[2] = __float2bfloat16(a2 * ic);
    pk.b[3] = __float2bfloat16(a3 * ic);
    pk.b[4] = __float2bfloat16(a4 * ic);
    pk.b[5] = __float2bfloat16(a5 * ic);
    pk.b[6] = __float2bfloat16(a6 * ic);
    pk.b[7] = __float2bfloat16(a7 * ic);
    *(uint4*)(outA + (size_t)n * CDIM + col) = pk.u;
}

// ---------------------------------------------------------------------------
__global__ void out_transpose_kernel(const float* __restrict__ q, float* __restrict__ out)
{
    __shared__ float tile[32][33];
    int n0 = blockIdx.x * 32;
    int c0 = blockIdx.y * 32;
    int tx = threadIdx.x, ty = threadIdx.y;
    for (int i = 0; i < 32; i += 8)
        tile[ty + i][tx] = q[(size_t)(n0 + ty + i) * CDIM + c0 + tx];
    __syncthreads();
    for (int i = 0; i < 32; i += 8)
        out[(size_t)(c0 + ty + i) * NQ + n0 + tx] = tile[tx][ty + i];
}

// ---------------------------------------------------------------------------
// Host launcher
// ---------------------------------------------------------------------------
extern "C" void kernel_launch(void* const* d_in, const int* in_sizes, int n_in,
                              void* d_out, int out_size, void* d_ws, size_t ws_size,
                              hipStream_t stream)
{
    const float* image_feats = (const float*)d_in[0];
    const float* intr        = (const float*)d_in[1];
    const float* extr        = (const float*)d_in[2];
    const float* prev_bev    = (const float*)d_in[3];
    const float* bev_embed   = (const float*)d_in[4];
    const float* tsa_vw = (const float*)d_in[5];
    const float* tsa_vb = (const float*)d_in[6];
    const float* tsa_ow = (const float*)d_in[7];
    const float* tsa_ob = (const float*)d_in[8];
    const float* tsa_aw = (const float*)d_in[9];
    const float* tsa_ab = (const float*)d_in[10];
    const float* tsa_pw = (const float*)d_in[11];
    const float* tsa_pb = (const float*)d_in[12];
    const float* sca_vw = (const float*)d_in[13];
    const float* sca_vb = (const float*)d_in[14];
    const float* sca_ow = (const float*)d_in[15];
    const float* sca_ob = (const float*)d_in[16];
    const float* sca_aw = (const float*)d_in[17];
    const float* sca_ab = (const float*)d_in[18];
    const float* sca_pw = (const float*)d_in[19];
    const float* sca_pb = (const float*)d_in[20];
    const float* ffn_w1 = (const float*)d_in[21];
    const float* ffn_b1 = (const float*)d_in[22];
    const float* ffn_w2 = (const float*)d_in[23];
    const float* ffn_b2 = (const float*)d_in[24];
    const float* ln1_g  = (const float*)d_in[25];
    const float* ln1_b  = (const float*)d_in[26];
    const float* ln2_g  = (const float*)d_in[27];
    const float* ln2_b  = (const float*)d_in[28];
    const float* ln3_g  = (const float*)d_in[29];
    const float* ln3_b  = (const float*)d_in[30];

    // --- workspace layout (~205 MB of the 268 MB d_ws) ---
    char* wp = (char*)d_ws;
    auto alloc = [&](size_t bytes) -> void* {
        void* r = (void*)wp;
        wp += (bytes + 255) & ~(size_t)255;
        return r;
    };
    float* q      = (float*)alloc((size_t)NQ * CDIM * 4);
    bf16*  prevbf = (bf16*) alloc((size_t)NQ * CDIM * 2);  // qb must follow contiguously
    bf16*  qb     = (bf16*) alloc((size_t)NQ * CDIM * 2);
    bf16*  attnA  = (bf16*) alloc((size_t)NQ * CDIM * 2);
    float* offlog = (float*)alloc((size_t)NQ * 128 * 4);
    float* refcam = (float*)alloc((size_t)NCAM * NQ * NPOINTS * 2 * 4);
    float* validb = (float*)alloc((size_t)NCAM * NQ * NPOINTS * 4);
    float* ego    = (float*)alloc(128 * 4);
    bf16*  featsT = (bf16*) alloc((size_t)NFEAT * CDIM * 2);   // union w/ hidden
    bf16*  pwT  = (bf16*)alloc((size_t)NLAYERS * 65536 * 2);
    bf16*  svwT = (bf16*)alloc((size_t)NLAYERS * 65536 * 2);
    bf16*  spwT = (bf16*)alloc((size_t)NLAYERS * 65536 * 2);
    bf16*  w1T  = (bf16*)alloc((size_t)NLAYERS * 131072 * 2);
    bf16*  w2T  = (bf16*)alloc((size_t)NLAYERS * 131072 * 2);
    bf16*  ptwT = (bf16*)alloc((size_t)NLAYERS * 384 * 256 * 2);  // tsa fused [vw|ow|aw|0]
    float* ptb  = (float*)alloc((size_t)NLAYERS * 384 * 4);
    bf16*  sowT = (bf16*)alloc((size_t)NLAYERS * 32768 * 2);
    float* sobF = (float*)alloc((size_t)NLAYERS * 128 * 4);
    bf16*  vgrid = (bf16*)alloc((size_t)NQ * CDIM * 2 * 2);       // prev/cur interleaved
    bf16*  vimg6 = (bf16*)alloc((size_t)NLAYERS * NFEAT * CDIM * 2); // 106.9 MB

    bf16* hidden = featsT;   // featsT consumed in prep; hidden used in loop

    dim3 blk32(32, 8);

    // --- prep ---
    init_q_kernel<<<(NQ * CDIM + 255) / 256, 256, 0, stream>>>(bev_embed, q, qb, NQ * CDIM);
    cvt_bf16_kernel<<<(NQ * CDIM + 255) / 256, 256, 0, stream>>>(prev_bev, prevbf, NQ * CDIM);
    invert4_kernel<<<1, 64, 0, stream>>>(extr, ego);
    refcam_kernel<<<(NCAM * NQ * NPOINTS + 255) / 256, 256, 0, stream>>>(ego, intr, refcam, validb);
    {
        dim3 g((HWF + 31) / 32, CDIM / 32, NCAM);
        feats_cvt_kernel<<<g, blk32, 0, stream>>>(image_feats, featsT);
    }
    wt_cvt_kernel<<<dim3(8, 8,  NLAYERS), blk32, 0, stream>>>(tsa_pw, pwT,  256, 256);
    wt_cvt_kernel<<<dim3(8, 8,  NLAYERS), blk32, 0, stream>>>(sca_vw, svwT, 256, 256);
    wt_cvt_kernel<<<dim3(8, 8,  NLAYERS), blk32, 0, stream>>>(sca_pw, spwT, 256, 256);
    wt_cvt_kernel<<<dim3(8, 16, NLAYERS), blk32, 0, stream>>>(ffn_w1, w1T, 256, 512);
    wt_cvt_kernel<<<dim3(16, 8, NLAYERS), blk32, 0, stream>>>(ffn_w2, w2T, 512, 256);
    pack_tsa_kernel<<<dim3(384, NLAYERS), 256, 0, stream>>>(
        tsa_vw, tsa_vb, tsa_ow, tsa_ob, tsa_aw, tsa_ab, ptwT, ptb);
    pack_offattn_kernel<<<dim3(128, NLAYERS), 256, 0, stream>>>(
        sca_ow, sca_ob, sca_aw, sca_ab, sowT, sobF);
    // all 6 layers of vimg in one batched launch (input-only dependency)
    gemm_mfma<bf16, false><<<dim3(2, (NFEAT + 127) / 128, NLAYERS), 256, 0, stream>>>(
        featsT, svwT, sca_vb, vimg6, NFEAT, CDIM, CDIM,
        65536, 256, (size_t)NFEAT * CDIM);

    for (int l = 0; l < NLAYERS; l++) {
        // ---- TSA: fused [v(prev+cur) | offlog] GEMM ----
        gemm_tsa<<<dim3(3, 2 * NQ / 128), 256, 0, stream>>>(
            prevbf, ptwT + (size_t)l * 98304, ptb + l * 384, vgrid, offlog);
        tsa_sample_kernel<<<NQ / 4, 256, 0, stream>>>(vgrid, offlog, attnA);
        gemm_ln<<<NQ / 64, 512, 0, stream>>>(
            attnA, pwT + (size_t)l * 65536, tsa_pb + l * CDIM,
            q, qb, ln1_g + l * CDIM, ln1_b + l * CDIM, CDIM);

        // ---- SCA ----
        gemm_mfma<float, false><<<dim3(1, NQ / 128, 1), 256, 0, stream>>>(
            qb, sowT + (size_t)l * 32768, sobF + l * 128, offlog, NQ, 128, CDIM, 0, 0, 0);
        sca_sample_kernel<<<NQ / 8, 256, 0, stream>>>(
            vimg6 + (size_t)l * NFEAT * CDIM, offlog, refcam, validb, attnA);
        gemm_ln<<<NQ / 64, 512, 0, stream>>>(
            attnA, spwT + (size_t)l * 65536, sca_pb + l * CDIM,
            q, qb, ln2_g + l * CDIM, ln2_b + l * CDIM, CDIM);

        // ---- FFN ----
        gemm_mfma<bf16, true><<<dim3(4, NQ / 128, 1), 256, 0, stream>>>(
            qb, w1T + (size_t)l * 131072, ffn_b1 + l * 512, hidden, NQ, 512, CDIM, 0, 0, 0);
        gemm_ln<<<NQ / 64, 512, 0, stream>>>(
            hidden, w2T + (size_t)l * 131072, ffn_b2 + l * CDIM,
            q, qb, ln3_g + l * CDIM, ln3_b + l * CDIM, 512);
    }

    {
        dim3 g(NQ / 32, CDIM / 32);
        out_transpose_kernel<<<g, blk32, 0, stream>>>(q, (float*)d_out);
    }
}

// Round 9
// 1081.308 us; speedup vs baseline: 5.0715x; 1.0981x over previous
//
#include <hip/hip_runtime.h>
#include <hip/hip_bf16.h>
#include <math.h>

typedef __hip_bfloat16 bf16;

#define NQ      16384
#define CDIM    256
#define NHEADS  8
#define NPOINTS 4
#define NCAM    6
#define HF      58
#define WF      100
#define HWF     (HF*WF)        /* 5800 */
#define NFEAT   (NCAM*HWF)     /* 34800 */
#define HD      32
#define NLAYERS 6

typedef __attribute__((ext_vector_type(8))) short short8;
typedef __attribute__((ext_vector_type(4))) float floatx4;

__device__ __forceinline__ float toF(float x) { return x; }
__device__ __forceinline__ float toF(bf16 x) { return __bfloat162float(x); }
__device__ __forceinline__ void storeD(float* p, float v) { *p = v; }
__device__ __forceinline__ void storeD(bf16* p, float v) { *p = __float2bfloat16(v); }

__device__ __forceinline__ float bfLo(unsigned u) { return __uint_as_float(u << 16); }
__device__ __forceinline__ float bfHi(unsigned u) { return __uint_as_float(u & 0xffff0000u); }

// ---------------------------------------------------------------------------
// MFMA bf16 GEMM: D[M,N] = A[M,K] * BT[N,K]^T + bias[N]  (optional ReLU)
// 128x128 tile, BK=32, 4 waves 2x2. Batched over blockIdx.z via strides.
// STAGE=true (bf16 D): stage C tile in LDS, then coalesced 16B row stores.
// ---------------------------------------------------------------------------
template <typename DT, bool RELU, bool STAGE>
__global__ __launch_bounds__(256) void gemm_mfma(
    const bf16* __restrict__ A, const bf16* __restrict__ BT,
    const float* __restrict__ bias, DT* __restrict__ D,
    int M, int N, int K, size_t sB, size_t sBias, size_t sD)
{
    int z = blockIdx.z;
    BT += (size_t)z * sB;
    bias += (size_t)z * sBias;
    D += (size_t)z * sD;

    __shared__ bf16 smem[STAGE ? 128 * 136 : 128 * 80];
    bf16* As = smem;
    bf16* Bs = smem + 128 * 40;

    int tid = threadIdx.x;
    int lane = tid & 63, w = tid >> 6;
    int wm = w & 1, wn = w >> 1;
    int l15 = lane & 15, quad = lane >> 4;
    int bm = blockIdx.y * 128, bn = blockIdx.x * 128;

    floatx4 acc[4][4];
#pragma unroll
    for (int i = 0; i < 4; i++)
#pragma unroll
        for (int j = 0; j < 4; j++)
            acc[i][j] = (floatx4){0.f, 0.f, 0.f, 0.f};

    int srow = tid >> 2;
    int skc  = (tid & 3) * 8;

    for (int k0 = 0; k0 < K; k0 += 32) {
#pragma unroll
        for (int r = 0; r < 2; r++) {
            int row = srow + r * 64;
            int gm = bm + row;
            int4 va = {0, 0, 0, 0};
            if (gm < M) va = *(const int4*)(A + (size_t)gm * K + k0 + skc);
            *(int4*)(&As[row * 40 + skc]) = va;
            int gn = bn + row;   // N multiple of 128 -> always valid
            int4 vb = *(const int4*)(BT + (size_t)gn * K + k0 + skc);
            *(int4*)(&Bs[row * 40 + skc]) = vb;
        }
        __syncthreads();

        short8 a[4], b[4];
#pragma unroll
        for (int i = 0; i < 4; i++)
            a[i] = *(const short8*)(&As[(wm * 64 + i * 16 + l15) * 40 + quad * 8]);
#pragma unroll
        for (int j = 0; j < 4; j++)
            b[j] = *(const short8*)(&Bs[(wn * 64 + j * 16 + l15) * 40 + quad * 8]);
#pragma unroll
        for (int i = 0; i < 4; i++)
#pragma unroll
            for (int j = 0; j < 4; j++)
                acc[i][j] = __builtin_amdgcn_mfma_f32_16x16x32_bf16(
                    a[i], b[j], acc[i][j], 0, 0, 0);
        __syncthreads();
    }

    if (STAGE) {
        // scatter C into LDS (rows padded to 136 -> 272B, 16B-aligned)
#pragma unroll
        for (int i = 0; i < 4; i++) {
#pragma unroll
            for (int j = 0; j < 4; j++) {
                int col = wn * 64 + j * 16 + l15;
                float bv = bias[bn + col];
#pragma unroll
                for (int r = 0; r < 4; r++) {
                    int row = wm * 64 + i * 16 + quad * 4 + r;
                    float v = acc[i][j][r] + bv;
                    if (RELU) v = fmaxf(v, 0.f);
                    smem[row * 136 + col] = __float2bfloat16(v);
                }
            }
        }
        __syncthreads();
        // coalesced stores: 16 rows per pass, 16B per thread
        int lr0 = tid >> 4;
        int ck  = tid & 15;
#pragma unroll
        for (int pass = 0; pass < 8; pass++) {
            int lr = pass * 16 + lr0;
            int gm = bm + lr;
            if (gm < M) {
                uint4 v = *(const uint4*)(&smem[lr * 136 + ck * 8]);
                *(uint4*)((bf16*)D + (size_t)gm * N + bn + ck * 8) = v;
            }
        }
    } else {
#pragma unroll
        for (int i = 0; i < 4; i++) {
#pragma unroll
            for (int j = 0; j < 4; j++) {
                int col = bn + wn * 64 + j * 16 + l15;
                float bv = bias[col];
#pragma unroll
                for (int r = 0; r < 4; r++) {
                    int row = bm + wm * 64 + i * 16 + quad * 4 + r;
                    if (row < M) {
                        float v = acc[i][j][r] + bv;
                        if (RELU) v = fmaxf(v, 0.f);
                        storeD(&D[(size_t)row * N + col], v);
                    }
                }
            }
        }
    }
}

// ---------------------------------------------------------------------------
// TSA fused GEMM: A = [prevbf; qb] (M = 2*NQ), packed BT (384 rows x K=256):
//   rows 0..255  = tsa_vw^T  -> vgrid (prev/cur interleaved bf16)
//   rows 256..383 = [ow|aw|0] -> offlog (fp32, qb rows only)
// ---------------------------------------------------------------------------
__global__ __launch_bounds__(256) void gemm_tsa(
    const bf16* __restrict__ A, const bf16* __restrict__ BT,
    const float* __restrict__ bias,
    bf16* __restrict__ vgrid, float* __restrict__ offlog)
{
    int bn3 = blockIdx.x;
    int bm = blockIdx.y * 128;
    if (bn3 == 2 && bm < NQ) return;
    int bn = bn3 * 128;

    __shared__ bf16 As[128 * 40];
    __shared__ bf16 Bs[128 * 40];

    int tid = threadIdx.x;
    int lane = tid & 63, w = tid >> 6;
    int wm = w & 1, wn = w >> 1;
    int l15 = lane & 15, quad = lane >> 4;

    floatx4 acc[4][4];
#pragma unroll
    for (int i = 0; i < 4; i++)
#pragma unroll
        for (int j = 0; j < 4; j++)
            acc[i][j] = (floatx4){0.f, 0.f, 0.f, 0.f};

    int srow = tid >> 2;
    int skc  = (tid & 3) * 8;

    for (int k0 = 0; k0 < 256; k0 += 32) {
#pragma unroll
        for (int r = 0; r < 2; r++) {
            int row = srow + r * 64;
            *(int4*)(&As[row * 40 + skc]) =
                *(const int4*)(A + (size_t)(bm + row) * 256 + k0 + skc);
            *(int4*)(&Bs[row * 40 + skc]) =
                *(const int4*)(BT + (size_t)(bn + row) * 256 + k0 + skc);
        }
        __syncthreads();

        short8 a[4], b[4];
#pragma unroll
        for (int i = 0; i < 4; i++)
            a[i] = *(const short8*)(&As[(wm * 64 + i * 16 + l15) * 40 + quad * 8]);
#pragma unroll
        for (int j = 0; j < 4; j++)
            b[j] = *(const short8*)(&Bs[(wn * 64 + j * 16 + l15) * 40 + quad * 8]);
#pragma unroll
        for (int i = 0; i < 4; i++)
#pragma unroll
            for (int j = 0; j < 4; j++)
                acc[i][j] = __builtin_amdgcn_mfma_f32_16x16x32_bf16(
                    a[i], b[j], acc[i][j], 0, 0, 0);
        __syncthreads();
    }

#pragma unroll
    for (int i = 0; i < 4; i++) {
#pragma unroll
        for (int j = 0; j < 4; j++) {
            int col = bn + wn * 64 + j * 16 + l15;
            float bv = bias[col];
#pragma unroll
            for (int r = 0; r < 4; r++) {
                int row = bm + wm * 64 + i * 16 + quad * 4 + r;
                float v = acc[i][j][r] + bv;
                if (bn3 < 2) {
                    int n = row & (NQ - 1);
                    int cur = row >= NQ;
                    size_t idx = ((size_t)n * 64 + (col >> 2)) * 8 + cur * 4 + (col & 3);
                    vgrid[idx] = __float2bfloat16(v);
                } else {
                    offlog[(size_t)(row - NQ) * 128 + (col - 256)] = v;
                }
            }
        }
    }
}

// ---------------------------------------------------------------------------
// Fused GEMM + residual + LayerNorm (N = 256, M mult of 64):
//   t = A*BT^T + bias ; x = qb + t ; qb = bf16(LN(x)*g + b)
// Residual stream is bf16-only (qb).
// ---------------------------------------------------------------------------
__global__ __launch_bounds__(512) void gemm_ln(
    const bf16* __restrict__ A, const bf16* __restrict__ BT,
    const float* __restrict__ bias,
    bf16* __restrict__ qb,
    const float* __restrict__ g, const float* __restrict__ b,
    int K)
{
    __shared__ bf16 As[64 * 40];
    __shared__ bf16 Bs[256 * 40];
    __shared__ float red[2][64][4];
    __shared__ float stats[2][64];

    int tid = threadIdx.x;
    int lane = tid & 63, w = tid >> 6;
    int wm = w & 1, wn = w >> 1;              // 2 x 4
    int l15 = lane & 15, quad = lane >> 4;
    int bm = blockIdx.x * 64;

    floatx4 acc[2][4];
#pragma unroll
    for (int i = 0; i < 2; i++)
#pragma unroll
        for (int j = 0; j < 4; j++)
            acc[i][j] = (floatx4){0.f, 0.f, 0.f, 0.f};

    int srow = tid >> 2;
    int skc  = (tid & 3) * 8;

    for (int k0 = 0; k0 < K; k0 += 32) {
        *(int4*)(&Bs[srow * 40 + skc]) =
            *(const int4*)(BT + (size_t)srow * K + k0 + skc);
        *(int4*)(&Bs[(srow + 128) * 40 + skc]) =
            *(const int4*)(BT + (size_t)(srow + 128) * K + k0 + skc);
        if (tid < 256)
            *(int4*)(&As[(tid >> 2) * 40 + skc]) =
                *(const int4*)(A + (size_t)(bm + (tid >> 2)) * K + k0 + skc);
        __syncthreads();

        short8 a[2], bfr[4];
#pragma unroll
        for (int i = 0; i < 2; i++)
            a[i] = *(const short8*)(&As[(wm * 32 + i * 16 + l15) * 40 + quad * 8]);
#pragma unroll
        for (int j = 0; j < 4; j++)
            bfr[j] = *(const short8*)(&Bs[(wn * 64 + j * 16 + l15) * 40 + quad * 8]);
#pragma unroll
        for (int i = 0; i < 2; i++)
#pragma unroll
            for (int j = 0; j < 4; j++)
                acc[i][j] = __builtin_amdgcn_mfma_f32_16x16x32_bf16(
                    a[i], bfr[j], acc[i][j], 0, 0, 0);
        __syncthreads();
    }

    float x[2][4][4];
#pragma unroll
    for (int i = 0; i < 2; i++) {
#pragma unroll
        for (int j = 0; j < 4; j++) {
            int col = wn * 64 + j * 16 + l15;
            float bv = bias[col];
#pragma unroll
            for (int r = 0; r < 4; r++) {
                int row = bm + wm * 32 + i * 16 + quad * 4 + r;
                x[i][j][r] = toF(qb[(size_t)row * CDIM + col]) + acc[i][j][r] + bv;
            }
        }
    }
#pragma unroll
    for (int i = 0; i < 2; i++) {
#pragma unroll
        for (int r = 0; r < 4; r++) {
            float s = x[i][0][r] + x[i][1][r] + x[i][2][r] + x[i][3][r];
            float sq = x[i][0][r] * x[i][0][r] + x[i][1][r] * x[i][1][r] +
                       x[i][2][r] * x[i][2][r] + x[i][3][r] * x[i][3][r];
#pragma unroll
            for (int m = 1; m < 16; m <<= 1) {
                s += __shfl_xor(s, m);
                sq += __shfl_xor(sq, m);
            }
            if (l15 == 0) {
                int rl = wm * 32 + i * 16 + quad * 4 + r;
                red[0][rl][wn] = s;
                red[1][rl][wn] = sq;
            }
        }
    }
    __syncthreads();
    if (tid < 64) {
        float s = red[0][tid][0] + red[0][tid][1] + red[0][tid][2] + red[0][tid][3];
        float sq = red[1][tid][0] + red[1][tid][1] + red[1][tid][2] + red[1][tid][3];
        float mean = s * (1.f / CDIM);
        float var = fmaxf(sq * (1.f / CDIM) - mean * mean, 0.f);
        stats[0][tid] = mean;
        stats[1][tid] = rsqrtf(var + 1e-5f);
    }
    __syncthreads();
#pragma unroll
    for (int i = 0; i < 2; i++) {
#pragma unroll
        for (int j = 0; j < 4; j++) {
            int col = wn * 64 + j * 16 + l15;
            float gc = g[col], bc = b[col];
#pragma unroll
            for (int r = 0; r < 4; r++) {
                int rl = wm * 32 + i * 16 + quad * 4 + r;
                int row = bm + rl;
                float y = (x[i][j][r] - stats[0][rl]) * stats[1][rl] * gc + bc;
                qb[(size_t)row * CDIM + col] = __float2bfloat16(y);
            }
        }
    }
}

// ---------------------------------------------------------------------------
// Weight convert+transpose, batched over layers (blockIdx.z)
// ---------------------------------------------------------------------------
__global__ void wt_cvt_kernel(const float* __restrict__ W, bf16* __restrict__ WT,
                              int K, int N)
{
    __shared__ float tile[32][33];
    int l = blockIdx.z;
    const float* Wl = W + (size_t)l * K * N;
    bf16* WTl = WT + (size_t)l * K * N;
    int k0 = blockIdx.x * 32, n0 = blockIdx.y * 32;
    int tx = threadIdx.x, ty = threadIdx.y;
    for (int i = 0; i < 32; i += 8)
        tile[ty + i][tx] = Wl[(size_t)(k0 + ty + i) * N + n0 + tx];
    __syncthreads();
    for (int i = 0; i < 32; i += 8)
        WTl[(size_t)(n0 + ty + i) * K + k0 + tx] = __float2bfloat16(tile[tx][ty + i]);
}

// Pack TSA fused weights: 384 rows = [vw^T(256) | ow(64) | aw(32) | 0(32)]
__global__ void pack_tsa_kernel(const float* __restrict__ vw, const float* __restrict__ vb,
                                const float* __restrict__ ow, const float* __restrict__ ob,
                                const float* __restrict__ aw, const float* __restrict__ ab,
                                bf16* __restrict__ WT, float* __restrict__ BIAS)
{
    int n = blockIdx.x;      // 0..383
    int l = blockIdx.y;
    int k = threadIdx.x;     // 0..255
    float v = 0.f;
    if (n < 256)      v = vw[((size_t)l * 256 + k) * 256 + n];
    else if (n < 320) v = ow[((size_t)l * 256 + k) * 64 + (n - 256)];
    else if (n < 352) v = aw[((size_t)l * 256 + k) * 32 + (n - 320)];
    WT[((size_t)l * 384 + n) * 256 + k] = __float2bfloat16(v);
    if (k == 0) {
        float bv = 0.f;
        if (n < 256)      bv = vb[l * 256 + n];
        else if (n < 320) bv = ob[l * 64 + (n - 256)];
        else if (n < 352) bv = ab[l * 32 + (n - 320)];
        BIAS[l * 384 + n] = bv;
    }
}

__global__ void pack_offattn_kernel(const float* __restrict__ ow, const float* __restrict__ ob,
                                    const float* __restrict__ aw, const float* __restrict__ ab,
                                    bf16* __restrict__ WT, float* __restrict__ BIAS)
{
    int l = blockIdx.y;
    int n = blockIdx.x;
    int k = threadIdx.x;
    float v = 0.f;
    if (n < 64)      v = ow[((size_t)l * 256 + k) * 64 + n];
    else if (n < 96) v = aw[((size_t)l * 256 + k) * 32 + (n - 64)];
    WT[((size_t)l * 128 + n) * 256 + k] = __float2bfloat16(v);
    if (k == 0) {
        float bv = 0.f;
        if (n < 64)      bv = ob[l * 64 + n];
        else if (n < 96) bv = ab[l * 32 + (n - 64)];
        BIAS[l * 128 + n] = bv;
    }
}

__global__ void feats_cvt_kernel(const float* __restrict__ in, bf16* __restrict__ outT)
{
    __shared__ float tile[32][33];
    int c = blockIdx.z;
    int r0 = blockIdx.x * 32, ch0 = blockIdx.y * 32;
    int tx = threadIdx.x, ty = threadIdx.y;
    for (int i = 0; i < 32; i += 8) {
        int r = r0 + tx, ch = ch0 + ty + i;
        tile[ty + i][tx] = (r < HWF) ? in[((size_t)c * CDIM + ch) * HWF + r] : 0.f;
    }
    __syncthreads();
    for (int i = 0; i < 32; i += 8) {
        int r = r0 + ty + i, ch = ch0 + tx;
        if (r < HWF)
            outT[((size_t)c * HWF + r) * CDIM + ch] = __float2bfloat16(tile[tx][ty + i]);
    }
}

__global__ __launch_bounds__(256) void cvt_bf16_kernel(const float* __restrict__ in,
                                                       bf16* __restrict__ out, int n)
{
    int i = blockIdx.x * 256 + threadIdx.x;
    if (i < n) out[i] = __float2bfloat16(in[i]);
}

// ---------------------------------------------------------------------------
__global__ void invert4_kernel(const float* __restrict__ extr, float* __restrict__ ego)
{
    int c = threadIdx.x;
    if (c >= NCAM) return;
    float a[4][8];
    for (int i = 0; i < 4; i++)
        for (int j = 0; j < 4; j++) {
            a[i][j] = extr[c * 16 + i * 4 + j];
            a[i][4 + j] = (i == j) ? 1.f : 0.f;
        }
    for (int col = 0; col < 4; col++) {
        int piv = col;
        float best = fabsf(a[col][col]);
        for (int r = col + 1; r < 4; r++) {
            float v = fabsf(a[r][col]);
            if (v > best) { best = v; piv = r; }
        }
        if (piv != col)
            for (int j = 0; j < 8; j++) {
                float t = a[col][j]; a[col][j] = a[piv][j]; a[piv][j] = t;
            }
        float inv = 1.f / a[col][col];
        for (int j = 0; j < 8; j++) a[col][j] *= inv;
        for (int r = 0; r < 4; r++) {
            if (r == col) continue;
            float f = a[r][col];
            for (int j = 0; j < 8; j++) a[r][j] -= f * a[col][j];
        }
    }
    for (int i = 0; i < 4; i++)
        for (int j = 0; j < 4; j++)
            ego[c * 16 + i * 4 + j] = a[i][4 + j];
}

__global__ __launch_bounds__(256) void refcam_kernel(
    const float* __restrict__ ego, const float* __restrict__ intr,
    float* __restrict__ refcam, float* __restrict__ validb)
{
    int t = blockIdx.x * 256 + threadIdx.x;
    if (t >= NCAM * NQ * NPOINTS) return;
    int p = t & 3;
    int n = (t >> 2) & (NQ - 1);
    int c = t >> 16;

    float gx = ((n & 127) + 0.5f) / 128.0f;
    float gy = ((n >> 7) + 0.5f) / 128.0f;
    float xm = -51.2f + gx * 102.4f;
    float ym = -51.2f + gy * 102.4f;
    float zm = -5.0f + (p + 0.5f) * 2.0f;

    const float* E = ego + c * 16;
    float pc[3];
#pragma unroll
    for (int i = 0; i < 3; i++)
        pc[i] = E[i * 4 + 0] * xm + E[i * 4 + 1] * ym + E[i * 4 + 2] * zm + E[i * 4 + 3];

    const float* I = intr + c * 9;
    float im[3];
#pragma unroll
    for (int i = 0; i < 3; i++)
        im[i] = I[i * 3 + 0] * pc[0] + I[i * 3 + 1] * pc[1] + I[i * 3 + 2] * pc[2];

    float z = im[2];
    float zc = fmaxf(z, 1e-5f);
    float un = im[0] / (zc * (float)WF);
    float vn = im[1] / (zc * (float)HF);
    float val = (z > 1e-5f && un >= 0.f && un <= 1.f && vn >= 0.f && vn <= 1.f) ? 1.f : 0.f;

    size_t idx = ((size_t)c * NQ + n) * NPOINTS + p;
    refcam[idx * 2] = un;
    refcam[idx * 2 + 1] = vn;
    validb[idx] = val;
}

// ---------------------------------------------------------------------------
// TSA sampling: 4096 blocks (XCD-swizzled), 256 thr = 4 queries x 8 heads x
// 8 ch-quads. vgrid interleaved: one 16B load = 4ch prev + 4ch cur.
// ---------------------------------------------------------------------------
__global__ __launch_bounds__(256) void tsa_sample_kernel(
    const bf16* __restrict__ vgrid, const float* __restrict__ offlog,
    bf16* __restrict__ outA)
{
    int blk = blockIdx.x;
    int qq = (blk & 7) * 512 + (blk >> 3);
    int t = threadIdx.x;
    int n = qq * 4 + (t >> 6);
    int r = t & 63;
    int h = r >> 3;
    int dq = r & 7;
    int col = h * HD + dq * 4;
    int q8 = h * 8 + dq;                 // col >> 2

    const float* fl = offlog + (size_t)n * 128;
    const float* lg = fl + 64 + h * 4;
    float l0 = lg[0], l1 = lg[1], l2 = lg[2], l3 = lg[3];
    float mx = fmaxf(fmaxf(l0, l1), fmaxf(l2, l3));
    float e0 = expf(l0 - mx), e1 = expf(l1 - mx), e2 = expf(l2 - mx), e3 = expf(l3 - mx);
    float inv = 1.f / (e0 + e1 + e2 + e3);
    float w[4] = { e0 * inv, e1 * inv, e2 * inv, e3 * inv };

    const float* of = fl + h * 8;
    float rx = ((n & 127) + 0.5f) / 128.f;
    float ry = ((n >> 7) + 0.5f) / 128.f;

    float a0 = 0.f, a1 = 0.f, a2 = 0.f, a3 = 0.f;
#pragma unroll
    for (int p = 0; p < NPOINTS; p++) {
        float lx = rx + of[p * 2] * (1.f / 128.f);
        float ly = ry + of[p * 2 + 1] * (1.f / 128.f);
        float ix = lx * 128.f - 0.5f;
        float iy = ly * 128.f - 0.5f;
        float xf = floorf(ix), yf = floorf(iy);
        float fx = ix - xf, fy = iy - yf;
        int x0 = (int)xf, y0 = (int)yf;
#pragma unroll
        for (int dy = 0; dy < 2; dy++) {
            int yi = y0 + dy;
            if (yi < 0 || yi >= 128) continue;
            float wy = dy ? fy : 1.f - fy;
#pragma unroll
            for (int dx = 0; dx < 2; dx++) {
                int xi = x0 + dx;
                if (xi < 0 || xi >= 128) continue;
                float wgt = w[p] * wy * (dx ? fx : 1.f - fx);
                size_t idx = ((size_t)(yi * 128 + xi) * 64 + q8) * 8;
                uint4 v = *(const uint4*)(vgrid + idx);   // prev(4ch) | cur(4ch)
                a0 += wgt * (bfLo(v.x) + bfLo(v.z));
                a1 += wgt * (bfHi(v.x) + bfHi(v.z));
                a2 += wgt * (bfLo(v.y) + bfLo(v.w));
                a3 += wgt * (bfHi(v.y) + bfHi(v.w));
            }
        }
    }
    union { bf16 b[4]; uint2 u; } pk;
    pk.b[0] = __float2bfloat16(0.5f * a0);
    pk.b[1] = __float2bfloat16(0.5f * a1);
    pk.b[2] = __float2bfloat16(0.5f * a2);
    pk.b[3] = __float2bfloat16(0.5f * a3);
    *(uint2*)(outA + (size_t)n * CDIM + col) = pk.u;
}

// ---------------------------------------------------------------------------
// SCA sampling: 2048 blocks (XCD-swizzled), 256 thr = 8 queries x 8 heads x
// 4 ch-octs; 16B loads. cnt computed inline.
// ---------------------------------------------------------------------------
__global__ __launch_bounds__(256) void sca_sample_kernel(
    const bf16* __restrict__ vimg, const float* __restrict__ offlog,
    const float* __restrict__ refcam, const float* __restrict__ validb,
    bf16* __restrict__ outA)
{
    int blk = blockIdx.x;
    int qo = (blk & 7) * 256 + (blk >> 3);
    int t = threadIdx.x;
    int n = qo * 8 + (t >> 5);
    int r = t & 31;
    int h = r >> 2;
    int d8 = r & 3;
    int col = h * HD + d8 * 8;

    const float* fl = offlog + (size_t)n * 128;
    const float* lg = fl + 64 + h * 4;
    float l0 = lg[0], l1 = lg[1], l2 = lg[2], l3 = lg[3];
    float mx = fmaxf(fmaxf(l0, l1), fmaxf(l2, l3));
    float e0 = expf(l0 - mx), e1 = expf(l1 - mx), e2 = expf(l2 - mx), e3 = expf(l3 - mx);
    float inv = 1.f / (e0 + e1 + e2 + e3);
    float w[4] = { e0 * inv, e1 * inv, e2 * inv, e3 * inv };

    const float* of = fl + h * 8;
    float ox[4], oy[4];
#pragma unroll
    for (int p = 0; p < NPOINTS; p++) {
        ox[p] = of[p * 2] * (1.f / (float)WF);
        oy[p] = of[p * 2 + 1] * (1.f / (float)HF);
    }

    float a0 = 0.f, a1 = 0.f, a2 = 0.f, a3 = 0.f;
    float a4 = 0.f, a5 = 0.f, a6 = 0.f, a7 = 0.f;
    float vsum = 0.f;
    for (int c = 0; c < NCAM; c++) {
        const bf16* vb = vimg + (size_t)c * HWF * CDIM;
        size_t base = ((size_t)c * NQ + n) * NPOINTS;
#pragma unroll
        for (int p = 0; p < NPOINTS; p++) {
            float vl = validb[base + p];
            vsum += vl;
            if (vl == 0.f) continue;
            float lx = refcam[(base + p) * 2] + ox[p];
            float ly = refcam[(base + p) * 2 + 1] + oy[p];
            float ix = lx * (float)WF - 0.5f;
            float iy = ly * (float)HF - 0.5f;
            float xf = floorf(ix), yf = floorf(iy);
            float fx = ix - xf, fy = iy - yf;
            int x0 = (int)xf, y0 = (int)yf;
            float wp_ = w[p] * vl;
#pragma unroll
            for (int dy = 0; dy < 2; dy++) {
                int yi = y0 + dy;
                if (yi < 0 || yi >= HF) continue;
                float wy = dy ? fy : 1.f - fy;
#pragma unroll
                for (int dx = 0; dx < 2; dx++) {
                    int xi = x0 + dx;
                    if (xi < 0 || xi >= WF) continue;
                    float wgt = wp_ * wy * (dx ? fx : 1.f - fx);
                    uint4 u = *(const uint4*)(vb + (size_t)(yi * WF + xi) * CDIM + col);
                    a0 += wgt * bfLo(u.x);
                    a1 += wgt * bfHi(u.x);
                    a2 += wgt * bfLo(u.y);
                    a3 += wgt * bfHi(u.y);
                    a4 += wgt * bfLo(u.z);
                    a5 += wgt * bfHi(u.z);
                    a6 += wgt * bfLo(u.w);
                    a7 += wgt * bfHi(u.w);
                }
            }
        }
    }
    float ic = 1.f / fmaxf(vsum, 1.f);
    union { bf16 b[8]; uint4 u; } pk;
    pk.b[0] = __float2bfloat16(a0 * ic);
    pk.b[1] = __float2bfloat16(a1 * ic);
    pk.b[2] = __float2bfloat16(a2 * ic);
    pk.b[3] = __float2bfloat16(a3 * ic);
    pk.b[4] = __float2bfloat16(a4 * ic);
    pk.b[5] = __float2bfloat16(a5 * ic);
    pk.b[6] = __float2bfloat16(a6 * ic);
    pk.b[7] = __float2bfloat16(a7 * ic);
    *(uint4*)(outA + (size_t)n * CDIM + col) = pk.u;
}

// ---------------------------------------------------------------------------
// out[ch*16384 + n] = float(qb[n*256 + ch])
// ---------------------------------------------------------------------------
__global__ void out_transpose_kernel(const bf16* __restrict__ qb, float* __restrict__ out)
{
    __shared__ float tile[32][33];
    int n0 = blockIdx.x * 32;
    int c0 = blockIdx.y * 32;
    int tx = threadIdx.x, ty = threadIdx.y;
    for (int i = 0; i < 32; i += 8)
        tile[ty + i][tx] = toF(qb[(size_t)(n0 + ty + i) * CDIM + c0 + tx]);
    __syncthreads();
    for (int i = 0; i < 32; i += 8)
        out[(size_t)(c0 + ty + i) * NQ + n0 + tx] = tile[tx][ty + i];
}

// ---------------------------------------------------------------------------
// Host launcher
// ---------------------------------------------------------------------------
extern "C" void kernel_launch(void* const* d_in, const int* in_sizes, int n_in,
                              void* d_out, int out_size, void* d_ws, size_t ws_size,
                              hipStream_t stream)
{
    const float* image_feats = (const float*)d_in[0];
    const float* intr        = (const float*)d_in[1];
    const float* extr        = (const float*)d_in[2];
    const float* prev_bev    = (const float*)d_in[3];
    const float* bev_embed   = (const float*)d_in[4];
    const float* tsa_vw = (const float*)d_in[5];
    const float* tsa_vb = (const float*)d_in[6];
    const float* tsa_ow = (const float*)d_in[7];
    const float* tsa_ob = (const float*)d_in[8];
    const float* tsa_aw = (const float*)d_in[9];
    const float* tsa_ab = (const float*)d_in[10];
    const float* tsa_pw = (const float*)d_in[11];
    const float* tsa_pb = (const float*)d_in[12];
    const float* sca_vw = (const float*)d_in[13];
    const float* sca_vb = (const float*)d_in[14];
    const float* sca_ow = (const float*)d_in[15];
    const float* sca_ob = (const float*)d_in[16];
    const float* sca_aw = (const float*)d_in[17];
    const float* sca_ab = (const float*)d_in[18];
    const float* sca_pw = (const float*)d_in[19];
    const float* sca_pb = (const float*)d_in[20];
    const float* ffn_w1 = (const float*)d_in[21];
    const float* ffn_b1 = (const float*)d_in[22];
    const float* ffn_w2 = (const float*)d_in[23];
    const float* ffn_b2 = (const float*)d_in[24];
    const float* ln1_g  = (const float*)d_in[25];
    const float* ln1_b  = (const float*)d_in[26];
    const float* ln2_g  = (const float*)d_in[27];
    const float* ln2_b  = (const float*)d_in[28];
    const float* ln3_g  = (const float*)d_in[29];
    const float* ln3_b  = (const float*)d_in[30];

    // --- workspace layout (~190 MB of the 268 MB d_ws) ---
    char* wp = (char*)d_ws;
    auto alloc = [&](size_t bytes) -> void* {
        void* r = (void*)wp;
        wp += (bytes + 255) & ~(size_t)255;
        return r;
    };
    bf16*  prevbf = (bf16*) alloc((size_t)NQ * CDIM * 2);  // qb must follow contiguously
    bf16*  qb     = (bf16*) alloc((size_t)NQ * CDIM * 2);
    bf16*  attnA  = (bf16*) alloc((size_t)NQ * CDIM * 2);
    float* offlog = (float*)alloc((size_t)NQ * 128 * 4);
    float* refcam = (float*)alloc((size_t)NCAM * NQ * NPOINTS * 2 * 4);
    float* validb = (float*)alloc((size_t)NCAM * NQ * NPOINTS * 4);
    float* ego    = (float*)alloc(128 * 4);
    bf16*  featsT = (bf16*) alloc((size_t)NFEAT * CDIM * 2);   // union w/ hidden
    bf16*  pwT  = (bf16*)alloc((size_t)NLAYERS * 65536 * 2);
    bf16*  svwT = (bf16*)alloc((size_t)NLAYERS * 65536 * 2);
    bf16*  spwT = (bf16*)alloc((size_t)NLAYERS * 65536 * 2);
    bf16*  w1T  = (bf16*)alloc((size_t)NLAYERS * 131072 * 2);
    bf16*  w2T  = (bf16*)alloc((size_t)NLAYERS * 131072 * 2);
    bf16*  ptwT = (bf16*)alloc((size_t)NLAYERS * 384 * 256 * 2);  // tsa fused [vw|ow|aw|0]
    float* ptb  = (float*)alloc((size_t)NLAYERS * 384 * 4);
    bf16*  sowT = (bf16*)alloc((size_t)NLAYERS * 32768 * 2);
    float* sobF = (float*)alloc((size_t)NLAYERS * 128 * 4);
    bf16*  vgrid = (bf16*)alloc((size_t)NQ * CDIM * 2 * 2);       // prev/cur interleaved
    bf16*  vimg6 = (bf16*)alloc((size_t)NLAYERS * NFEAT * CDIM * 2); // 106.9 MB

    bf16* hidden = featsT;   // featsT consumed in prep; hidden used in loop

    dim3 blk32(32, 8);

    // --- prep ---
    cvt_bf16_kernel<<<(NQ * CDIM + 255) / 256, 256, 0, stream>>>(bev_embed, qb, NQ * CDIM);
    cvt_bf16_kernel<<<(NQ * CDIM + 255) / 256, 256, 0, stream>>>(prev_bev, prevbf, NQ * CDIM);
    invert4_kernel<<<1, 64, 0, stream>>>(extr, ego);
    refcam_kernel<<<(NCAM * NQ * NPOINTS + 255) / 256, 256, 0, stream>>>(ego, intr, refcam, validb);
    {
        dim3 g((HWF + 31) / 32, CDIM / 32, NCAM);
        feats_cvt_kernel<<<g, blk32, 0, stream>>>(image_feats, featsT);
    }
    wt_cvt_kernel<<<dim3(8, 8,  NLAYERS), blk32, 0, stream>>>(tsa_pw, pwT,  256, 256);
    wt_cvt_kernel<<<dim3(8, 8,  NLAYERS), blk32, 0, stream>>>(sca_vw, svwT, 256, 256);
    wt_cvt_kernel<<<dim3(8, 8,  NLAYERS), blk32, 0, stream>>>(sca_pw, spwT, 256, 256);
    wt_cvt_kernel<<<dim3(8, 16, NLAYERS), blk32, 0, stream>>>(ffn_w1, w1T, 256, 512);
    wt_cvt_kernel<<<dim3(16, 8, NLAYERS), blk32, 0, stream>>>(ffn_w2, w2T, 512, 256);
    pack_tsa_kernel<<<dim3(384, NLAYERS), 256, 0, stream>>>(
        tsa_vw, tsa_vb, tsa_ow, tsa_ob, tsa_aw, tsa_ab, ptwT, ptb);
    pack_offattn_kernel<<<dim3(128, NLAYERS), 256, 0, stream>>>(
        sca_ow, sca_ob, sca_aw, sca_ab, sowT, sobF);
    // all 6 layers of vimg in one batched launch (input-only dependency)
    gemm_mfma<bf16, false, true><<<dim3(2, (NFEAT + 127) / 128, NLAYERS), 256, 0, stream>>>(
        featsT, svwT, sca_vb, vimg6, NFEAT, CDIM, CDIM,
        65536, 256, (size_t)NFEAT * CDIM);

    for (int l = 0; l < NLAYERS; l++) {
        // ---- TSA: fused [v(prev+cur) | offlog] GEMM ----
        gemm_tsa<<<dim3(3, 2 * NQ / 128), 256, 0, stream>>>(
            prevbf, ptwT + (size_t)l * 98304, ptb + l * 384, vgrid, offlog);
        tsa_sample_kernel<<<NQ / 4, 256, 0, stream>>>(vgrid, offlog, attnA);
        gemm_ln<<<NQ / 64, 512, 0, stream>>>(
            attnA, pwT + (size_t)l * 65536, tsa_pb + l * CDIM,
            qb, ln1_g + l * CDIM, ln1_b + l * CDIM, CDIM);

        // ---- SCA ----
        gemm_mfma<float, false, false><<<dim3(1, NQ / 128, 1), 256, 0, stream>>>(
            qb, sowT + (size_t)l * 32768, sobF + l * 128, offlog, NQ, 128, CDIM, 0, 0, 0);
        sca_sample_kernel<<<NQ / 8, 256, 0, stream>>>(
            vimg6 + (size_t)l * NFEAT * CDIM, offlog, refcam, validb, attnA);
        gemm_ln<<<NQ / 64, 512, 0, stream>>>(
            attnA, spwT + (size_t)l * 65536, sca_pb + l * CDIM,
            qb, ln2_g + l * CDIM, ln2_b + l * CDIM, CDIM);

        // ---- FFN ----
        gemm_mfma<bf16, true, true><<<dim3(4, NQ / 128, 1), 256, 0, stream>>>(
            qb, w1T + (size_t)l * 131072, ffn_b1 + l * 512, hidden, NQ, 512, CDIM, 0, 0, 0);
        gemm_ln<<<NQ / 64, 512, 0, stream>>>(
            hidden, w2T + (size_t)l * 131072, ffn_b2 + l * CDIM,
            qb, ln3_g + l * CDIM, ln3_b + l * CDIM, 512);
    }

    {
        dim3 g(NQ / 32, CDIM / 32);
        out_transpose_kernel<<<g, blk32, 0, stream>>>(qb, (float*)d_out);
    }
}